// Round 3
// baseline (8093.108 us; speedup 1.0000x reference)
//
#include <hip/hip_runtime.h>
#include <hip/hip_bf16.h>
#include <cmath>

#define DEVFN __device__ __forceinline__

constexpr int HW = 16384;                      // 128*128
constexpr long long U = 16777216LL;            // 8*128*16384 floats (one full tensor)

// ---- workspace layout (floats). TWO big buffers in d_ws + d_out as third. ~130 MB ws. ----
// B1 = ws[0,U), B2 = ws[U,2U), S = ws[2U, 2U+434944).  eff/ybuf live in d_out.
constexpr long long OFF_X1   = 0;              // B1[0 : U/2)          phase 1
constexpr long long OFF_QS   = U/2;            // B1[U/2 : 3U/4)
constexpr long long OFF_KK   = 3*U/4;          // B1[3U/4 : U)
constexpr long long OFF_X2O  = U/2;            // overwrites dead qs
constexpr long long OFF_V    = U;              // B2[0 : U/4)
constexpr long long OFF_LF   = U + U/4;        // B2[U/4 : U/2)
constexpr long long OFF_QP   = U + U/2;        // 1,048,576
constexpr long long OFF_KP   = U + U/2 + 1048576;
constexpr long long OFF_TA   = 0;              // blur temp A = B1     phase 2
constexpr long long OFF_TB   = U;              // blur temp B = B2
constexpr long long OFF_CTX  = U;              // ctx = B2
constexpr long long OFF_ATTP = 0;              // attp = B1[0 : U/4)
constexpr long long OFF_QX   = 0;              // qx = B1              phase 3
constexpr long long OFF_FREQ = U;              // freq = B2
constexpr long long OFF_LOW  = 0;              // lowc = B1            phase 4
constexpr long long OFF_HIGH = U;              // highc = B2 (freq dead)
constexpr long long OFF_F    = 0;              // f = B1 (in-place over lowc)
constexpr long long S0       = 2*U;
constexpr long long OFF_QKB  = S0;             // 8192
constexpr long long OFF_AA   = S0 + 8192;      // 8192
constexpr long long OFF_MQ   = S0 + 16384;     // 1024
constexpr long long OFF_DQ   = S0 + 17408;     // 1024
constexpr long long OFF_PMAX = S0 + 18432;     // 131072
constexpr long long OFF_PSUM = S0 + 149504;    // 131072
constexpr long long OFF_MC   = S0 + 280576;    // 1024
constexpr long long OFF_DC   = S0 + 281600;    // 1024
constexpr long long OFF_ATT  = S0 + 282624;    // 131072
constexpr long long OFF_BNP  = S0 + 413696;    // 16384
constexpr long long OFF_SSL  = S0 + 430080;    // 256
constexpr long long OFF_SSH  = S0 + 430336;    // 256
constexpr long long OFF_SSY  = S0 + 430592;    // 256
constexpr long long OFF_DV   = S0 + 430848;    // 2048
constexpr long long OFF_D0   = S0 + 432896;    // 1024
constexpr long long OFF_D1   = S0 + 433920;    // 1024
// total ws floats = 2U + 434944 = 33,989,376 -> 135,957,504 bytes (~130 MB)

struct Taps { float g[7]; };

DEVFN float gelu_f(float v) { return 0.5f * v * (1.0f + erff(v * 0.7071067811865475f)); }

// ---------------- depthwise 3x3 + gelu on even channels ----------------
__global__ __launch_bounds__(256) void k_dwconv(const float* __restrict__ x, const float* __restrict__ w9,
                                                const float* __restrict__ bia, float* __restrict__ out) {
  int g = blockIdx.x * 256 + threadIdx.x;        // 8*64*16384
  int w = g & 127, h = (g >> 7) & 127, c = (g >> 14) & 63, n = g >> 20;
  const float* src = x + (long long)(n * 128 + 2 * c) * HW;
  float acc = bia[c];
  #pragma unroll
  for (int ky = 0; ky < 3; ++ky) {
    int h2 = h + ky - 1;
    if ((unsigned)h2 < 128u) {
      #pragma unroll
      for (int kx = 0; kx < 3; ++kx) {
        int w2 = w + kx - 1;
        if ((unsigned)w2 < 128u) acc = fmaf(w9[c * 9 + ky * 3 + kx], src[h2 * 128 + w2], acc);
      }
    }
  }
  out[(long long)(n * 64 + c) * HW + h * 128 + w] = gelu_f(acc);
}

// ---------------- qkvl 1x1 conv (64->160) + gelu, fused head routing ----------------
__global__ __launch_bounds__(256) void k_qkvl(const float* __restrict__ x, const float* __restrict__ wq,
                                              const float* __restrict__ bq, float* __restrict__ qs,
                                              float* __restrict__ kk, float* __restrict__ vv,
                                              float* __restrict__ lf) {
  __shared__ float lw[160 * 64];
  __shared__ float lb[160];
  int t = threadIdx.x;
  for (int e = t; e < 160 * 64; e += 256) lw[e] = wq[e];
  for (int e = t; e < 160; e += 256) lb[e] = bq[e];
  __syncthreads();
  int g = blockIdx.x * 256 + t;   // 131072
  int n = g >> 14, p = g & 16383;
  float xin[64];
  #pragma unroll
  for (int ci = 0; ci < 64; ++ci) xin[ci] = x[(long long)(n * 128 + 2 * ci + 1) * HW + p];
  for (int j = 0; j < 32; ++j) {
    float d0 = lb[j], d1 = lb[32 + j], d2 = lb[64 + j], d3 = lb[96 + j], d4 = lb[128 + j];
    #pragma unroll
    for (int ci = 0; ci < 64; ++ci) {
      float xv = xin[ci];
      d0 = fmaf(lw[j * 64 + ci], xv, d0);
      d1 = fmaf(lw[(32 + j) * 64 + ci], xv, d1);
      d2 = fmaf(lw[(64 + j) * 64 + ci], xv, d2);
      d3 = fmaf(lw[(96 + j) * 64 + ci], xv, d3);
      d4 = fmaf(lw[(128 + j) * 64 + ci], xv, d4);
    }
    long long o = (long long)(n * 32 + j) * HW + p;
    qs[o] = gelu_f(d0) + gelu_f(d1);
    kk[o] = gelu_f(d2);
    vv[o] = gelu_f(d3);
    lf[o] = gelu_f(d4);
  }
}

// ---------------- pools ----------------
__global__ __launch_bounds__(256) void k_avgpool(const float* __restrict__ in, float* __restrict__ out) {
  int g = blockIdx.x * 256 + threadIdx.x;   // 8*32*4096
  int ow = g & 63, oh = (g >> 6) & 63, c = (g >> 12) & 31, n = g >> 17;
  const float* src = in + (long long)(n * 32 + c) * HW;
  float s = 0.f;
  #pragma unroll
  for (int i = 0; i < 3; ++i) {
    int h = oh * 2 - 1 + i;
    if ((unsigned)h < 128u) {
      #pragma unroll
      for (int j = 0; j < 3; ++j) {
        int w = ow * 2 - 1 + j;
        if ((unsigned)w < 128u) s += src[h * 128 + w];
      }
    }
  }
  out[(long long)(n * 32 + c) * 4096 + oh * 64 + ow] = s * (1.f / 9.f);
}

__global__ __launch_bounds__(256) void k_maxpool(const float* __restrict__ in, float* __restrict__ out) {
  int g = blockIdx.x * 256 + threadIdx.x;
  int ow = g & 63, oh = (g >> 6) & 63, c = (g >> 12) & 31, n = g >> 17;
  const float* src = in + (long long)(n * 32 + c) * HW;
  float m = -3.0e38f;
  #pragma unroll
  for (int i = 0; i < 2; ++i)
    #pragma unroll
    for (int j = 0; j < 2; ++j)
      m = fmaxf(m, src[(oh * 2 + i) * 128 + ow * 2 + j]);
  out[(long long)(n * 32 + c) * 4096 + oh * 64 + ow] = m;
}

// ---------------- qk (32x32 per n, K=4096) ----------------
__global__ __launch_bounds__(256) void k_qk(const float* __restrict__ qp, const float* __restrict__ kp,
                                            float* __restrict__ qk) {
  int c = blockIdx.x, n = blockIdx.y;
  int t = threadIdx.x, d = t >> 3, r = t & 7;
  const float* qr = qp + (long long)(n * 32 + c) * 4096;
  const float* kr = kp + (long long)(n * 32 + d) * 4096;
  float acc = 0.f;
  for (int p = r; p < 4096; p += 8) acc = fmaf(qr[p], kr[p], acc);
  acc += __shfl_down(acc, 4, 8);
  acc += __shfl_down(acc, 2, 8);
  acc += __shfl_down(acc, 1, 8);
  if (r == 0) qk[(n * 32 + c) * 32 + d] = acc;
}

__global__ void k_qksm(const float* __restrict__ qk, float* __restrict__ A) {
  int n = blockIdx.x, d = threadIdx.x;   // block 32
  float m = -3.0e38f;
  for (int c = 0; c < 32; ++c) m = fmaxf(m, qk[(n * 32 + c) * 32 + d]);
  float s = 0.f;
  for (int c = 0; c < 32; ++c) s += expf(qk[(n * 32 + c) * 32 + d] - m);
  float inv = 1.f / s;
  for (int c = 0; c < 32; ++c) A[(n * 32 + c) * 32 + d] = expf(qk[(n * 32 + c) * 32 + d] - m) * inv;
}

// ---------------- x2o = A^T @ v ----------------
__global__ __launch_bounds__(256) void k_x2o(const float* __restrict__ A, const float* __restrict__ vsrc,
                                             float* __restrict__ out) {
  __shared__ float lA[1024];
  int t = threadIdx.x;
  int g = blockIdx.x * 256 + t;
  int n = g >> 14, p = g & 16383;
  for (int e = t; e < 1024; e += 256) lA[e] = A[n * 1024 + e];
  __syncthreads();
  float acc[32];
  #pragma unroll
  for (int i = 0; i < 32; ++i) acc[i] = 0.f;
  for (int q = 0; q < 32; ++q) {
    float vv = vsrc[(long long)(n * 32 + q) * HW + p];
    #pragma unroll
    for (int k2 = 0; k2 < 32; ++k2) acc[k2] = fmaf(lA[q * 32 + k2], vv, acc[k2]);
  }
  #pragma unroll
  for (int k2 = 0; k2 < 32; ++k2) out[(long long)(n * 32 + k2) * HW + p] = acc[k2];
}

// ---------------- generic 128x128x128 1x1-conv / attention GEMM ----------------
enum { M_EFF = 0, M_QX = 1, M_OUT = 2, M_FREQ = 3 };

template <int MODE>
__global__ __launch_bounds__(256) void k_gemm1x1(
    const float* __restrict__ Amat, const float* __restrict__ B0, const float* __restrict__ B1,
    const float* __restrict__ B2, const float* __restrict__ bias, const float* __restrict__ scale,
    const float* __restrict__ Mq, const float* __restrict__ invDq, const float* __restrict__ xres,
    float* __restrict__ outp) {
  __shared__ float As[32 * 129];
  __shared__ float Bs[32 * 129];
  const int t = threadIdx.x;
  const int bx = blockIdx.x, n = blockIdx.y;
  const int pxb = bx * 128;
  const int ty = t >> 4, tx = t & 15;
  const int ch0 = ty * 8, px0 = tx * 8;
  float acc[8][8];
  #pragma unroll
  for (int i = 0; i < 8; ++i)
    #pragma unroll
    for (int j = 0; j < 8; ++j) acc[i][j] = 0.f;

  for (int kc = 0; kc < 4; ++kc) {
    __syncthreads();
    if (MODE == M_FREQ) {
      #pragma unroll
      for (int it = 0; it < 16; ++it) {
        int e = it * 256 + t; int jj = e >> 7; int ch = e & 127;
        As[jj * 129 + ch] = Amat[(long long)(n * 128 + kc * 32 + jj) * 128 + ch];
      }
      #pragma unroll
      for (int it = 0; it < 16; ++it) {
        int ww = it * 8 + (t >> 5); int jj = t & 31; int j = kc * 32 + jj;
        float v = B0[(long long)(n * HW + pxb + ww) * 128 + j];
        Bs[jj * 129 + ww] = expf(v - Mq[n * 128 + j]) * invDq[n * 128 + j];
      }
    } else {
      #pragma unroll
      for (int it = 0; it < 16; ++it) {
        int e = it * 256 + t; int co = e >> 5; int kk = e & 31;
        As[kk * 129 + co] = Amat[co * 128 + kc * 32 + kk];
      }
      #pragma unroll
      for (int it = 0; it < 16; ++it) {
        int e = it * 256 + t; int kk = e >> 7; int px = e & 127;
        int ci = kc * 32 + kk;
        float v;
        if (MODE == M_EFF) {
          if (ci < 64)      v = B0[(long long)(n * 64 + ci) * HW + pxb + px];
          else if (ci < 96) v = B1[(long long)(n * 32 + ci - 64) * HW + pxb + px];
          else              v = B2[(long long)(n * 32 + ci - 96) * HW + pxb + px];
        } else if (MODE == M_QX) {
          v = B0[(long long)(n * 128 + ci) * HW + pxb + px];
        } else {  // M_OUT
          float u = B0[(long long)(n * 128 + ci) * HW + pxb + px];
          v = fmaxf(fmaf(u, scale[ci], scale[128 + ci]), 0.f);
        }
        Bs[kk * 129 + px] = v;
      }
    }
    __syncthreads();
    #pragma unroll 4
    for (int kk = 0; kk < 32; ++kk) {
      float a_[8], b_[8];
      #pragma unroll
      for (int i = 0; i < 8; ++i) a_[i] = As[kk * 129 + ch0 + i];
      #pragma unroll
      for (int j = 0; j < 8; ++j) b_[j] = Bs[kk * 129 + px0 + j];
      #pragma unroll
      for (int i = 0; i < 8; ++i)
        #pragma unroll
        for (int j = 0; j < 8; ++j) acc[i][j] = fmaf(a_[i], b_[j], acc[i][j]);
    }
  }
  #pragma unroll
  for (int i = 0; i < 8; ++i) {
    int ch = ch0 + i;
    long long ob = (long long)(n * 128 + ch) * HW + pxb + px0;
    float badd = (MODE == M_FREQ) ? 0.f : bias[ch];
    #pragma unroll
    for (int j = 0; j < 8; ++j) {
      float v = acc[i][j] + badd;
      if (MODE == M_FREQ) v += xres[ob + j];
      outp[ob + j] = v;
    }
  }
}

// ---------------- qx softmax stats (over (c,h) per (n,w)) ----------------
__global__ __launch_bounds__(128) void k_qx_pmax(const float* __restrict__ qx, float* __restrict__ pmax) {
  int c = blockIdx.x, n = blockIdx.y, w = threadIdx.x;
  long long base = (long long)(n * 128 + c) * HW + w;
  float m = -3.0e38f;
  for (int h = 0; h < 128; ++h) m = fmaxf(m, qx[base + h * 128]);
  pmax[(n * 128 + c) * 128 + w] = m;
}
__global__ __launch_bounds__(128) void k_qx_rmax(const float* __restrict__ pmax, float* __restrict__ Mq) {
  int n = blockIdx.x, w = threadIdx.x;
  float m = -3.0e38f;
  for (int c = 0; c < 128; ++c) m = fmaxf(m, pmax[(n * 128 + c) * 128 + w]);
  Mq[n * 128 + w] = m;
}
__global__ __launch_bounds__(128) void k_qx_psum(const float* __restrict__ qx, const float* __restrict__ Mq,
                                                 float* __restrict__ psum) {
  int c = blockIdx.x, n = blockIdx.y, w = threadIdx.x;
  float M = Mq[n * 128 + w];
  long long base = (long long)(n * 128 + c) * HW + w;
  float s = 0.f;
  for (int h = 0; h < 128; ++h) s += expf(qx[base + h * 128] - M);
  psum[(n * 128 + c) * 128 + w] = s;
}
__global__ __launch_bounds__(128) void k_qx_rsum(const float* __restrict__ psum, float* __restrict__ invDq) {
  int n = blockIdx.x, w = threadIdx.x;
  float s = 0.f;
  for (int c = 0; c < 128; ++c) s += psum[(n * 128 + c) * 128 + w];
  invDq[n * 128 + w] = 1.f / s;
}

// ---------------- separable gaussian blurs ----------------
template <int R>
__global__ __launch_bounds__(256) void k_hblur(const float* __restrict__ in, float* __restrict__ out, Taps tp) {
  int g = blockIdx.x * 256 + threadIdx.x;
  int w = g & 127;
  float s = 0.f;
  #pragma unroll
  for (int d = -R; d <= R; ++d) {
    int wd = w + d;
    if (0 <= wd && wd < 128) s = fmaf(tp.g[d + R], in[g + d], s);
  }
  out[g] = s;
}
template <int R, bool SUB>
__global__ __launch_bounds__(256) void k_vblur(const float* __restrict__ in, const float* __restrict__ xr,
                                               float* __restrict__ out, Taps tp) {
  int g = blockIdx.x * 256 + threadIdx.x;
  int h = (g >> 7) & 127;
  float s = 0.f;
  #pragma unroll
  for (int d = -R; d <= R; ++d) {
    int hd = h + d;
    if (0 <= hd && hd < 128) s = fmaf(tp.g[d + R], in[g + d * 128], s);
  }
  out[g] = SUB ? (xr[g] - s) : s;
}

// ---------------- ctx softmax stats (over p per (n,c)) ----------------
__global__ __launch_bounds__(256) void k_ctx_stats(const float* __restrict__ ctx, float* __restrict__ Mc,
                                                   float* __restrict__ invDc) {
  int c = blockIdx.x, n = blockIdx.y, t = threadIdx.x;
  long long base = (long long)(n * 128 + c) * HW;
  __shared__ float red[256];
  float m = -3.0e38f;
  for (int i = t; i < HW; i += 256) m = fmaxf(m, ctx[base + i]);
  red[t] = m; __syncthreads();
  for (int o = 128; o > 0; o >>= 1) { if (t < o) red[t] = fmaxf(red[t], red[t + o]); __syncthreads(); }
  m = red[0]; __syncthreads();
  float s = 0.f;
  for (int i = t; i < HW; i += 256) s += expf(ctx[base + i] - m);
  red[t] = s; __syncthreads();
  for (int o = 128; o > 0; o >>= 1) { if (t < o) red[t] += red[t + o]; __syncthreads(); }
  if (t == 0) { Mc[n * 128 + c] = m; invDc[n * 128 + c] = 1.f / red[0]; }
}

// ---------------- att = softmax(ctx) @ ctx^T (partial over p-splits) ----------------
__global__ __launch_bounds__(256) void k_att(const float* __restrict__ ctx, const float* __restrict__ Mc,
                                             const float* __restrict__ invDc, float* __restrict__ attp) {
  __shared__ float As[32 * 129];
  __shared__ float Bs[32 * 129];
  int t = threadIdx.x, sp = blockIdx.x, n = blockIdx.y;
  int ty = t >> 4, tx = t & 15;
  int c0 = ty * 8, d0 = tx * 8;
  float acc[8][8];
  #pragma unroll
  for (int i = 0; i < 8; ++i)
    #pragma unroll
    for (int j = 0; j < 8; ++j) acc[i][j] = 0.f;
  for (int kc = 0; kc < 16; ++kc) {
    __syncthreads();
    int pb = sp * 512 + kc * 32;
    #pragma unroll
    for (int it = 0; it < 16; ++it) {
      int e = it * 256 + t; int row = e >> 5; int kk = e & 31;
      float v = ctx[(long long)(n * 128 + row) * HW + pb + kk];
      Bs[kk * 129 + row] = v;
      As[kk * 129 + row] = expf(v - Mc[n * 128 + row]) * invDc[n * 128 + row];
    }
    __syncthreads();
    #pragma unroll 4
    for (int kk = 0; kk < 32; ++kk) {
      float a_[8], b_[8];
      #pragma unroll
      for (int i = 0; i < 8; ++i) a_[i] = As[kk * 129 + c0 + i];
      #pragma unroll
      for (int j = 0; j < 8; ++j) b_[j] = Bs[kk * 129 + d0 + j];
      #pragma unroll
      for (int i = 0; i < 8; ++i)
        #pragma unroll
        for (int j = 0; j < 8; ++j) acc[i][j] = fmaf(a_[i], b_[j], acc[i][j]);
    }
  }
  long long ob = ((long long)(sp * 8 + n) * 128 + c0) * 128 + d0;
  #pragma unroll
  for (int i = 0; i < 8; ++i)
    #pragma unroll
    for (int j = 0; j < 8; ++j) attp[ob + i * 128 + j] = acc[i][j];
}

__global__ __launch_bounds__(256) void k_attred(const float* __restrict__ attp, float* __restrict__ att) {
  int g = blockIdx.x * 256 + threadIdx.x;  // 131072
  float s = 0.f;
  for (int sp = 0; sp < 32; ++sp) s += attp[(long long)sp * 131072 + g];
  att[g] = s;
}

// ---------------- direct 3x3 conv, 128->128 ----------------
__global__ __launch_bounds__(256) void k_conv3(const float* __restrict__ in, const float* __restrict__ wts,
                                               float* __restrict__ out) {
  __shared__ float lin[16 * 18 * 34];
  __shared__ float lw[32 * 16 * 9];
  const int t = threadIdx.x;
  const int wwt = blockIdx.x & 3, cot = blockIdx.x >> 2;
  const int hht = blockIdx.y, n = blockIdx.z;
  const int ww0 = wwt * 32, hh0 = hht * 16, co0 = cot * 32;
  const int y = t >> 4, xx = t & 15;
  float a0[32], a1[32];
  #pragma unroll
  for (int i = 0; i < 32; ++i) { a0[i] = 0.f; a1[i] = 0.f; }
  for (int cc = 0; cc < 8; ++cc) {
    __syncthreads();
    for (int e = t; e < 16 * 18 * 34; e += 256) {
      int ci = e / 612; int rem = e % 612; int r = rem / 34; int col = rem % 34;
      int gh = hh0 + r - 1, gw = ww0 + col - 1;
      float v = 0.f;
      if ((unsigned)gh < 128u && (unsigned)gw < 128u)
        v = in[(long long)((n * 128 + cc * 16 + ci) * 128 + gh) * 128 + gw];
      lin[e] = v;
    }
    for (int e = t; e < 32 * 16 * 9; e += 256) {
      int co = e / 144; int rem = e % 144;
      lw[e] = wts[(long long)(co0 + co) * 1152 + cc * 144 + rem];
    }
    __syncthreads();
    for (int ci = 0; ci < 16; ++ci) {
      #pragma unroll
      for (int k = 0; k < 9; ++k) {
        int ky = k / 3, kx = k % 3;
        float i0 = lin[ci * 612 + (y + ky) * 34 + xx + kx];
        float i1 = lin[ci * 612 + (y + ky) * 34 + xx + 16 + kx];
        #pragma unroll
        for (int co = 0; co < 32; ++co) {
          float wv = lw[co * 144 + ci * 9 + k];
          a0[co] = fmaf(wv, i0, a0[co]);
          a1[co] = fmaf(wv, i1, a1[co]);
        }
      }
    }
  }
  long long ob = ((long long)(n * 128 + co0) * 128 + hh0 + y) * 128 + ww0;
  #pragma unroll
  for (int co = 0; co < 32; ++co) {
    out[ob + (long long)co * HW + xx] = a0[co];
    out[ob + (long long)co * HW + 16 + xx] = a1[co];
  }
}

// ---------------- BN batch stats ----------------
__global__ __launch_bounds__(256) void k_bnpart(const float* __restrict__ in, float* __restrict__ part) {
  int c = blockIdx.x, b = blockIdx.y, t = threadIdx.x;
  int n = b >> 3, seg = b & 7;
  long long base = (long long)(n * 128 + c) * HW + seg * 2048;
  float s = 0.f, ss = 0.f;
  for (int i = t; i < 2048; i += 256) { float v = in[base + i]; s += v; ss = fmaf(v, v, ss); }
  __shared__ float r1[256], r2[256];
  r1[t] = s; r2[t] = ss; __syncthreads();
  for (int o = 128; o > 0; o >>= 1) { if (t < o) { r1[t] += r1[t + o]; r2[t] += r2[t + o]; } __syncthreads(); }
  if (t == 0) { part[(c * 64 + b) * 2] = r1[0]; part[(c * 64 + b) * 2 + 1] = r2[0]; }
}
__global__ __launch_bounds__(64) void k_bnfin(const float* __restrict__ part, const float* __restrict__ g,
                                              const float* __restrict__ bb, float* __restrict__ ssout) {
  int c = blockIdx.x, t = threadIdx.x;
  float s = part[(c * 64 + t) * 2], ss = part[(c * 64 + t) * 2 + 1];
  for (int o = 32; o > 0; o >>= 1) { s += __shfl_down(s, o, 64); ss += __shfl_down(ss, o, 64); }
  if (t == 0) {
    float mean = s / 131072.f;
    float var = ss / 131072.f - mean * mean;
    float sc = g[c] * rsqrtf(var + 1e-5f);
    ssout[c] = sc;
    ssout[128 + c] = bb[c] - mean * sc;
  }
}

// ---------------- cubic power-mean per (n,c) ----------------
__global__ __launch_bounds__(256) void k_power(const float* __restrict__ in, const float* __restrict__ ss,
                                               float* __restrict__ dst, int off) {
  int c = blockIdx.x, n = blockIdx.y, t = threadIdx.x;
  float sc = ss[c], sh = ss[128 + c];
  long long base = (long long)(n * 128 + c) * HW;
  float s = 0.f;
  for (int i = t; i < HW; i += 256) {
    float r = fmaxf(fmaf(in[base + i], sc, sh), 0.f);
    s += r * r * r;
  }
  __shared__ float red[256];
  red[t] = s; __syncthreads();
  for (int o = 128; o > 0; o >>= 1) { if (t < o) red[t] += red[t + o]; __syncthreads(); }
  if (t == 0) dst[n * 256 + 2 * c + off] = cbrtf(red[0] * (1.f / 16384.f) + 1e-12f);
}

// ---------------- 1d conv x2 + sigmoid ----------------
__global__ __launch_bounds__(256) void k_dvec(const float* __restrict__ din, const float* __restrict__ c1,
                                              const float* __restrict__ c2, float* __restrict__ d0,
                                              float* __restrict__ d1) {
  __shared__ float a[256], b[256];
  int n = blockIdx.x, t = threadIdx.x;
  a[t] = din[n * 256 + t];
  __syncthreads();
  float acc = 0.f;
  #pragma unroll
  for (int k = 0; k < 5; ++k) { int j = t + k - 2; if (0 <= j && j < 256) acc = fmaf(c1[k], a[j], acc); }
  b[t] = acc; __syncthreads();
  float acc2 = 0.f;
  #pragma unroll
  for (int k = 0; k < 5; ++k) { int j = t + k - 2; if (0 <= j && j < 256) acc2 = fmaf(c2[k], b[j], acc2); }
  float sg = 1.f / (1.f + expf(-acc2));
  if ((t & 1) == 0) d0[n * 128 + (t >> 1)] = sg; else d1[n * 128 + (t >> 1)] = sg;
}

// ---------------- f = d0*relu(bn(low)) + d1*relu(bn(high)), in-place into low ----------------
__global__ __launch_bounds__(256) void k_fmix(float* __restrict__ low, const float* __restrict__ high,
                                              const float* __restrict__ ssl, const float* __restrict__ ssh,
                                              const float* __restrict__ d0, const float* __restrict__ d1) {
  int g = blockIdx.x * 256 + threadIdx.x;
  int c = (g >> 14) & 127, n = g >> 21;
  float xl = fmaxf(fmaf(low[g], ssl[c], ssl[128 + c]), 0.f);
  float xh = fmaxf(fmaf(high[g], ssh[c], ssh[128 + c]), 0.f);
  low[g] = d0[n * 128 + c] * xl + d1[n * 128 + c] * xh;
}

static void make_taps(int ks, double sigma, Taps* tp) {
  double c = (ks - 1) / 2.0, sum = 0.0, v[7];
  for (int i = 0; i < ks; ++i) { double d = i - c; v[i] = std::exp(-d * d / (2.0 * sigma * sigma)); sum += v[i]; }
  for (int i = 0; i < 7; ++i) tp->g[i] = (i < ks) ? (float)(v[i] / sum) : 0.f;
}

extern "C" void kernel_launch(void* const* d_in, const int* in_sizes, int n_in,
                              void* d_out, int out_size, void* d_ws, size_t ws_size,
                              hipStream_t stream) {
  const float* x         = (const float*)d_in[0];
  const float* dwconv_w  = (const float*)d_in[1];
  const float* dwconv_b  = (const float*)d_in[2];
  const float* qkvl_w    = (const float*)d_in[3];
  const float* qkvl_b    = (const float*)d_in[4];
  const float* reproj_w  = (const float*)d_in[5];
  const float* reproj_b  = (const float*)d_in[6];
  const float* queries_w = (const float*)d_in[7];
  const float* queries_b = (const float*)d_in[8];
  const float* sff_low_w = (const float*)d_in[9];
  const float* sff_low_g = (const float*)d_in[10];
  const float* sff_low_b = (const float*)d_in[11];
  const float* sff_high_w= (const float*)d_in[12];
  const float* sff_high_g= (const float*)d_in[13];
  const float* sff_high_b= (const float*)d_in[14];
  const float* sff_c1_w  = (const float*)d_in[15];
  const float* sff_c2_w  = (const float*)d_in[16];
  const float* out_conv_w= (const float*)d_in[17];
  const float* out_bn_g  = (const float*)d_in[18];
  const float* out_bn_b  = (const float*)d_in[19];
  const float* out_proj_w= (const float*)d_in[20];
  const float* out_proj_b= (const float*)d_in[21];
  float* ws  = (float*)d_ws;
  float* out = (float*)d_out;

  float* x1   = ws + OFF_X1;
  float* qs   = ws + OFF_QS;
  float* kk   = ws + OFF_KK;
  float* x2o  = ws + OFF_X2O;
  float* vv   = ws + OFF_V;
  float* lf   = ws + OFF_LF;
  float* qp   = ws + OFF_QP;
  float* kp   = ws + OFF_KP;
  float* eff  = out;            // d_out doubles as eff (phase 1-4a), then ybuf, then final out
  float* tA   = ws + OFF_TA;
  float* tB   = ws + OFF_TB;
  float* ctx  = ws + OFF_CTX;
  float* attp = ws + OFF_ATTP;
  float* qx   = ws + OFF_QX;
  float* freq = ws + OFF_FREQ;
  float* lowc = ws + OFF_LOW;
  float* highc= ws + OFF_HIGH;
  float* fbuf = ws + OFF_F;     // == lowc (in-place)
  float* ybuf = out;            // reuses d_out after eff is dead
  float* qkb  = ws + OFF_QKB;
  float* Abuf = ws + OFF_AA;
  float* Mq   = ws + OFF_MQ;
  float* Dq   = ws + OFF_DQ;
  float* pmax = ws + OFF_PMAX;
  float* psum = ws + OFF_PSUM;
  float* Mc   = ws + OFF_MC;
  float* Dc   = ws + OFF_DC;
  float* att  = ws + OFF_ATT;
  float* bnp  = ws + OFF_BNP;
  float* ssl  = ws + OFF_SSL;
  float* ssh  = ws + OFF_SSH;
  float* ssy  = ws + OFF_SSY;
  float* dv   = ws + OFF_DV;
  float* d0v  = ws + OFF_D0;
  float* d1v  = ws + OFF_D1;

  Taps t3, t5, t7;
  const double s3 = std::pow(2.0, 1.0 / 3.0);
  make_taps(3, 1.6, &t3);
  make_taps(5, 1.6 * s3, &t5);
  make_taps(7, 1.6 * s3 * s3, &t7);

  dim3 b256(256), b128(128);

  // ---- phase 1: eff (into d_out) ----
  k_dwconv<<<dim3(32768), b256, 0, stream>>>(x, dwconv_w, dwconv_b, x1);
  k_qkvl<<<dim3(512), b256, 0, stream>>>(x, qkvl_w, qkvl_b, qs, kk, vv, lf);
  k_avgpool<<<dim3(4096), b256, 0, stream>>>(qs, qp);
  k_maxpool<<<dim3(4096), b256, 0, stream>>>(kk, kp);
  k_qk<<<dim3(32, 8), b256, 0, stream>>>(qp, kp, qkb);
  k_qksm<<<dim3(8), dim3(32), 0, stream>>>(qkb, Abuf);
  k_x2o<<<dim3(512), b256, 0, stream>>>(Abuf, vv, x2o);      // overwrites dead qs
  k_gemm1x1<M_EFF><<<dim3(128, 8), b256, 0, stream>>>(reproj_w, x1, lf, x2o, reproj_b,
                                                      nullptr, nullptr, nullptr, nullptr, eff);
  // ---- phase 2: ctx / att (B1,B2 free now) ----
  k_hblur<1><<<dim3(65536), b256, 0, stream>>>(x, tA, t3);
  k_vblur<1, false><<<dim3(65536), b256, 0, stream>>>(tA, nullptr, tB, t3);
  k_hblur<2><<<dim3(65536), b256, 0, stream>>>(tB, tA, t5);
  k_vblur<2, false><<<dim3(65536), b256, 0, stream>>>(tA, nullptr, tB, t5);
  k_hblur<3><<<dim3(65536), b256, 0, stream>>>(tB, tA, t7);
  k_vblur<3, true><<<dim3(65536), b256, 0, stream>>>(tA, x, ctx, t7);   // ctx = B2
  k_ctx_stats<<<dim3(128, 8), b256, 0, stream>>>(ctx, Mc, Dc);
  k_att<<<dim3(32, 8), b256, 0, stream>>>(ctx, Mc, Dc, attp);          // attp = B1[0:U/4)
  k_attred<<<dim3(512), b256, 0, stream>>>(attp, att);
  // ---- phase 3: qx -> freq ----
  k_gemm1x1<M_QX><<<dim3(128, 8), b256, 0, stream>>>(queries_w, x, nullptr, nullptr, queries_b,
                                                     nullptr, nullptr, nullptr, nullptr, qx);  // qx = B1
  k_qx_pmax<<<dim3(128, 8), b128, 0, stream>>>(qx, pmax);
  k_qx_rmax<<<dim3(8), b128, 0, stream>>>(pmax, Mq);
  k_qx_psum<<<dim3(128, 8), b128, 0, stream>>>(qx, Mq, psum);
  k_qx_rsum<<<dim3(8), b128, 0, stream>>>(psum, Dq);
  k_gemm1x1<M_FREQ><<<dim3(128, 8), b256, 0, stream>>>(att, qx, nullptr, nullptr, nullptr,
                                                       nullptr, Mq, Dq, x, freq);              // freq = B2
  // ---- phase 4: convs / BN / mix / out ----
  k_conv3<<<dim3(16, 8, 8), b256, 0, stream>>>(freq, sff_low_w, lowc);     // lowc = B1 (qx dead)
  k_conv3<<<dim3(16, 8, 8), b256, 0, stream>>>(eff, sff_high_w, highc);    // highc = B2 (freq dead)
  k_bnpart<<<dim3(128, 64), b256, 0, stream>>>(lowc, bnp);
  k_bnfin<<<dim3(128), dim3(64), 0, stream>>>(bnp, sff_low_g, sff_low_b, ssl);
  k_bnpart<<<dim3(128, 64), b256, 0, stream>>>(highc, bnp);
  k_bnfin<<<dim3(128), dim3(64), 0, stream>>>(bnp, sff_high_g, sff_high_b, ssh);
  k_power<<<dim3(128, 8), b256, 0, stream>>>(lowc, ssl, dv, 0);
  k_power<<<dim3(128, 8), b256, 0, stream>>>(highc, ssh, dv, 1);
  k_dvec<<<dim3(8), b256, 0, stream>>>(dv, sff_c1_w, sff_c2_w, d0v, d1v);
  k_fmix<<<dim3(65536), b256, 0, stream>>>(lowc, highc, ssl, ssh, d0v, d1v);  // f in-place -> B1
  k_conv3<<<dim3(16, 8, 8), b256, 0, stream>>>(fbuf, out_conv_w, ybuf);       // ybuf = d_out (eff dead)
  k_bnpart<<<dim3(128, 64), b256, 0, stream>>>(ybuf, bnp);
  k_bnfin<<<dim3(128), dim3(64), 0, stream>>>(bnp, out_bn_g, out_bn_b, ssy);
  k_gemm1x1<M_OUT><<<dim3(128, 8), b256, 0, stream>>>(out_proj_w, ybuf, nullptr, nullptr, out_proj_b,
                                                      ssy, nullptr, nullptr, nullptr, out);    // in-place safe
  (void)in_sizes; (void)n_in; (void)out_size; (void)ws_size;
}

// Round 4
// 2046.690 us; speedup vs baseline: 3.9542x; 3.9542x over previous
//
#include <hip/hip_runtime.h>
#include <hip/hip_bf16.h>
#include <cmath>

#define DEVFN __device__ __forceinline__

constexpr int HW = 16384;                      // 128*128
constexpr long long U = 16777216LL;            // 8*128*16384 floats (one full tensor)

typedef __attribute__((ext_vector_type(8))) short bf16x8;
typedef __attribute__((ext_vector_type(4))) float f32x4;

// ---- workspace layout (floats). TWO big buffers in d_ws + d_out as third. ~130 MB ws. ----
constexpr long long OFF_X1   = 0;
constexpr long long OFF_QS   = U/2;
constexpr long long OFF_KK   = 3*U/4;
constexpr long long OFF_X2O  = U/2;
constexpr long long OFF_V    = U;
constexpr long long OFF_LF   = U + U/4;
constexpr long long OFF_QP   = U + U/2;
constexpr long long OFF_KP   = U + U/2 + 1048576;
constexpr long long OFF_TA   = 0;
constexpr long long OFF_TB   = U;
constexpr long long OFF_CTX  = U;
constexpr long long OFF_ATTP = 0;
constexpr long long OFF_QX   = 0;
constexpr long long OFF_FREQ = U;
constexpr long long OFF_LOW  = 0;
constexpr long long OFF_HIGH = U;
constexpr long long OFF_F    = 0;
constexpr long long S0       = 2*U;
constexpr long long OFF_QKB  = S0;             // 8192
constexpr long long OFF_AA   = S0 + 8192;      // 8192
constexpr long long OFF_MQ   = S0 + 16384;     // 1024
constexpr long long OFF_DQ   = S0 + 17408;     // 1024
constexpr long long OFF_PMAX = S0 + 18432;     // 131072 (reused for bf16 weight packs later)
constexpr long long OFF_PSUM = S0 + 149504;    // 131072
constexpr long long OFF_MC   = S0 + 280576;    // 1024
constexpr long long OFF_DC   = S0 + 281600;    // 1024
constexpr long long OFF_ATT  = S0 + 282624;    // 131072
constexpr long long OFF_BNP  = S0 + 413696;    // 16384
constexpr long long OFF_SSL  = S0 + 430080;    // 256
constexpr long long OFF_SSH  = S0 + 430336;
constexpr long long OFF_SSY  = S0 + 430592;
constexpr long long OFF_DV   = S0 + 430848;    // 2048
constexpr long long OFF_D0   = S0 + 432896;    // 1024
constexpr long long OFF_D1   = S0 + 433920;    // 1024
// bf16 weight packs alias pmax/psum (dead after qx stats): 3 * 73728 floats = 221184 <= 262144
constexpr long long OFF_WLOW  = OFF_PMAX;            // 147456 bf16 = 73728 floats
constexpr long long OFF_WHIGH = OFF_PMAX + 73728;
constexpr long long OFF_WOUT  = OFF_PMAX + 147456;

struct Taps { float g[7]; };

DEVFN float gelu_f(float v) { return 0.5f * v * (1.0f + erff(v * 0.7071067811865475f)); }
DEVFN unsigned short f2b(float f) {  // RNE f32->bf16
  unsigned u = __float_as_uint(f);
  unsigned r = u + 0x7fffu + ((u >> 16) & 1u);
  return (unsigned short)(r >> 16);
}

// ---------------- depthwise 3x3 + gelu on even channels ----------------
__global__ __launch_bounds__(256) void k_dwconv(const float* __restrict__ x, const float* __restrict__ w9,
                                                const float* __restrict__ bia, float* __restrict__ out) {
  int g = blockIdx.x * 256 + threadIdx.x;        // 8*64*16384
  int w = g & 127, h = (g >> 7) & 127, c = (g >> 14) & 63, n = g >> 20;
  const float* src = x + (long long)(n * 128 + 2 * c) * HW;
  float acc = bia[c];
  #pragma unroll
  for (int ky = 0; ky < 3; ++ky) {
    int h2 = h + ky - 1;
    if ((unsigned)h2 < 128u) {
      #pragma unroll
      for (int kx = 0; kx < 3; ++kx) {
        int w2 = w + kx - 1;
        if ((unsigned)w2 < 128u) acc = fmaf(w9[c * 9 + ky * 3 + kx], src[h2 * 128 + w2], acc);
      }
    }
  }
  out[(long long)(n * 64 + c) * HW + h * 128 + w] = gelu_f(acc);
}

// ---------------- qkvl 1x1 conv (64->160) + gelu, fused head routing ----------------
__global__ __launch_bounds__(256) void k_qkvl(const float* __restrict__ x, const float* __restrict__ wq,
                                              const float* __restrict__ bq, float* __restrict__ qs,
                                              float* __restrict__ kk, float* __restrict__ vv,
                                              float* __restrict__ lf) {
  __shared__ float lw[160 * 64];
  __shared__ float lb[160];
  int t = threadIdx.x;
  for (int e = t; e < 160 * 64; e += 256) lw[e] = wq[e];
  for (int e = t; e < 160; e += 256) lb[e] = bq[e];
  __syncthreads();
  int g = blockIdx.x * 256 + t;   // 131072
  int n = g >> 14, p = g & 16383;
  float xin[64];
  #pragma unroll
  for (int ci = 0; ci < 64; ++ci) xin[ci] = x[(long long)(n * 128 + 2 * ci + 1) * HW + p];
  for (int j = 0; j < 32; ++j) {
    float d0 = lb[j], d1 = lb[32 + j], d2 = lb[64 + j], d3 = lb[96 + j], d4 = lb[128 + j];
    #pragma unroll
    for (int ci = 0; ci < 64; ++ci) {
      float xv = xin[ci];
      d0 = fmaf(lw[j * 64 + ci], xv, d0);
      d1 = fmaf(lw[(32 + j) * 64 + ci], xv, d1);
      d2 = fmaf(lw[(64 + j) * 64 + ci], xv, d2);
      d3 = fmaf(lw[(96 + j) * 64 + ci], xv, d3);
      d4 = fmaf(lw[(128 + j) * 64 + ci], xv, d4);
    }
    long long o = (long long)(n * 32 + j) * HW + p;
    qs[o] = gelu_f(d0) + gelu_f(d1);
    kk[o] = gelu_f(d2);
    vv[o] = gelu_f(d3);
    lf[o] = gelu_f(d4);
  }
}

// ---------------- pools ----------------
__global__ __launch_bounds__(256) void k_avgpool(const float* __restrict__ in, float* __restrict__ out) {
  int g = blockIdx.x * 256 + threadIdx.x;   // 8*32*4096
  int ow = g & 63, oh = (g >> 6) & 63, c = (g >> 12) & 31, n = g >> 17;
  const float* src = in + (long long)(n * 32 + c) * HW;
  float s = 0.f;
  #pragma unroll
  for (int i = 0; i < 3; ++i) {
    int h = oh * 2 - 1 + i;
    if ((unsigned)h < 128u) {
      #pragma unroll
      for (int j = 0; j < 3; ++j) {
        int w = ow * 2 - 1 + j;
        if ((unsigned)w < 128u) s += src[h * 128 + w];
      }
    }
  }
  out[(long long)(n * 32 + c) * 4096 + oh * 64 + ow] = s * (1.f / 9.f);
}

__global__ __launch_bounds__(256) void k_maxpool(const float* __restrict__ in, float* __restrict__ out) {
  int g = blockIdx.x * 256 + threadIdx.x;
  int ow = g & 63, oh = (g >> 6) & 63, c = (g >> 12) & 31, n = g >> 17;
  const float* src = in + (long long)(n * 32 + c) * HW;
  float m = -3.0e38f;
  #pragma unroll
  for (int i = 0; i < 2; ++i)
    #pragma unroll
    for (int j = 0; j < 2; ++j)
      m = fmaxf(m, src[(oh * 2 + i) * 128 + ow * 2 + j]);
  out[(long long)(n * 32 + c) * 4096 + oh * 64 + ow] = m;
}

// ---------------- qk (32x32 per n, K=4096) ----------------
__global__ __launch_bounds__(256) void k_qk(const float* __restrict__ qp, const float* __restrict__ kp,
                                            float* __restrict__ qk) {
  int c = blockIdx.x, n = blockIdx.y;
  int t = threadIdx.x, d = t >> 3, r = t & 7;
  const float* qr = qp + (long long)(n * 32 + c) * 4096;
  const float* kr = kp + (long long)(n * 32 + d) * 4096;
  float acc = 0.f;
  for (int p = r; p < 4096; p += 8) acc = fmaf(qr[p], kr[p], acc);
  acc += __shfl_down(acc, 4, 8);
  acc += __shfl_down(acc, 2, 8);
  acc += __shfl_down(acc, 1, 8);
  if (r == 0) qk[(n * 32 + c) * 32 + d] = acc;
}

__global__ void k_qksm(const float* __restrict__ qk, float* __restrict__ A) {
  int n = blockIdx.x, d = threadIdx.x;   // block 32
  float m = -3.0e38f;
  for (int c = 0; c < 32; ++c) m = fmaxf(m, qk[(n * 32 + c) * 32 + d]);
  float s = 0.f;
  for (int c = 0; c < 32; ++c) s += expf(qk[(n * 32 + c) * 32 + d] - m);
  float inv = 1.f / s;
  for (int c = 0; c < 32; ++c) A[(n * 32 + c) * 32 + d] = expf(qk[(n * 32 + c) * 32 + d] - m) * inv;
}

// ---------------- x2o = A^T @ v ----------------
__global__ __launch_bounds__(256) void k_x2o(const float* __restrict__ A, const float* __restrict__ vsrc,
                                             float* __restrict__ out) {
  __shared__ float lA[1024];
  int t = threadIdx.x;
  int g = blockIdx.x * 256 + t;
  int n = g >> 14, p = g & 16383;
  for (int e = t; e < 1024; e += 256) lA[e] = A[n * 1024 + e];
  __syncthreads();
  float acc[32];
  #pragma unroll
  for (int i = 0; i < 32; ++i) acc[i] = 0.f;
  for (int q = 0; q < 32; ++q) {
    float vv = vsrc[(long long)(n * 32 + q) * HW + p];
    #pragma unroll
    for (int k2 = 0; k2 < 32; ++k2) acc[k2] = fmaf(lA[q * 32 + k2], vv, acc[k2]);
  }
  #pragma unroll
  for (int k2 = 0; k2 < 32; ++k2) out[(long long)(n * 32 + k2) * HW + p] = acc[k2];
}

// ---------------- generic 128x128x128 1x1-conv / attention GEMM ----------------
enum { M_EFF = 0, M_QX = 1, M_OUT = 2, M_FREQ = 3 };

template <int MODE>
__global__ __launch_bounds__(256) void k_gemm1x1(
    const float* __restrict__ Amat, const float* __restrict__ B0, const float* __restrict__ B1,
    const float* __restrict__ B2, const float* __restrict__ bias, const float* __restrict__ scale,
    const float* __restrict__ Mq, const float* __restrict__ invDq, const float* __restrict__ xres,
    float* __restrict__ outp) {
  __shared__ float As[32 * 129];
  __shared__ float Bs[32 * 129];
  const int t = threadIdx.x;
  const int bx = blockIdx.x, n = blockIdx.y;
  const int pxb = bx * 128;
  const int ty = t >> 4, tx = t & 15;
  const int ch0 = ty * 8, px0 = tx * 8;
  float acc[8][8];
  #pragma unroll
  for (int i = 0; i < 8; ++i)
    #pragma unroll
    for (int j = 0; j < 8; ++j) acc[i][j] = 0.f;

  for (int kc = 0; kc < 4; ++kc) {
    __syncthreads();
    if (MODE == M_FREQ) {
      #pragma unroll
      for (int it = 0; it < 16; ++it) {
        int e = it * 256 + t; int jj = e >> 7; int ch = e & 127;
        As[jj * 129 + ch] = Amat[(long long)(n * 128 + kc * 32 + jj) * 128 + ch];
      }
      #pragma unroll
      for (int it = 0; it < 16; ++it) {
        int ww = it * 8 + (t >> 5); int jj = t & 31; int j = kc * 32 + jj;
        float v = B0[(long long)(n * HW + pxb + ww) * 128 + j];
        Bs[jj * 129 + ww] = expf(v - Mq[n * 128 + j]) * invDq[n * 128 + j];
      }
    } else {
      #pragma unroll
      for (int it = 0; it < 16; ++it) {
        int e = it * 256 + t; int co = e >> 5; int kk = e & 31;
        As[kk * 129 + co] = Amat[co * 128 + kc * 32 + kk];
      }
      #pragma unroll
      for (int it = 0; it < 16; ++it) {
        int e = it * 256 + t; int kk = e >> 7; int px = e & 127;
        int ci = kc * 32 + kk;
        float v;
        if (MODE == M_EFF) {
          if (ci < 64)      v = B0[(long long)(n * 64 + ci) * HW + pxb + px];
          else if (ci < 96) v = B1[(long long)(n * 32 + ci - 64) * HW + pxb + px];
          else              v = B2[(long long)(n * 32 + ci - 96) * HW + pxb + px];
        } else if (MODE == M_QX) {
          v = B0[(long long)(n * 128 + ci) * HW + pxb + px];
        } else {  // M_OUT
          float u = B0[(long long)(n * 128 + ci) * HW + pxb + px];
          v = fmaxf(fmaf(u, scale[ci], scale[128 + ci]), 0.f);
        }
        Bs[kk * 129 + px] = v;
      }
    }
    __syncthreads();
    #pragma unroll 4
    for (int kk = 0; kk < 32; ++kk) {
      float a_[8], b_[8];
      #pragma unroll
      for (int i = 0; i < 8; ++i) a_[i] = As[kk * 129 + ch0 + i];
      #pragma unroll
      for (int j = 0; j < 8; ++j) b_[j] = Bs[kk * 129 + px0 + j];
      #pragma unroll
      for (int i = 0; i < 8; ++i)
        #pragma unroll
        for (int j = 0; j < 8; ++j) acc[i][j] = fmaf(a_[i], b_[j], acc[i][j]);
    }
  }
  #pragma unroll
  for (int i = 0; i < 8; ++i) {
    int ch = ch0 + i;
    long long ob = (long long)(n * 128 + ch) * HW + pxb + px0;
    float badd = (MODE == M_FREQ) ? 0.f : bias[ch];
    #pragma unroll
    for (int j = 0; j < 8; ++j) {
      float v = acc[i][j] + badd;
      if (MODE == M_FREQ) v += xres[ob + j];
      outp[ob + j] = v;
    }
  }
}

// ---------------- qx softmax stats (over (c,h) per (n,w)) ----------------
__global__ __launch_bounds__(128) void k_qx_pmax(const float* __restrict__ qx, float* __restrict__ pmax) {
  int c = blockIdx.x, n = blockIdx.y, w = threadIdx.x;
  long long base = (long long)(n * 128 + c) * HW + w;
  float m = -3.0e38f;
  for (int h = 0; h < 128; ++h) m = fmaxf(m, qx[base + h * 128]);
  pmax[(n * 128 + c) * 128 + w] = m;
}
__global__ __launch_bounds__(128) void k_qx_rmax(const float* __restrict__ pmax, float* __restrict__ Mq) {
  int n = blockIdx.x, w = threadIdx.x;
  float m = -3.0e38f;
  for (int c = 0; c < 128; ++c) m = fmaxf(m, pmax[(n * 128 + c) * 128 + w]);
  Mq[n * 128 + w] = m;
}
__global__ __launch_bounds__(128) void k_qx_psum(const float* __restrict__ qx, const float* __restrict__ Mq,
                                                 float* __restrict__ psum) {
  int c = blockIdx.x, n = blockIdx.y, w = threadIdx.x;
  float M = Mq[n * 128 + w];
  long long base = (long long)(n * 128 + c) * HW + w;
  float s = 0.f;
  for (int h = 0; h < 128; ++h) s += expf(qx[base + h * 128] - M);
  psum[(n * 128 + c) * 128 + w] = s;
}
__global__ __launch_bounds__(128) void k_qx_rsum(const float* __restrict__ psum, float* __restrict__ invDq) {
  int n = blockIdx.x, w = threadIdx.x;
  float s = 0.f;
  for (int c = 0; c < 128; ++c) s += psum[(n * 128 + c) * 128 + w];
  invDq[n * 128 + w] = 1.f / s;
}

// ---------------- separable gaussian blurs ----------------
template <int R>
__global__ __launch_bounds__(256) void k_hblur(const float* __restrict__ in, float* __restrict__ out, Taps tp) {
  int g = blockIdx.x * 256 + threadIdx.x;
  int w = g & 127;
  float s = 0.f;
  #pragma unroll
  for (int d = -R; d <= R; ++d) {
    int wd = w + d;
    if (0 <= wd && wd < 128) s = fmaf(tp.g[d + R], in[g + d], s);
  }
  out[g] = s;
}
template <int R, bool SUB>
__global__ __launch_bounds__(256) void k_vblur(const float* __restrict__ in, const float* __restrict__ xr,
                                               float* __restrict__ out, Taps tp) {
  int g = blockIdx.x * 256 + threadIdx.x;
  int h = (g >> 7) & 127;
  float s = 0.f;
  #pragma unroll
  for (int d = -R; d <= R; ++d) {
    int hd = h + d;
    if (0 <= hd && hd < 128) s = fmaf(tp.g[d + R], in[g + d * 128], s);
  }
  out[g] = SUB ? (xr[g] - s) : s;
}

// ---------------- ctx softmax stats (over p per (n,c)) ----------------
__global__ __launch_bounds__(256) void k_ctx_stats(const float* __restrict__ ctx, float* __restrict__ Mc,
                                                   float* __restrict__ invDc) {
  int c = blockIdx.x, n = blockIdx.y, t = threadIdx.x;
  long long base = (long long)(n * 128 + c) * HW;
  __shared__ float red[256];
  float m = -3.0e38f;
  for (int i = t; i < HW; i += 256) m = fmaxf(m, ctx[base + i]);
  red[t] = m; __syncthreads();
  for (int o = 128; o > 0; o >>= 1) { if (t < o) red[t] = fmaxf(red[t], red[t + o]); __syncthreads(); }
  m = red[0]; __syncthreads();
  float s = 0.f;
  for (int i = t; i < HW; i += 256) s += expf(ctx[base + i] - m);
  red[t] = s; __syncthreads();
  for (int o = 128; o > 0; o >>= 1) { if (t < o) red[t] += red[t + o]; __syncthreads(); }
  if (t == 0) { Mc[n * 128 + c] = m; invDc[n * 128 + c] = 1.f / red[0]; }
}

// ---------------- att = softmax(ctx) @ ctx^T (partial over p-splits) ----------------
__global__ __launch_bounds__(256) void k_att(const float* __restrict__ ctx, const float* __restrict__ Mc,
                                             const float* __restrict__ invDc, float* __restrict__ attp) {
  __shared__ float As[32 * 129];
  __shared__ float Bs[32 * 129];
  int t = threadIdx.x, sp = blockIdx.x, n = blockIdx.y;
  int ty = t >> 4, tx = t & 15;
  int c0 = ty * 8, d0 = tx * 8;
  float acc[8][8];
  #pragma unroll
  for (int i = 0; i < 8; ++i)
    #pragma unroll
    for (int j = 0; j < 8; ++j) acc[i][j] = 0.f;
  for (int kc = 0; kc < 16; ++kc) {
    __syncthreads();
    int pb = sp * 512 + kc * 32;
    #pragma unroll
    for (int it = 0; it < 16; ++it) {
      int e = it * 256 + t; int row = e >> 5; int kk = e & 31;
      float v = ctx[(long long)(n * 128 + row) * HW + pb + kk];
      Bs[kk * 129 + row] = v;
      As[kk * 129 + row] = expf(v - Mc[n * 128 + row]) * invDc[n * 128 + row];
    }
    __syncthreads();
    #pragma unroll 4
    for (int kk = 0; kk < 32; ++kk) {
      float a_[8], b_[8];
      #pragma unroll
      for (int i = 0; i < 8; ++i) a_[i] = As[kk * 129 + c0 + i];
      #pragma unroll
      for (int j = 0; j < 8; ++j) b_[j] = Bs[kk * 129 + d0 + j];
      #pragma unroll
      for (int i = 0; i < 8; ++i)
        #pragma unroll
        for (int j = 0; j < 8; ++j) acc[i][j] = fmaf(a_[i], b_[j], acc[i][j]);
    }
  }
  long long ob = ((long long)(sp * 8 + n) * 128 + c0) * 128 + d0;
  #pragma unroll
  for (int i = 0; i < 8; ++i)
    #pragma unroll
    for (int j = 0; j < 8; ++j) attp[ob + i * 128 + j] = acc[i][j];
}

__global__ __launch_bounds__(256) void k_attred(const float* __restrict__ attp, float* __restrict__ att) {
  int g = blockIdx.x * 256 + threadIdx.x;  // 131072
  float s = 0.f;
  for (int sp = 0; sp < 32; ++sp) s += attp[(long long)sp * 131072 + g];
  att[g] = s;
}

// ---------------- pack conv weight [co][ci][3][3] f32 -> bf16 [co][tap*128+ci] ----------------
__global__ __launch_bounds__(256) void k_wpack(const float* __restrict__ w, unsigned short* __restrict__ wp) {
  int g = blockIdx.x * 256 + threadIdx.x;   // 147456
  int ci = g & 127;
  int tap = (g >> 7) % 9;
  int co = g / 1152;
  wp[g] = f2b(w[co * 1152 + ci * 9 + tap]);
}

// ---------------- 3x3 conv 128->128 via bf16 MFMA implicit GEMM ----------------
// block: (h0 = blockIdx.x, n = blockIdx.y), 256 threads = 4 waves (2 co-halves x 2 px-halves)
// out[n, co, h0, w] = sum_{tap,ci} wp[co][tap*128+ci] * in[n, ci, h0+ky-1, w+kx-1]
__global__ __launch_bounds__(256) void k_conv3m(const float* __restrict__ in,
                                                const unsigned short* __restrict__ wp,
                                                float* __restrict__ out) {
  __shared__ __align__(16) unsigned short Bs[15840];   // [row 3][s=w+1 (0..129) stride 132][ci 32 pad 40]
  const int t = threadIdx.x;
  const int h0 = blockIdx.x, n = blockIdx.y;
  const int wid = t >> 6, lane = t & 63;
  const int wy = wid >> 1, wx = wid & 1;     // wy: co half, wx: px half
  const int l15 = lane & 15, l4 = lane >> 4;
  f32x4 acc[4][4];
  #pragma unroll
  for (int i = 0; i < 4; ++i)
    #pragma unroll
    for (int j = 0; j < 4; ++j) { f32x4 z = {0.f, 0.f, 0.f, 0.f}; acc[i][j] = z; }
  const float* src = in + (long long)n * 128 * HW;
  const unsigned short* arow = wp + (wy * 64 + l15) * 1152 + l4 * 8;

  for (int kc = 0; kc < 4; ++kc) {
    __syncthreads();
    for (int e = t; e < 12480; e += 256) {
      int rc = e / 130, s = e - rc * 130;    // rc = r*32+ci, s = w+1
      int r = rc >> 5, ci = rc & 31;
      int h = h0 - 1 + r, w = s - 1;
      float v = 0.f;
      if ((unsigned)h < 128u && (unsigned)w < 128u)
        v = src[(long long)(kc * 32 + ci) * HW + h * 128 + w];
      Bs[(r * 132 + s) * 40 + ci] = f2b(v);
    }
    __syncthreads();
    #pragma unroll
    for (int ky = 0; ky < 3; ++ky) {
      #pragma unroll
      for (int kx = 0; kx < 3; ++kx) {
        const int tap = ky * 3 + kx;
        bf16x8 af[4], bfr[4];
        #pragma unroll
        for (int cf = 0; cf < 4; ++cf)
          af[cf] = *(const bf16x8*)(arow + (cf * 16) * 1152 + tap * 128 + kc * 32);
        #pragma unroll
        for (int pf = 0; pf < 4; ++pf)
          bfr[pf] = *(const bf16x8*)(&Bs[(ky * 132 + wx * 64 + pf * 16 + l15 + kx) * 40 + l4 * 8]);
        #pragma unroll
        for (int cf = 0; cf < 4; ++cf)
          #pragma unroll
          for (int pf = 0; pf < 4; ++pf)
            acc[cf][pf] = __builtin_amdgcn_mfma_f32_16x16x32_bf16(af[cf], bfr[pf], acc[cf][pf], 0, 0, 0);
      }
    }
  }
  long long ob = (long long)n * 128 * HW + h0 * 128;
  #pragma unroll
  for (int cf = 0; cf < 4; ++cf)
    #pragma unroll
    for (int pf = 0; pf < 4; ++pf) {
      int co = wy * 64 + cf * 16 + l4 * 4;
      int w  = wx * 64 + pf * 16 + l15;
      #pragma unroll
      for (int r = 0; r < 4; ++r)
        out[ob + (long long)(co + r) * HW + w] = acc[cf][pf][r];
    }
}

// ---------------- BN batch stats ----------------
__global__ __launch_bounds__(256) void k_bnpart(const float* __restrict__ in, float* __restrict__ part) {
  int c = blockIdx.x, b = blockIdx.y, t = threadIdx.x;
  int n = b >> 3, seg = b & 7;
  long long base = (long long)(n * 128 + c) * HW + seg * 2048;
  float s = 0.f, ss = 0.f;
  for (int i = t; i < 2048; i += 256) { float v = in[base + i]; s += v; ss = fmaf(v, v, ss); }
  __shared__ float r1[256], r2[256];
  r1[t] = s; r2[t] = ss; __syncthreads();
  for (int o = 128; o > 0; o >>= 1) { if (t < o) { r1[t] += r1[t + o]; r2[t] += r2[t + o]; } __syncthreads(); }
  if (t == 0) { part[(c * 64 + b) * 2] = r1[0]; part[(c * 64 + b) * 2 + 1] = r2[0]; }
}
__global__ __launch_bounds__(64) void k_bnfin(const float* __restrict__ part, const float* __restrict__ g,
                                              const float* __restrict__ bb, float* __restrict__ ssout) {
  int c = blockIdx.x, t = threadIdx.x;
  float s = part[(c * 64 + t) * 2], ss = part[(c * 64 + t) * 2 + 1];
  for (int o = 32; o > 0; o >>= 1) { s += __shfl_down(s, o, 64); ss += __shfl_down(ss, o, 64); }
  if (t == 0) {
    float mean = s / 131072.f;
    float var = ss / 131072.f - mean * mean;
    float sc = g[c] * rsqrtf(var + 1e-5f);
    ssout[c] = sc;
    ssout[128 + c] = bb[c] - mean * sc;
  }
}

// ---------------- cubic power-mean per (n,c) ----------------
__global__ __launch_bounds__(256) void k_power(const float* __restrict__ in, const float* __restrict__ ss,
                                               float* __restrict__ dst, int off) {
  int c = blockIdx.x, n = blockIdx.y, t = threadIdx.x;
  float sc = ss[c], sh = ss[128 + c];
  long long base = (long long)(n * 128 + c) * HW;
  float s = 0.f;
  for (int i = t; i < HW; i += 256) {
    float r = fmaxf(fmaf(in[base + i], sc, sh), 0.f);
    s += r * r * r;
  }
  __shared__ float red[256];
  red[t] = s; __syncthreads();
  for (int o = 128; o > 0; o >>= 1) { if (t < o) red[t] += red[t + o]; __syncthreads(); }
  if (t == 0) dst[n * 256 + 2 * c + off] = cbrtf(red[0] * (1.f / 16384.f) + 1e-12f);
}

// ---------------- 1d conv x2 + sigmoid ----------------
__global__ __launch_bounds__(256) void k_dvec(const float* __restrict__ din, const float* __restrict__ c1,
                                              const float* __restrict__ c2, float* __restrict__ d0,
                                              float* __restrict__ d1) {
  __shared__ float a[256], b[256];
  int n = blockIdx.x, t = threadIdx.x;
  a[t] = din[n * 256 + t];
  __syncthreads();
  float acc = 0.f;
  #pragma unroll
  for (int k = 0; k < 5; ++k) { int j = t + k - 2; if (0 <= j && j < 256) acc = fmaf(c1[k], a[j], acc); }
  b[t] = acc; __syncthreads();
  float acc2 = 0.f;
  #pragma unroll
  for (int k = 0; k < 5; ++k) { int j = t + k - 2; if (0 <= j && j < 256) acc2 = fmaf(c2[k], b[j], acc2); }
  float sg = 1.f / (1.f + expf(-acc2));
  if ((t & 1) == 0) d0[n * 128 + (t >> 1)] = sg; else d1[n * 128 + (t >> 1)] = sg;
}

// ---------------- f = d0*relu(bn(low)) + d1*relu(bn(high)), in-place into low ----------------
__global__ __launch_bounds__(256) void k_fmix(float* __restrict__ low, const float* __restrict__ high,
                                              const float* __restrict__ ssl, const float* __restrict__ ssh,
                                              const float* __restrict__ d0, const float* __restrict__ d1) {
  int g = blockIdx.x * 256 + threadIdx.x;
  int c = (g >> 14) & 127, n = g >> 21;
  float xl = fmaxf(fmaf(low[g], ssl[c], ssl[128 + c]), 0.f);
  float xh = fmaxf(fmaf(high[g], ssh[c], ssh[128 + c]), 0.f);
  low[g] = d0[n * 128 + c] * xl + d1[n * 128 + c] * xh;
}

static void make_taps(int ks, double sigma, Taps* tp) {
  double c = (ks - 1) / 2.0, sum = 0.0, v[7];
  for (int i = 0; i < ks; ++i) { double d = i - c; v[i] = std::exp(-d * d / (2.0 * sigma * sigma)); sum += v[i]; }
  for (int i = 0; i < 7; ++i) tp->g[i] = (i < ks) ? (float)(v[i] / sum) : 0.f;
}

extern "C" void kernel_launch(void* const* d_in, const int* in_sizes, int n_in,
                              void* d_out, int out_size, void* d_ws, size_t ws_size,
                              hipStream_t stream) {
  const float* x         = (const float*)d_in[0];
  const float* dwconv_w  = (const float*)d_in[1];
  const float* dwconv_b  = (const float*)d_in[2];
  const float* qkvl_w    = (const float*)d_in[3];
  const float* qkvl_b    = (const float*)d_in[4];
  const float* reproj_w  = (const float*)d_in[5];
  const float* reproj_b  = (const float*)d_in[6];
  const float* queries_w = (const float*)d_in[7];
  const float* queries_b = (const float*)d_in[8];
  const float* sff_low_w = (const float*)d_in[9];
  const float* sff_low_g = (const float*)d_in[10];
  const float* sff_low_b = (const float*)d_in[11];
  const float* sff_high_w= (const float*)d_in[12];
  const float* sff_high_g= (const float*)d_in[13];
  const float* sff_high_b= (const float*)d_in[14];
  const float* sff_c1_w  = (const float*)d_in[15];
  const float* sff_c2_w  = (const float*)d_in[16];
  const float* out_conv_w= (const float*)d_in[17];
  const float* out_bn_g  = (const float*)d_in[18];
  const float* out_bn_b  = (const float*)d_in[19];
  const float* out_proj_w= (const float*)d_in[20];
  const float* out_proj_b= (const float*)d_in[21];
  float* ws  = (float*)d_ws;
  float* out = (float*)d_out;

  float* x1   = ws + OFF_X1;
  float* qs   = ws + OFF_QS;
  float* kk   = ws + OFF_KK;
  float* x2o  = ws + OFF_X2O;
  float* vv   = ws + OFF_V;
  float* lf   = ws + OFF_LF;
  float* qp   = ws + OFF_QP;
  float* kp   = ws + OFF_KP;
  float* eff  = out;            // d_out doubles as eff, then ybuf, then final out
  float* tA   = ws + OFF_TA;
  float* tB   = ws + OFF_TB;
  float* ctx  = ws + OFF_CTX;
  float* attp = ws + OFF_ATTP;
  float* qx   = ws + OFF_QX;
  float* freq = ws + OFF_FREQ;
  float* lowc = ws + OFF_LOW;
  float* highc= ws + OFF_HIGH;
  float* fbuf = ws + OFF_F;     // == lowc (in-place)
  float* ybuf = out;
  float* qkb  = ws + OFF_QKB;
  float* Abuf = ws + OFF_AA;
  float* Mq   = ws + OFF_MQ;
  float* Dq   = ws + OFF_DQ;
  float* pmax = ws + OFF_PMAX;
  float* psum = ws + OFF_PSUM;
  float* Mc   = ws + OFF_MC;
  float* Dc   = ws + OFF_DC;
  float* att  = ws + OFF_ATT;
  float* bnp  = ws + OFF_BNP;
  float* ssl  = ws + OFF_SSL;
  float* ssh  = ws + OFF_SSH;
  float* ssy  = ws + OFF_SSY;
  float* dv   = ws + OFF_DV;
  float* d0v  = ws + OFF_D0;
  float* d1v  = ws + OFF_D1;
  unsigned short* wlow  = (unsigned short*)(ws + OFF_WLOW);
  unsigned short* whigh = (unsigned short*)(ws + OFF_WHIGH);
  unsigned short* wout  = (unsigned short*)(ws + OFF_WOUT);

  Taps t3, t5, t7;
  const double s3 = std::pow(2.0, 1.0 / 3.0);
  make_taps(3, 1.6, &t3);
  make_taps(5, 1.6 * s3, &t5);
  make_taps(7, 1.6 * s3 * s3, &t7);

  dim3 b256(256), b128(128);

  // ---- phase 1: eff (into d_out) ----
  k_dwconv<<<dim3(32768), b256, 0, stream>>>(x, dwconv_w, dwconv_b, x1);
  k_qkvl<<<dim3(512), b256, 0, stream>>>(x, qkvl_w, qkvl_b, qs, kk, vv, lf);
  k_avgpool<<<dim3(4096), b256, 0, stream>>>(qs, qp);
  k_maxpool<<<dim3(4096), b256, 0, stream>>>(kk, kp);
  k_qk<<<dim3(32, 8), b256, 0, stream>>>(qp, kp, qkb);
  k_qksm<<<dim3(8), dim3(32), 0, stream>>>(qkb, Abuf);
  k_x2o<<<dim3(512), b256, 0, stream>>>(Abuf, vv, x2o);
  k_gemm1x1<M_EFF><<<dim3(128, 8), b256, 0, stream>>>(reproj_w, x1, lf, x2o, reproj_b,
                                                      nullptr, nullptr, nullptr, nullptr, eff);
  // ---- phase 2: ctx / att ----
  k_hblur<1><<<dim3(65536), b256, 0, stream>>>(x, tA, t3);
  k_vblur<1, false><<<dim3(65536), b256, 0, stream>>>(tA, nullptr, tB, t3);
  k_hblur<2><<<dim3(65536), b256, 0, stream>>>(tB, tA, t5);
  k_vblur<2, false><<<dim3(65536), b256, 0, stream>>>(tA, nullptr, tB, t5);
  k_hblur<3><<<dim3(65536), b256, 0, stream>>>(tB, tA, t7);
  k_vblur<3, true><<<dim3(65536), b256, 0, stream>>>(tA, x, ctx, t7);
  k_ctx_stats<<<dim3(128, 8), b256, 0, stream>>>(ctx, Mc, Dc);
  k_att<<<dim3(32, 8), b256, 0, stream>>>(ctx, Mc, Dc, attp);
  k_attred<<<dim3(512), b256, 0, stream>>>(attp, att);
  // ---- phase 3: qx -> freq ----
  k_gemm1x1<M_QX><<<dim3(128, 8), b256, 0, stream>>>(queries_w, x, nullptr, nullptr, queries_b,
                                                     nullptr, nullptr, nullptr, nullptr, qx);
  k_qx_pmax<<<dim3(128, 8), b128, 0, stream>>>(qx, pmax);
  k_qx_rmax<<<dim3(8), b128, 0, stream>>>(pmax, Mq);
  k_qx_psum<<<dim3(128, 8), b128, 0, stream>>>(qx, Mq, psum);
  k_qx_rsum<<<dim3(8), b128, 0, stream>>>(psum, Dq);
  // pack conv weights to bf16 (pmax/psum now dead; packs alias that region)
  k_wpack<<<dim3(576), b256, 0, stream>>>(sff_low_w, wlow);
  k_wpack<<<dim3(576), b256, 0, stream>>>(sff_high_w, whigh);
  k_wpack<<<dim3(576), b256, 0, stream>>>(out_conv_w, wout);
  k_gemm1x1<M_FREQ><<<dim3(128, 8), b256, 0, stream>>>(att, qx, nullptr, nullptr, nullptr,
                                                       nullptr, Mq, Dq, x, freq);
  // ---- phase 4: convs / BN / mix / out ----
  k_conv3m<<<dim3(128, 8), b256, 0, stream>>>(freq, wlow, lowc);
  k_conv3m<<<dim3(128, 8), b256, 0, stream>>>(eff, whigh, highc);
  k_bnpart<<<dim3(128, 64), b256, 0, stream>>>(lowc, bnp);
  k_bnfin<<<dim3(128), dim3(64), 0, stream>>>(bnp, sff_low_g, sff_low_b, ssl);
  k_bnpart<<<dim3(128, 64), b256, 0, stream>>>(highc, bnp);
  k_bnfin<<<dim3(128), dim3(64), 0, stream>>>(bnp, sff_high_g, sff_high_b, ssh);
  k_power<<<dim3(128, 8), b256, 0, stream>>>(lowc, ssl, dv, 0);
  k_power<<<dim3(128, 8), b256, 0, stream>>>(highc, ssh, dv, 1);
  k_dvec<<<dim3(8), b256, 0, stream>>>(dv, sff_c1_w, sff_c2_w, d0v, d1v);
  k_fmix<<<dim3(65536), b256, 0, stream>>>(lowc, highc, ssl, ssh, d0v, d1v);
  k_conv3m<<<dim3(128, 8), b256, 0, stream>>>(fbuf, wout, ybuf);
  k_bnpart<<<dim3(128, 64), b256, 0, stream>>>(ybuf, bnp);
  k_bnfin<<<dim3(128), dim3(64), 0, stream>>>(bnp, out_bn_g, out_bn_b, ssy);
  k_gemm1x1<M_OUT><<<dim3(128, 8), b256, 0, stream>>>(out_proj_w, ybuf, nullptr, nullptr, out_proj_b,
                                                      ssy, nullptr, nullptr, nullptr, out);
  (void)in_sizes; (void)n_in; (void)out_size; (void)ws_size;
}

// Round 5
// 1651.534 us; speedup vs baseline: 4.9004x; 1.2393x over previous
//
#include <hip/hip_runtime.h>
#include <hip/hip_bf16.h>
#include <cmath>

#define DEVFN __device__ __forceinline__

constexpr int HW = 16384;                      // 128*128
constexpr long long U = 16777216LL;            // 8*128*16384 floats
constexpr long long NHWC_N = 2163200LL;        // 130*130*128 ushorts per image

typedef __attribute__((ext_vector_type(8))) short bf16x8;
typedef __attribute__((ext_vector_type(4))) float f32x4;

// ---- workspace layout (floats). B1 = ws[0,U), B2 = ws[U,2U), S = ws[2U,...). ~130 MB. ----
constexpr long long OFF_X1   = 0;              // B1 front (phase 1)
constexpr long long OFF_QS   = U/2;
constexpr long long OFF_KK   = 3*U/4;
constexpr long long OFF_X2O  = U/2;            // over dead qs
constexpr long long OFF_V    = U;              // B2 front
constexpr long long OFF_LF   = U + U/4;
constexpr long long OFF_QP   = U + U/2;
constexpr long long OFF_KP   = U + U/2 + 1048576;
constexpr long long S0       = 2*U;
constexpr long long OFF_QKB  = S0;
constexpr long long OFF_AA   = S0 + 8192;
constexpr long long OFF_MQ   = S0 + 16384;
constexpr long long OFF_DQ   = S0 + 17408;
constexpr long long OFF_PMAX = S0 + 18432;     // 131072 (later: bf16 weight packs)
constexpr long long OFF_PSUM = S0 + 149504;    // 131072
constexpr long long OFF_MC   = S0 + 280576;
constexpr long long OFF_DC   = S0 + 281600;
constexpr long long OFF_ATT  = S0 + 282624;    // 131072
constexpr long long OFF_BNP  = S0 + 413696;    // 16384
constexpr long long OFF_SSL  = S0 + 430080;
constexpr long long OFF_SSH  = S0 + 430336;
constexpr long long OFF_SSY  = S0 + 430592;
constexpr long long OFF_DV   = S0 + 430848;
constexpr long long OFF_D0   = S0 + 432896;
constexpr long long OFF_D1   = S0 + 433920;
constexpr long long OFF_WLOW  = OFF_PMAX;            // 3 packs of 73728 floats (bf16)
constexpr long long OFF_WHIGH = OFF_PMAX + 73728;
constexpr long long OFF_WOUT  = OFF_PMAX + 147456;

struct Taps { float g[7]; };

DEVFN float gelu_f(float v) { return 0.5f * v * (1.0f + erff(v * 0.7071067811865475f)); }
DEVFN unsigned short f2b(float f) {  // RNE f32->bf16
  unsigned u = __float_as_uint(f);
  unsigned r = u + 0x7fffu + ((u >> 16) & 1u);
  return (unsigned short)(r >> 16);
}

// ---------------- depthwise 3x3 + gelu on even channels ----------------
__global__ __launch_bounds__(256) void k_dwconv(const float* __restrict__ x, const float* __restrict__ w9,
                                                const float* __restrict__ bia, float* __restrict__ out) {
  int g = blockIdx.x * 256 + threadIdx.x;
  int w = g & 127, h = (g >> 7) & 127, c = (g >> 14) & 63, n = g >> 20;
  const float* src = x + (long long)(n * 128 + 2 * c) * HW;
  float acc = bia[c];
  #pragma unroll
  for (int ky = 0; ky < 3; ++ky) {
    int h2 = h + ky - 1;
    if ((unsigned)h2 < 128u) {
      #pragma unroll
      for (int kx = 0; kx < 3; ++kx) {
        int w2 = w + kx - 1;
        if ((unsigned)w2 < 128u) acc = fmaf(w9[c * 9 + ky * 3 + kx], src[h2 * 128 + w2], acc);
      }
    }
  }
  out[(long long)(n * 64 + c) * HW + h * 128 + w] = gelu_f(acc);
}

// ---------------- qkvl 1x1 conv (64->160) + gelu, fused head routing ----------------
__global__ __launch_bounds__(256) void k_qkvl(const float* __restrict__ x, const float* __restrict__ wq,
                                              const float* __restrict__ bq, float* __restrict__ qs,
                                              float* __restrict__ kk, float* __restrict__ vv,
                                              float* __restrict__ lf) {
  __shared__ float lw[160 * 64];
  __shared__ float lb[160];
  int t = threadIdx.x;
  for (int e = t; e < 160 * 64; e += 256) lw[e] = wq[e];
  for (int e = t; e < 160; e += 256) lb[e] = bq[e];
  __syncthreads();
  int g = blockIdx.x * 256 + t;
  int n = g >> 14, p = g & 16383;
  float xin[64];
  #pragma unroll
  for (int ci = 0; ci < 64; ++ci) xin[ci] = x[(long long)(n * 128 + 2 * ci + 1) * HW + p];
  for (int j = 0; j < 32; ++j) {
    float d0 = lb[j], d1 = lb[32 + j], d2 = lb[64 + j], d3 = lb[96 + j], d4 = lb[128 + j];
    #pragma unroll
    for (int ci = 0; ci < 64; ++ci) {
      float xv = xin[ci];
      d0 = fmaf(lw[j * 64 + ci], xv, d0);
      d1 = fmaf(lw[(32 + j) * 64 + ci], xv, d1);
      d2 = fmaf(lw[(64 + j) * 64 + ci], xv, d2);
      d3 = fmaf(lw[(96 + j) * 64 + ci], xv, d3);
      d4 = fmaf(lw[(128 + j) * 64 + ci], xv, d4);
    }
    long long o = (long long)(n * 32 + j) * HW + p;
    qs[o] = gelu_f(d0) + gelu_f(d1);
    kk[o] = gelu_f(d2);
    vv[o] = gelu_f(d3);
    lf[o] = gelu_f(d4);
  }
}

// ---------------- pools ----------------
__global__ __launch_bounds__(256) void k_avgpool(const float* __restrict__ in, float* __restrict__ out) {
  int g = blockIdx.x * 256 + threadIdx.x;
  int ow = g & 63, oh = (g >> 6) & 63, c = (g >> 12) & 31, n = g >> 17;
  const float* src = in + (long long)(n * 32 + c) * HW;
  float s = 0.f;
  #pragma unroll
  for (int i = 0; i < 3; ++i) {
    int h = oh * 2 - 1 + i;
    if ((unsigned)h < 128u) {
      #pragma unroll
      for (int j = 0; j < 3; ++j) {
        int w = ow * 2 - 1 + j;
        if ((unsigned)w < 128u) s += src[h * 128 + w];
      }
    }
  }
  out[(long long)(n * 32 + c) * 4096 + oh * 64 + ow] = s * (1.f / 9.f);
}

__global__ __launch_bounds__(256) void k_maxpool(const float* __restrict__ in, float* __restrict__ out) {
  int g = blockIdx.x * 256 + threadIdx.x;
  int ow = g & 63, oh = (g >> 6) & 63, c = (g >> 12) & 31, n = g >> 17;
  const float* src = in + (long long)(n * 32 + c) * HW;
  float m = -3.0e38f;
  #pragma unroll
  for (int i = 0; i < 2; ++i)
    #pragma unroll
    for (int j = 0; j < 2; ++j)
      m = fmaxf(m, src[(oh * 2 + i) * 128 + ow * 2 + j]);
  out[(long long)(n * 32 + c) * 4096 + oh * 64 + ow] = m;
}

// ---------------- qk (32x32 per n, K=4096) ----------------
__global__ __launch_bounds__(256) void k_qk(const float* __restrict__ qp, const float* __restrict__ kp,
                                            float* __restrict__ qk) {
  int c = blockIdx.x, n = blockIdx.y;
  int t = threadIdx.x, d = t >> 3, r = t & 7;
  const float* qr = qp + (long long)(n * 32 + c) * 4096;
  const float* kr = kp + (long long)(n * 32 + d) * 4096;
  float acc = 0.f;
  for (int p = r; p < 4096; p += 8) acc = fmaf(qr[p], kr[p], acc);
  acc += __shfl_down(acc, 4, 8);
  acc += __shfl_down(acc, 2, 8);
  acc += __shfl_down(acc, 1, 8);
  if (r == 0) qk[(n * 32 + c) * 32 + d] = acc;
}

__global__ void k_qksm(const float* __restrict__ qk, float* __restrict__ A) {
  int n = blockIdx.x, d = threadIdx.x;
  float m = -3.0e38f;
  for (int c = 0; c < 32; ++c) m = fmaxf(m, qk[(n * 32 + c) * 32 + d]);
  float s = 0.f;
  for (int c = 0; c < 32; ++c) s += expf(qk[(n * 32 + c) * 32 + d] - m);
  float inv = 1.f / s;
  for (int c = 0; c < 32; ++c) A[(n * 32 + c) * 32 + d] = expf(qk[(n * 32 + c) * 32 + d] - m) * inv;
}

// ---------------- x2o = A^T @ v ----------------
__global__ __launch_bounds__(256) void k_x2o(const float* __restrict__ A, const float* __restrict__ vsrc,
                                             float* __restrict__ out) {
  __shared__ float lA[1024];
  int t = threadIdx.x;
  int g = blockIdx.x * 256 + t;
  int n = g >> 14, p = g & 16383;
  for (int e = t; e < 1024; e += 256) lA[e] = A[n * 1024 + e];
  __syncthreads();
  float acc[32];
  #pragma unroll
  for (int i = 0; i < 32; ++i) acc[i] = 0.f;
  for (int q = 0; q < 32; ++q) {
    float vv = vsrc[(long long)(n * 32 + q) * HW + p];
    #pragma unroll
    for (int k2 = 0; k2 < 32; ++k2) acc[k2] = fmaf(lA[q * 32 + k2], vv, acc[k2]);
  }
  #pragma unroll
  for (int k2 = 0; k2 < 32; ++k2) out[(long long)(n * 32 + k2) * HW + p] = acc[k2];
}

// ---------------- generic 128x128x128 GEMM; M_EFF/M_FREQ emit bf16 NHWC padded ----------------
enum { M_EFF = 0, M_QX = 1, M_OUT = 2, M_FREQ = 3 };

template <int MODE>
__global__ __launch_bounds__(256) void k_gemm1x1(
    const float* __restrict__ Amat, const float* __restrict__ B0, const float* __restrict__ B1,
    const float* __restrict__ B2, const float* __restrict__ bias, const float* __restrict__ scale,
    const float* __restrict__ Mq, const float* __restrict__ invDq, const float* __restrict__ xres,
    void* __restrict__ outp) {
  __shared__ float As[32 * 129];
  __shared__ float Bs[32 * 129];
  const int t = threadIdx.x;
  const int bx = blockIdx.x, n = blockIdx.y;
  const int pxb = bx * 128;
  const int ty = t >> 4, tx = t & 15;
  const int ch0 = ty * 8, px0 = tx * 8;
  float acc[8][8];
  #pragma unroll
  for (int i = 0; i < 8; ++i)
    #pragma unroll
    for (int j = 0; j < 8; ++j) acc[i][j] = 0.f;

  for (int kc = 0; kc < 4; ++kc) {
    __syncthreads();
    if (MODE == M_FREQ) {
      #pragma unroll
      for (int it = 0; it < 16; ++it) {
        int e = it * 256 + t; int jj = e >> 7; int ch = e & 127;
        As[jj * 129 + ch] = Amat[(long long)(n * 128 + kc * 32 + jj) * 128 + ch];
      }
      #pragma unroll
      for (int it = 0; it < 16; ++it) {
        int ww = it * 8 + (t >> 5); int jj = t & 31; int j = kc * 32 + jj;
        float v = B0[(long long)(n * HW + pxb + ww) * 128 + j];
        Bs[jj * 129 + ww] = expf(v - Mq[n * 128 + j]) * invDq[n * 128 + j];
      }
    } else {
      #pragma unroll
      for (int it = 0; it < 16; ++it) {
        int e = it * 256 + t; int co = e >> 5; int kk = e & 31;
        As[kk * 129 + co] = Amat[co * 128 + kc * 32 + kk];
      }
      #pragma unroll
      for (int it = 0; it < 16; ++it) {
        int e = it * 256 + t; int kk = e >> 7; int px = e & 127;
        int ci = kc * 32 + kk;
        float v;
        if (MODE == M_EFF) {
          if (ci < 64)      v = B0[(long long)(n * 64 + ci) * HW + pxb + px];
          else if (ci < 96) v = B1[(long long)(n * 32 + ci - 64) * HW + pxb + px];
          else              v = B2[(long long)(n * 32 + ci - 96) * HW + pxb + px];
        } else if (MODE == M_QX) {
          v = B0[(long long)(n * 128 + ci) * HW + pxb + px];
        } else {  // M_OUT
          float u = B0[(long long)(n * 128 + ci) * HW + pxb + px];
          v = fmaxf(fmaf(u, scale[ci], scale[128 + ci]), 0.f);
        }
        Bs[kk * 129 + px] = v;
      }
    }
    __syncthreads();
    #pragma unroll 4
    for (int kk = 0; kk < 32; ++kk) {
      float a_[8], b_[8];
      #pragma unroll
      for (int i = 0; i < 8; ++i) a_[i] = As[kk * 129 + ch0 + i];
      #pragma unroll
      for (int j = 0; j < 8; ++j) b_[j] = Bs[kk * 129 + px0 + j];
      #pragma unroll
      for (int i = 0; i < 8; ++i)
        #pragma unroll
        for (int j = 0; j < 8; ++j) acc[i][j] = fmaf(a_[i], b_[j], acc[i][j]);
    }
  }
  if (MODE == M_EFF || MODE == M_FREQ) {
    // emit bf16 NHWC padded [n][130][130][128]
    unsigned short* oT = (unsigned short*)outp;
    #pragma unroll
    for (int j = 0; j < 8; ++j) {
      int px = pxb + px0 + j;
      int hh = px >> 7, wwp = (px & 127) + 1;
      bf16x8 pk;
      #pragma unroll
      for (int i = 0; i < 8; ++i) {
        float v = acc[i][j] + ((MODE == M_EFF) ? bias[ch0 + i] : 0.f);
        if (MODE == M_FREQ) v += xres[(long long)(n * 128 + ch0 + i) * HW + px];
        pk[i] = (short)f2b(v);
      }
      *(bf16x8*)(oT + (long long)n * NHWC_N + ((long long)(hh + 1) * 130 + wwp) * 128 + ch0) = pk;
    }
  } else {
    float* of = (float*)outp;
    #pragma unroll
    for (int i = 0; i < 8; ++i) {
      int ch = ch0 + i;
      long long ob = (long long)(n * 128 + ch) * HW + pxb + px0;
      float badd = bias[ch];
      #pragma unroll
      for (int j = 0; j < 8; ++j) of[ob + j] = acc[i][j] + badd;
    }
  }
}

// ---------------- qx softmax stats ----------------
__global__ __launch_bounds__(128) void k_qx_pmax(const float* __restrict__ qx, float* __restrict__ pmax) {
  int c = blockIdx.x, n = blockIdx.y, w = threadIdx.x;
  long long base = (long long)(n * 128 + c) * HW + w;
  float m = -3.0e38f;
  for (int h = 0; h < 128; ++h) m = fmaxf(m, qx[base + h * 128]);
  pmax[(n * 128 + c) * 128 + w] = m;
}
__global__ __launch_bounds__(128) void k_qx_rmax(const float* __restrict__ pmax, float* __restrict__ Mq) {
  int n = blockIdx.x, w = threadIdx.x;
  float m = -3.0e38f;
  for (int c = 0; c < 128; ++c) m = fmaxf(m, pmax[(n * 128 + c) * 128 + w]);
  Mq[n * 128 + w] = m;
}
__global__ __launch_bounds__(128) void k_qx_psum(const float* __restrict__ qx, const float* __restrict__ Mq,
                                                 float* __restrict__ psum) {
  int c = blockIdx.x, n = blockIdx.y, w = threadIdx.x;
  float M = Mq[n * 128 + w];
  long long base = (long long)(n * 128 + c) * HW + w;
  float s = 0.f;
  for (int h = 0; h < 128; ++h) s += expf(qx[base + h * 128] - M);
  psum[(n * 128 + c) * 128 + w] = s;
}
__global__ __launch_bounds__(128) void k_qx_rsum(const float* __restrict__ psum, float* __restrict__ invDq) {
  int n = blockIdx.x, w = threadIdx.x;
  float s = 0.f;
  for (int c = 0; c < 128; ++c) s += psum[(n * 128 + c) * 128 + w];
  invDq[n * 128 + w] = 1.f / s;
}

// ---------------- fused separable gaussian blur (h+v in one pass) ----------------
template <int R, bool SUB>
__global__ __launch_bounds__(256) void k_blur2(const float* __restrict__ in, const float* __restrict__ xr,
                                               float* __restrict__ out, Taps tp) {
  constexpr int ROWS = 16 + 2 * R;
  __shared__ float s1[ROWS * 128];
  __shared__ float s2[ROWS * 128];
  int t = threadIdx.x;
  int h0 = blockIdx.x * 16;
  long long nc = blockIdx.y;
  const float* src = in + nc * HW;
  for (int e = t; e < ROWS * 128; e += 256) {
    int r = e >> 7, w = e & 127;
    int h = h0 - R + r;
    s1[e] = ((unsigned)h < 128u) ? src[h * 128 + w] : 0.f;
    (void)w;
  }
  __syncthreads();
  for (int e = t; e < ROWS * 128; e += 256) {
    int w = e & 127;
    float s = 0.f;
    #pragma unroll
    for (int d = -R; d <= R; ++d) {
      int wd = w + d;
      if (0 <= wd && wd < 128) s = fmaf(tp.g[d + R], s1[e + d], s);
    }
    s2[e] = s;
  }
  __syncthreads();
  long long ob = nc * HW + (long long)h0 * 128;
  for (int e = t; e < 16 * 128; e += 256) {
    int r = e >> 7, w = e & 127;
    float s = 0.f;
    #pragma unroll
    for (int d = 0; d <= 2 * R; ++d) s = fmaf(tp.g[d], s2[(r + d) * 128 + w], s);
    out[ob + e] = SUB ? (xr[ob + e] - s) : s;
  }
}

// ---------------- ctx softmax stats ----------------
__global__ __launch_bounds__(256) void k_ctx_stats(const float* __restrict__ ctx, float* __restrict__ Mc,
                                                   float* __restrict__ invDc) {
  int c = blockIdx.x, n = blockIdx.y, t = threadIdx.x;
  long long base = (long long)(n * 128 + c) * HW;
  __shared__ float red[256];
  float m = -3.0e38f;
  for (int i = t; i < HW; i += 256) m = fmaxf(m, ctx[base + i]);
  red[t] = m; __syncthreads();
  for (int o = 128; o > 0; o >>= 1) { if (t < o) red[t] = fmaxf(red[t], red[t + o]); __syncthreads(); }
  m = red[0]; __syncthreads();
  float s = 0.f;
  for (int i = t; i < HW; i += 256) s += expf(ctx[base + i] - m);
  red[t] = s; __syncthreads();
  for (int o = 128; o > 0; o >>= 1) { if (t < o) red[t] += red[t + o]; __syncthreads(); }
  if (t == 0) { Mc[n * 128 + c] = m; invDc[n * 128 + c] = 1.f / red[0]; }
}

// ---------------- att = softmax(ctx) @ ctx^T (partials over p-splits) ----------------
__global__ __launch_bounds__(256) void k_att(const float* __restrict__ ctx, const float* __restrict__ Mc,
                                             const float* __restrict__ invDc, float* __restrict__ attp) {
  __shared__ float As[32 * 129];
  __shared__ float Bs[32 * 129];
  int t = threadIdx.x, sp = blockIdx.x, n = blockIdx.y;
  int ty = t >> 4, tx = t & 15;
  int c0 = ty * 8, d0 = tx * 8;
  float acc[8][8];
  #pragma unroll
  for (int i = 0; i < 8; ++i)
    #pragma unroll
    for (int j = 0; j < 8; ++j) acc[i][j] = 0.f;
  for (int kc = 0; kc < 16; ++kc) {
    __syncthreads();
    int pb = sp * 512 + kc * 32;
    #pragma unroll
    for (int it = 0; it < 16; ++it) {
      int e = it * 256 + t; int row = e >> 5; int kk = e & 31;
      float v = ctx[(long long)(n * 128 + row) * HW + pb + kk];
      Bs[kk * 129 + row] = v;
      As[kk * 129 + row] = expf(v - Mc[n * 128 + row]) * invDc[n * 128 + row];
    }
    __syncthreads();
    #pragma unroll 4
    for (int kk = 0; kk < 32; ++kk) {
      float a_[8], b_[8];
      #pragma unroll
      for (int i = 0; i < 8; ++i) a_[i] = As[kk * 129 + c0 + i];
      #pragma unroll
      for (int j = 0; j < 8; ++j) b_[j] = Bs[kk * 129 + d0 + j];
      #pragma unroll
      for (int i = 0; i < 8; ++i)
        #pragma unroll
        for (int j = 0; j < 8; ++j) acc[i][j] = fmaf(a_[i], b_[j], acc[i][j]);
    }
  }
  long long ob = ((long long)(sp * 8 + n) * 128 + c0) * 128 + d0;
  #pragma unroll
  for (int i = 0; i < 8; ++i)
    #pragma unroll
    for (int j = 0; j < 8; ++j) attp[ob + i * 128 + j] = acc[i][j];
}

__global__ __launch_bounds__(256) void k_attred(const float* __restrict__ attp, float* __restrict__ att) {
  int g = blockIdx.x * 256 + threadIdx.x;
  float s = 0.f;
  for (int sp = 0; sp < 32; ++sp) s += attp[(long long)sp * 131072 + g];
  att[g] = s;
}

// ---------------- pack conv weight [co][ci][3][3] f32 -> bf16 [co][tap*128+ci] ----------------
__global__ __launch_bounds__(256) void k_wpack(const float* __restrict__ w, unsigned short* __restrict__ wp) {
  int g = blockIdx.x * 256 + threadIdx.x;   // 147456
  int ci = g & 127;
  int tap = (g >> 7) % 9;
  int co = g / 1152;
  wp[g] = f2b(w[co * 1152 + ci * 9 + tap]);
}

// ---------------- zero the halo of a padded NHWC bf16 tensor ----------------
__global__ __launch_bounds__(256) void k_haloz(unsigned short* __restrict__ p) {
  int idx = blockIdx.x * 256 + threadIdx.x;   // 8 * 516 * 16 = 66048
  if (idx >= 66048) return;
  int n = idx / 8256;
  int r = idx % 8256;
  int cell = r >> 4, q = r & 15;
  int h, w;
  if (cell < 130)      { h = 0;   w = cell; }
  else if (cell < 260) { h = 129; w = cell - 130; }
  else if (cell < 388) { h = cell - 260 + 1; w = 0; }
  else                 { h = cell - 388 + 1; w = 129; }
  uint4 z = {0u, 0u, 0u, 0u};
  *(uint4*)(p + (long long)n * NHWC_N + ((long long)h * 130 + w) * 128 + q * 8) = z;
}

// ---------------- NCHW f32 -> padded NHWC bf16 transpose ----------------
__global__ __launch_bounds__(256) void k_t2nhwc(const float* __restrict__ in, unsigned short* __restrict__ outT) {
  __shared__ float ld[64 * 129];
  int t = threadIdx.x;
  int h = blockIdx.x, n = blockIdx.y;
  const float* src = in + (long long)n * 128 * HW + h * 128;
  unsigned short* dst = outT + (long long)n * NHWC_N + ((long long)(h + 1) * 130 + 1) * 128;
  for (int half = 0; half < 2; ++half) {
    __syncthreads();
    for (int e = t; e < 8192; e += 256) {
      int c = e >> 7, w = e & 127;
      ld[c * 129 + w] = src[(long long)(half * 64 + c) * HW + w];
    }
    __syncthreads();
    for (int q = t; q < 1024; q += 256) {
      int w = q >> 3, cg = q & 7;
      bf16x8 pk;
      #pragma unroll
      for (int u = 0; u < 8; ++u) pk[u] = (short)f2b(ld[(cg * 8 + u) * 129 + w]);
      *(bf16x8*)(dst + (long long)w * 128 + half * 64 + cg * 8) = pk;
    }
  }
}

// ---------------- 3x3 conv 128->128: bf16 MFMA, B direct from padded NHWC (no LDS) ----------------
__global__ __launch_bounds__(256) void k_conv3g(const unsigned short* __restrict__ inT,
                                                const unsigned short* __restrict__ wp,
                                                float* __restrict__ out) {
  const int t = threadIdx.x;
  const int h0 = blockIdx.x, n = blockIdx.y;
  const int wid = t >> 6, lane = t & 63;
  const int wy = wid >> 1, wx = wid & 1;
  const int l15 = lane & 15, l4 = lane >> 4;
  f32x4 acc[4][4];
  #pragma unroll
  for (int i = 0; i < 4; ++i)
    #pragma unroll
    for (int j = 0; j < 4; ++j) { f32x4 z = {0.f, 0.f, 0.f, 0.f}; acc[i][j] = z; }
  const unsigned short* bbase = inT + (long long)n * NHWC_N
                              + ((long long)h0 * 130 + wx * 64 + l15) * 128 + l4 * 8;
  const unsigned short* abase = wp + (wy * 64 + l15) * 1152 + l4 * 8;

  for (int kc = 0; kc < 4; ++kc) {
    #pragma unroll
    for (int ky = 0; ky < 3; ++ky) {
      #pragma unroll
      for (int kx = 0; kx < 3; ++kx) {
        bf16x8 af[4], bfr[4];
        #pragma unroll
        for (int cf = 0; cf < 4; ++cf)
          af[cf] = *(const bf16x8*)(abase + cf * 16 * 1152 + (ky * 3 + kx) * 128 + kc * 32);
        #pragma unroll
        for (int pf = 0; pf < 4; ++pf)
          bfr[pf] = *(const bf16x8*)(bbase + ((long long)ky * 130 + pf * 16 + kx) * 128 + kc * 32);
        #pragma unroll
        for (int cf = 0; cf < 4; ++cf)
          #pragma unroll
          for (int pf = 0; pf < 4; ++pf)
            acc[cf][pf] = __builtin_amdgcn_mfma_f32_16x16x32_bf16(af[cf], bfr[pf], acc[cf][pf], 0, 0, 0);
      }
    }
  }
  long long ob = (long long)n * 128 * HW + h0 * 128;
  #pragma unroll
  for (int cf = 0; cf < 4; ++cf)
    #pragma unroll
    for (int pf = 0; pf < 4; ++pf) {
      int co = wy * 64 + cf * 16 + l4 * 4;
      int w  = wx * 64 + pf * 16 + l15;
      #pragma unroll
      for (int r = 0; r < 4; ++r)
        out[ob + (long long)(co + r) * HW + w] = acc[cf][pf][r];
    }
}

// ---------------- BN batch stats ----------------
__global__ __launch_bounds__(256) void k_bnpart(const float* __restrict__ in, float* __restrict__ part) {
  int c = blockIdx.x, b = blockIdx.y, t = threadIdx.x;
  int n = b >> 3, seg = b & 7;
  long long base = (long long)(n * 128 + c) * HW + seg * 2048;
  float s = 0.f, ss = 0.f;
  for (int i = t; i < 2048; i += 256) { float v = in[base + i]; s += v; ss = fmaf(v, v, ss); }
  __shared__ float r1[256], r2[256];
  r1[t] = s; r2[t] = ss; __syncthreads();
  for (int o = 128; o > 0; o >>= 1) { if (t < o) { r1[t] += r1[t + o]; r2[t] += r2[t + o]; } __syncthreads(); }
  if (t == 0) { part[(c * 64 + b) * 2] = r1[0]; part[(c * 64 + b) * 2 + 1] = r2[0]; }
}
__global__ __launch_bounds__(64) void k_bnfin(const float* __restrict__ part, const float* __restrict__ g,
                                              const float* __restrict__ bb, float* __restrict__ ssout) {
  int c = blockIdx.x, t = threadIdx.x;
  float s = part[(c * 64 + t) * 2], ss = part[(c * 64 + t) * 2 + 1];
  for (int o = 32; o > 0; o >>= 1) { s += __shfl_down(s, o, 64); ss += __shfl_down(ss, o, 64); }
  if (t == 0) {
    float mean = s / 131072.f;
    float var = ss / 131072.f - mean * mean;
    float sc = g[c] * rsqrtf(var + 1e-5f);
    ssout[c] = sc;
    ssout[128 + c] = bb[c] - mean * sc;
  }
}

// ---------------- cubic power-mean per (n,c) ----------------
__global__ __launch_bounds__(256) void k_power(const float* __restrict__ in, const float* __restrict__ ss,
                                               float* __restrict__ dst, int off) {
  int c = blockIdx.x, n = blockIdx.y, t = threadIdx.x;
  float sc = ss[c], sh = ss[128 + c];
  long long base = (long long)(n * 128 + c) * HW;
  float s = 0.f;
  for (int i = t; i < HW; i += 256) {
    float r = fmaxf(fmaf(in[base + i], sc, sh), 0.f);
    s += r * r * r;
  }
  __shared__ float red[256];
  red[t] = s; __syncthreads();
  for (int o = 128; o > 0; o >>= 1) { if (t < o) red[t] += red[t + o]; __syncthreads(); }
  if (t == 0) dst[n * 256 + 2 * c + off] = cbrtf(red[0] * (1.f / 16384.f) + 1e-12f);
}

// ---------------- 1d conv x2 + sigmoid ----------------
__global__ __launch_bounds__(256) void k_dvec(const float* __restrict__ din, const float* __restrict__ c1,
                                              const float* __restrict__ c2, float* __restrict__ d0,
                                              float* __restrict__ d1) {
  __shared__ float a[256], b[256];
  int n = blockIdx.x, t = threadIdx.x;
  a[t] = din[n * 256 + t];
  __syncthreads();
  float acc = 0.f;
  #pragma unroll
  for (int k = 0; k < 5; ++k) { int j = t + k - 2; if (0 <= j && j < 256) acc = fmaf(c1[k], a[j], acc); }
  b[t] = acc; __syncthreads();
  float acc2 = 0.f;
  #pragma unroll
  for (int k = 0; k < 5; ++k) { int j = t + k - 2; if (0 <= j && j < 256) acc2 = fmaf(c2[k], b[j], acc2); }
  float sg = 1.f / (1.f + expf(-acc2));
  if ((t & 1) == 0) d0[n * 128 + (t >> 1)] = sg; else d1[n * 128 + (t >> 1)] = sg;
}

// ---------------- f = d0*relu(bn(low)) + d1*relu(bn(high)), in-place into low ----------------
__global__ __launch_bounds__(256) void k_fmix(float* __restrict__ low, const float* __restrict__ high,
                                              const float* __restrict__ ssl, const float* __restrict__ ssh,
                                              const float* __restrict__ d0, const float* __restrict__ d1) {
  int g = blockIdx.x * 256 + threadIdx.x;
  int c = (g >> 14) & 127, n = g >> 21;
  float xl = fmaxf(fmaf(low[g], ssl[c], ssl[128 + c]), 0.f);
  float xh = fmaxf(fmaf(high[g], ssh[c], ssh[128 + c]), 0.f);
  low[g] = d0[n * 128 + c] * xl + d1[n * 128 + c] * xh;
}

static void make_taps(int ks, double sigma, Taps* tp) {
  double c = (ks - 1) / 2.0, sum = 0.0, v[7];
  for (int i = 0; i < ks; ++i) { double d = i - c; v[i] = std::exp(-d * d / (2.0 * sigma * sigma)); sum += v[i]; }
  for (int i = 0; i < 7; ++i) tp->g[i] = (i < ks) ? (float)(v[i] / sum) : 0.f;
}

extern "C" void kernel_launch(void* const* d_in, const int* in_sizes, int n_in,
                              void* d_out, int out_size, void* d_ws, size_t ws_size,
                              hipStream_t stream) {
  const float* x         = (const float*)d_in[0];
  const float* dwconv_w  = (const float*)d_in[1];
  const float* dwconv_b  = (const float*)d_in[2];
  const float* qkvl_w    = (const float*)d_in[3];
  const float* qkvl_b    = (const float*)d_in[4];
  const float* reproj_w  = (const float*)d_in[5];
  const float* reproj_b  = (const float*)d_in[6];
  const float* queries_w = (const float*)d_in[7];
  const float* queries_b = (const float*)d_in[8];
  const float* sff_low_w = (const float*)d_in[9];
  const float* sff_low_g = (const float*)d_in[10];
  const float* sff_low_b = (const float*)d_in[11];
  const float* sff_high_w= (const float*)d_in[12];
  const float* sff_high_g= (const float*)d_in[13];
  const float* sff_high_b= (const float*)d_in[14];
  const float* sff_c1_w  = (const float*)d_in[15];
  const float* sff_c2_w  = (const float*)d_in[16];
  const float* out_conv_w= (const float*)d_in[17];
  const float* out_bn_g  = (const float*)d_in[18];
  const float* out_bn_b  = (const float*)d_in[19];
  const float* out_proj_w= (const float*)d_in[20];
  const float* out_proj_b= (const float*)d_in[21];
  float* ws  = (float*)d_ws;
  float* out = (float*)d_out;

  float* x1   = ws + OFF_X1;
  float* qs   = ws + OFF_QS;
  float* kk   = ws + OFF_KK;
  float* x2o  = ws + OFF_X2O;
  float* vv   = ws + OFF_V;
  float* lf   = ws + OFF_LF;
  float* qp   = ws + OFF_QP;
  float* kp   = ws + OFF_KP;
  float* tA   = ws;            // B1
  float* tB   = ws + U;        // B2
  float* ctx  = ws + U;        // B2 (written while reading tA=B1)
  float* attp = ws;            // B1 front (ctx dead... ctx=B2; attp=B1 ok)
  float* qx   = ws;            // B1 (after attred)
  float* lowc = ws;            // B1
  float* highc= ws + U;        // B2
  float* fbuf = ws;            // B1 in-place
  float* qkb  = ws + OFF_QKB;
  float* Abuf = ws + OFF_AA;
  float* Mq   = ws + OFF_MQ;
  float* Dq   = ws + OFF_DQ;
  float* pmax = ws + OFF_PMAX;
  float* psum = ws + OFF_PSUM;
  float* Mc   = ws + OFF_MC;
  float* Dc   = ws + OFF_DC;
  float* att  = ws + OFF_ATT;
  float* bnp  = ws + OFF_BNP;
  float* ssl  = ws + OFF_SSL;
  float* ssh  = ws + OFF_SSH;
  float* ssy  = ws + OFF_SSY;
  float* dv   = ws + OFF_DV;
  float* d0v  = ws + OFF_D0;
  float* d1v  = ws + OFF_D1;
  unsigned short* wlow  = (unsigned short*)(ws + OFF_WLOW);
  unsigned short* whigh = (unsigned short*)(ws + OFF_WHIGH);
  unsigned short* wout  = (unsigned short*)(ws + OFF_WOUT);
  unsigned short* effT  = (unsigned short*)out;      // d_out as padded NHWC bf16 (34.6MB of 64MB)
  unsigned short* freqT = (unsigned short*)(ws + U); // B2 front
  unsigned short* fT    = (unsigned short*)(ws + U); // B2 front (after highc dead)
  float* ybuf = out;

  Taps t3, t5, t7;
  const double s3 = std::pow(2.0, 1.0 / 3.0);
  make_taps(3, 1.6, &t3);
  make_taps(5, 1.6 * s3, &t5);
  make_taps(7, 1.6 * s3 * s3, &t7);

  dim3 b256(256), b128(128);

  // ---- phase 1: eff -> effT (bf16 NHWC in d_out) ----
  k_haloz<<<dim3(258), b256, 0, stream>>>(effT);
  k_dwconv<<<dim3(32768), b256, 0, stream>>>(x, dwconv_w, dwconv_b, x1);
  k_qkvl<<<dim3(512), b256, 0, stream>>>(x, qkvl_w, qkvl_b, qs, kk, vv, lf);
  k_avgpool<<<dim3(4096), b256, 0, stream>>>(qs, qp);
  k_maxpool<<<dim3(4096), b256, 0, stream>>>(kk, kp);
  k_qk<<<dim3(32, 8), b256, 0, stream>>>(qp, kp, qkb);
  k_qksm<<<dim3(8), dim3(32), 0, stream>>>(qkb, Abuf);
  k_x2o<<<dim3(512), b256, 0, stream>>>(Abuf, vv, x2o);
  k_gemm1x1<M_EFF><<<dim3(128, 8), b256, 0, stream>>>(reproj_w, x1, lf, x2o, reproj_b,
                                                      nullptr, nullptr, nullptr, nullptr, effT);
  // ---- phase 2: ctx / att (fused blur pairs; x -> tB -> tA -> ctx=B2) ----
  k_blur2<1, false><<<dim3(8, 1024), b256, 0, stream>>>(x, nullptr, tB, t3);
  k_blur2<2, false><<<dim3(8, 1024), b256, 0, stream>>>(tB, nullptr, tA, t5);
  k_blur2<3, true><<<dim3(8, 1024), b256, 0, stream>>>(tA, x, ctx, t7);
  k_ctx_stats<<<dim3(128, 8), b256, 0, stream>>>(ctx, Mc, Dc);
  k_att<<<dim3(32, 8), b256, 0, stream>>>(ctx, Mc, Dc, attp);          // attp = B1 front
  k_attred<<<dim3(512), b256, 0, stream>>>(attp, att);
  // ---- phase 3: qx -> freqT (bf16 NHWC in B2) ----
  k_gemm1x1<M_QX><<<dim3(128, 8), b256, 0, stream>>>(queries_w, x, nullptr, nullptr, queries_b,
                                                     nullptr, nullptr, nullptr, nullptr, qx);  // qx = B1
  k_qx_pmax<<<dim3(128, 8), b128, 0, stream>>>(qx, pmax);
  k_qx_rmax<<<dim3(8), b128, 0, stream>>>(pmax, Mq);
  k_qx_psum<<<dim3(128, 8), b128, 0, stream>>>(qx, Mq, psum);
  k_qx_rsum<<<dim3(8), b128, 0, stream>>>(psum, Dq);
  k_wpack<<<dim3(576), b256, 0, stream>>>(sff_low_w, wlow);
  k_wpack<<<dim3(576), b256, 0, stream>>>(sff_high_w, whigh);
  k_wpack<<<dim3(576), b256, 0, stream>>>(out_conv_w, wout);
  k_haloz<<<dim3(258), b256, 0, stream>>>(freqT);                       // ctx dead (B2 front)
  k_gemm1x1<M_FREQ><<<dim3(128, 8), b256, 0, stream>>>(att, qx, nullptr, nullptr, nullptr,
                                                       nullptr, Mq, Dq, x, freqT);
  // ---- phase 4: convs / BN / mix / out ----
  k_conv3g<<<dim3(128, 8), b256, 0, stream>>>(freqT, wlow, lowc);      // B2 -> B1 (qx dead)
  k_conv3g<<<dim3(128, 8), b256, 0, stream>>>(effT, whigh, highc);     // d_out -> B2 (freqT dead)
  k_bnpart<<<dim3(128, 64), b256, 0, stream>>>(lowc, bnp);
  k_bnfin<<<dim3(128), dim3(64), 0, stream>>>(bnp, sff_low_g, sff_low_b, ssl);
  k_bnpart<<<dim3(128, 64), b256, 0, stream>>>(highc, bnp);
  k_bnfin<<<dim3(128), dim3(64), 0, stream>>>(bnp, sff_high_g, sff_high_b, ssh);
  k_power<<<dim3(128, 8), b256, 0, stream>>>(lowc, ssl, dv, 0);
  k_power<<<dim3(128, 8), b256, 0, stream>>>(highc, ssh, dv, 1);
  k_dvec<<<dim3(8), b256, 0, stream>>>(dv, sff_c1_w, sff_c2_w, d0v, d1v);
  k_fmix<<<dim3(65536), b256, 0, stream>>>(lowc, highc, ssl, ssh, d0v, d1v);  // f -> B1
  k_haloz<<<dim3(258), b256, 0, stream>>>(fT);                                // highc dead
  k_t2nhwc<<<dim3(128, 8), b256, 0, stream>>>(fbuf, fT);                      // B1 -> B2
  k_conv3g<<<dim3(128, 8), b256, 0, stream>>>(fT, wout, ybuf);                // B2 -> d_out (effT dead)
  k_bnpart<<<dim3(128, 64), b256, 0, stream>>>(ybuf, bnp);
  k_bnfin<<<dim3(128), dim3(64), 0, stream>>>(bnp, out_bn_g, out_bn_b, ssy);
  k_gemm1x1<M_OUT><<<dim3(128, 8), b256, 0, stream>>>(out_proj_w, ybuf, nullptr, nullptr, out_proj_b,
                                                      ssy, nullptr, nullptr, nullptr, out);    // in-place
  (void)in_sizes; (void)n_in; (void)out_size; (void)ws_size;
}

// Round 6
// 1334.584 us; speedup vs baseline: 6.0641x; 1.2375x over previous
//
#include <hip/hip_runtime.h>
#include <hip/hip_bf16.h>
#include <cmath>

#define DEVFN __device__ __forceinline__

constexpr int HW = 16384;                      // 128*128
constexpr long long U = 16777216LL;            // 8*128*16384 floats
constexpr long long NHWC_N = 2163200LL;        // 130*130*128 ushorts per image

typedef __attribute__((ext_vector_type(8))) short bf16x8;
typedef __attribute__((ext_vector_type(4))) float f32x4;
typedef __attribute__((ext_vector_type(4))) unsigned short u16x4;

// ---- workspace layout (floats). B1 = ws[0,U), B2 = ws[U,2U), S = ws[2U,...). ~130 MB. ----
constexpr long long OFF_X1   = 0;
constexpr long long OFF_QS   = U/2;
constexpr long long OFF_KK   = 3*U/4;
constexpr long long OFF_X2O  = U/2;
constexpr long long OFF_V    = U;
constexpr long long OFF_LF   = U + U/4;
constexpr long long OFF_QP   = U + U/2;
constexpr long long OFF_KP   = U + U/2 + 1048576;
constexpr long long S0       = 2*U;
constexpr long long OFF_QKB  = S0;
constexpr long long OFF_AA   = S0 + 8192;
constexpr long long OFF_MQ   = S0 + 16384;
constexpr long long OFF_DQ   = S0 + 17408;
constexpr long long OFF_PMAX = S0 + 18432;     // 131072 (later: bf16 weight packs)
constexpr long long OFF_PSUM = S0 + 149504;    // 131072
constexpr long long OFF_MC   = S0 + 280576;
constexpr long long OFF_DC   = S0 + 281600;
constexpr long long OFF_ATT  = S0 + 282624;    // 131072
constexpr long long OFF_BNP  = S0 + 413696;    // 16384
constexpr long long OFF_SSL  = S0 + 430080;
constexpr long long OFF_SSH  = S0 + 430336;
constexpr long long OFF_SSY  = S0 + 430592;
constexpr long long OFF_DV   = S0 + 430848;
constexpr long long OFF_D0   = S0 + 432896;
constexpr long long OFF_D1   = S0 + 433920;
constexpr long long OFF_WQK  = S0 + 434944;    // 5120 floats = 10240 bf16 (qkvl weights)
constexpr long long OFF_WLOW  = OFF_PMAX;
constexpr long long OFF_WHIGH = OFF_PMAX + 73728;
constexpr long long OFF_WOUT  = OFF_PMAX + 147456;
// ws total = 2U + 440064 floats ~ 130 MB

struct Taps { float g[7]; };

DEVFN float gelu_f(float v) { return 0.5f * v * (1.0f + erff(v * 0.7071067811865475f)); }
DEVFN unsigned short f2b(float f) {
  unsigned u = __float_as_uint(f);
  unsigned r = u + 0x7fffu + ((u >> 16) & 1u);
  return (unsigned short)(r >> 16);
}
DEVFN unsigned pk2(float a, float b) {
  return (unsigned)f2b(a) | ((unsigned)f2b(b) << 16);
}

// ---------------- depthwise 3x3 + gelu on even channels ----------------
__global__ __launch_bounds__(256) void k_dwconv(const float* __restrict__ x, const float* __restrict__ w9,
                                                const float* __restrict__ bia, float* __restrict__ out) {
  int g = blockIdx.x * 256 + threadIdx.x;
  int w = g & 127, h = (g >> 7) & 127, c = (g >> 14) & 63, n = g >> 20;
  const float* src = x + (long long)(n * 128 + 2 * c) * HW;
  float acc = bia[c];
  #pragma unroll
  for (int ky = 0; ky < 3; ++ky) {
    int h2 = h + ky - 1;
    if ((unsigned)h2 < 128u) {
      #pragma unroll
      for (int kx = 0; kx < 3; ++kx) {
        int w2 = w + kx - 1;
        if ((unsigned)w2 < 128u) acc = fmaf(w9[c * 9 + ky * 3 + kx], src[h2 * 128 + w2], acc);
      }
    }
  }
  out[(long long)(n * 64 + c) * HW + h * 128 + w] = gelu_f(acc);
}

// ---------------- pack qkvl weights [160][64] f32 -> bf16 ----------------
__global__ __launch_bounds__(256) void k_wpackq(const float* __restrict__ w, unsigned short* __restrict__ wp) {
  int g = blockIdx.x * 256 + threadIdx.x;
  if (g < 10240) wp[g] = f2b(w[g]);
}

// ---------------- qkvl 1x1 conv (64->160) via bf16 MFMA + gelu + head routing ----------------
__global__ __launch_bounds__(256) void k_qkvlm(const float* __restrict__ x, const unsigned short* __restrict__ wqk,
                                               const float* __restrict__ bq, float* __restrict__ qs,
                                               float* __restrict__ kk, float* __restrict__ vv,
                                               float* __restrict__ lf) {
  __shared__ unsigned int As[160 * 36];
  __shared__ unsigned int Bs[128 * 36];
  const int t = threadIdx.x;
  const int bx = blockIdx.x, n = blockIdx.y;
  const int pxb = bx * 128;
  for (int e = t; e < 5120; e += 256) As[(e >> 5) * 36 + (e & 31)] = ((const unsigned int*)wqk)[e];
  #pragma unroll
  for (int it = 0; it < 16; ++it) {
    int e = it * 256 + t;
    int px = e & 127, k2 = e >> 7;   // k2 0..31, ci pair (2k2, 2k2+1) -> x channels 4k2+1, 4k2+3
    float v0 = x[(long long)(n * 128 + 4 * k2 + 1) * HW + pxb + px];
    float v1 = x[(long long)(n * 128 + 4 * k2 + 3) * HW + pxb + px];
    Bs[px * 36 + k2] = pk2(v0, v1);
  }
  __syncthreads();
  const int wid = t >> 6, lane = t & 63, l15 = lane & 15, l4 = lane >> 4;
  f32x4 acc[10][2];
  #pragma unroll
  for (int m = 0; m < 10; ++m)
    #pragma unroll
    for (int p = 0; p < 2; ++p) { f32x4 z = {0.f,0.f,0.f,0.f}; acc[m][p] = z; }
  #pragma unroll
  for (int ks = 0; ks < 2; ++ks) {
    bf16x8 bfr[2];
    #pragma unroll
    for (int pf = 0; pf < 2; ++pf)
      bfr[pf] = *(const bf16x8*)(&Bs[(wid * 32 + pf * 16 + l15) * 36 + ks * 16 + l4 * 4]);
    #pragma unroll
    for (int mf = 0; mf < 10; ++mf) {
      bf16x8 af = *(const bf16x8*)(&As[(mf * 16 + l15) * 36 + ks * 16 + l4 * 4]);
      acc[mf][0] = __builtin_amdgcn_mfma_f32_16x16x32_bf16(af, bfr[0], acc[mf][0], 0, 0, 0);
      acc[mf][1] = __builtin_amdgcn_mfma_f32_16x16x32_bf16(af, bfr[1], acc[mf][1], 0, 0, 0);
    }
  }
  #pragma unroll
  for (int pf = 0; pf < 2; ++pf) {
    int px = pxb + wid * 32 + pf * 16 + l15;
    #pragma unroll
    for (int mf = 0; mf < 2; ++mf) {
      #pragma unroll
      for (int r = 0; r < 4; ++r) {
        int j = mf * 16 + l4 * 4 + r;
        long long o = (long long)(n * 32 + j) * HW + px;
        float a0 = gelu_f(acc[mf][pf][r] + bq[j]);
        float a1 = gelu_f(acc[mf + 2][pf][r] + bq[32 + j]);
        qs[o] = a0 + a1;
        kk[o] = gelu_f(acc[mf + 4][pf][r] + bq[64 + j]);
        vv[o] = gelu_f(acc[mf + 6][pf][r] + bq[96 + j]);
        lf[o] = gelu_f(acc[mf + 8][pf][r] + bq[128 + j]);
      }
    }
  }
}

// ---------------- pools ----------------
__global__ __launch_bounds__(256) void k_avgpool(const float* __restrict__ in, float* __restrict__ out) {
  int g = blockIdx.x * 256 + threadIdx.x;
  int ow = g & 63, oh = (g >> 6) & 63, c = (g >> 12) & 31, n = g >> 17;
  const float* src = in + (long long)(n * 32 + c) * HW;
  float s = 0.f;
  #pragma unroll
  for (int i = 0; i < 3; ++i) {
    int h = oh * 2 - 1 + i;
    if ((unsigned)h < 128u) {
      #pragma unroll
      for (int j = 0; j < 3; ++j) {
        int w = ow * 2 - 1 + j;
        if ((unsigned)w < 128u) s += src[h * 128 + w];
      }
    }
  }
  out[(long long)(n * 32 + c) * 4096 + oh * 64 + ow] = s * (1.f / 9.f);
}

__global__ __launch_bounds__(256) void k_maxpool(const float* __restrict__ in, float* __restrict__ out) {
  int g = blockIdx.x * 256 + threadIdx.x;
  int ow = g & 63, oh = (g >> 6) & 63, c = (g >> 12) & 31, n = g >> 17;
  const float* src = in + (long long)(n * 32 + c) * HW;
  float m = -3.0e38f;
  #pragma unroll
  for (int i = 0; i < 2; ++i)
    #pragma unroll
    for (int j = 0; j < 2; ++j)
      m = fmaxf(m, src[(oh * 2 + i) * 128 + ow * 2 + j]);
  out[(long long)(n * 32 + c) * 4096 + oh * 64 + ow] = m;
}

// ---------------- qk (32x32 per n, K=4096) ----------------
__global__ __launch_bounds__(256) void k_qk(const float* __restrict__ qp, const float* __restrict__ kp,
                                            float* __restrict__ qk) {
  int c = blockIdx.x, n = blockIdx.y;
  int t = threadIdx.x, d = t >> 3, r = t & 7;
  const float* qr = qp + (long long)(n * 32 + c) * 4096;
  const float* kr = kp + (long long)(n * 32 + d) * 4096;
  float acc = 0.f;
  for (int p = r; p < 4096; p += 8) acc = fmaf(qr[p], kr[p], acc);
  acc += __shfl_down(acc, 4, 8);
  acc += __shfl_down(acc, 2, 8);
  acc += __shfl_down(acc, 1, 8);
  if (r == 0) qk[(n * 32 + c) * 32 + d] = acc;
}

__global__ void k_qksm(const float* __restrict__ qk, float* __restrict__ A) {
  int n = blockIdx.x, d = threadIdx.x;
  float m = -3.0e38f;
  for (int c = 0; c < 32; ++c) m = fmaxf(m, qk[(n * 32 + c) * 32 + d]);
  float s = 0.f;
  for (int c = 0; c < 32; ++c) s += expf(qk[(n * 32 + c) * 32 + d] - m);
  float inv = 1.f / s;
  for (int c = 0; c < 32; ++c) A[(n * 32 + c) * 32 + d] = expf(qk[(n * 32 + c) * 32 + d] - m) * inv;
}

// ---------------- x2o = A^T @ v ----------------
__global__ __launch_bounds__(256) void k_x2o(const float* __restrict__ A, const float* __restrict__ vsrc,
                                             float* __restrict__ out) {
  __shared__ float lA[1024];
  int t = threadIdx.x;
  int g = blockIdx.x * 256 + t;
  int n = g >> 14, p = g & 16383;
  for (int e = t; e < 1024; e += 256) lA[e] = A[n * 1024 + e];
  __syncthreads();
  float acc[32];
  #pragma unroll
  for (int i = 0; i < 32; ++i) acc[i] = 0.f;
  for (int q = 0; q < 32; ++q) {
    float vv = vsrc[(long long)(n * 32 + q) * HW + p];
    #pragma unroll
    for (int k2 = 0; k2 < 32; ++k2) acc[k2] = fmaf(lA[q * 32 + k2], vv, acc[k2]);
  }
  #pragma unroll
  for (int k2 = 0; k2 < 32; ++k2) out[(long long)(n * 32 + k2) * HW + p] = acc[k2];
}

// ---------------- 128x128x128 GEMMs via bf16 MFMA ----------------
enum { M_EFF = 0, M_QX = 1, M_OUT = 2, M_FREQ = 3 };

template <int MODE>
__global__ __launch_bounds__(256) void k_gemm1x1m(
    const float* __restrict__ Amat, const float* __restrict__ B0, const float* __restrict__ B1,
    const float* __restrict__ B2, const float* __restrict__ bias, const float* __restrict__ scale,
    const float* __restrict__ Mq, const float* __restrict__ invDq, const float* __restrict__ xres,
    void* __restrict__ outp) {
  __shared__ unsigned int As[128 * 36];
  __shared__ unsigned int Bs[128 * 36];
  const int t = threadIdx.x;
  const int bx = blockIdx.x, n = blockIdx.y;
  const int pxb = bx * 128;
  const int wid = t >> 6, lane = t & 63, l15 = lane & 15, l4 = lane >> 4;
  const int wy = wid >> 1, wx = wid & 1;
  f32x4 acc[4][4];
  #pragma unroll
  for (int i = 0; i < 4; ++i)
    #pragma unroll
    for (int j = 0; j < 4; ++j) { f32x4 z = {0.f,0.f,0.f,0.f}; acc[i][j] = z; }

  for (int kc = 0; kc < 2; ++kc) {
    __syncthreads();
    // ---- stage A half: k2l in [0,32) -> K = kc*64 + 2*k2l ----
    if (MODE == M_FREQ) {
      #pragma unroll
      for (int it = 0; it < 16; ++it) {
        int e = it * 256 + t;
        int i = e & 127, j2l = e >> 7;          // j2l 0..31
        int j = kc * 64 + 2 * j2l;
        float v0 = Amat[(long long)(n * 128 + j) * 128 + i];
        float v1 = Amat[(long long)(n * 128 + j + 1) * 128 + i];
        As[i * 36 + j2l] = pk2(v0, v1);
      }
    } else {
      #pragma unroll
      for (int it = 0; it < 16; ++it) {
        int e = it * 256 + t;
        int m = e >> 5, k2l = e & 31;
        float2 v = *(const float2*)(&Amat[m * 128 + kc * 64 + 2 * k2l]);
        As[m * 36 + k2l] = pk2(v.x, v.y);
      }
    }
    // ---- stage B half ----
    if (MODE == M_FREQ) {
      #pragma unroll
      for (int it = 0; it < 16; ++it) {
        int e = it * 256 + t;
        int j2l = e & 31, px = e >> 5;
        int j = kc * 64 + 2 * j2l;
        long long qb = ((long long)n * HW + pxb + px) * 128 + j;
        float2 v = *(const float2*)(&B0[qb]);
        float e0 = expf(v.x - Mq[n * 128 + j]) * invDq[n * 128 + j];
        float e1 = expf(v.y - Mq[n * 128 + j + 1]) * invDq[n * 128 + j + 1];
        Bs[px * 36 + j2l] = pk2(e0, e1);
      }
    } else {
      #pragma unroll
      for (int it = 0; it < 16; ++it) {
        int e = it * 256 + t;
        int px = e & 127, k2l = e >> 7;
        int ci = kc * 64 + 2 * k2l;
        float v0, v1;
        if (MODE == M_EFF) {
          if (ci < 64) {
            v0 = B0[(long long)(n * 64 + ci) * HW + pxb + px];
            v1 = B0[(long long)(n * 64 + ci + 1) * HW + pxb + px];
          } else if (ci < 96) {
            v0 = B1[(long long)(n * 32 + ci - 64) * HW + pxb + px];
            v1 = B1[(long long)(n * 32 + ci - 63) * HW + pxb + px];
          } else {
            v0 = B2[(long long)(n * 32 + ci - 96) * HW + pxb + px];
            v1 = B2[(long long)(n * 32 + ci - 95) * HW + pxb + px];
          }
        } else if (MODE == M_QX) {
          v0 = B0[(long long)(n * 128 + ci) * HW + pxb + px];
          v1 = B0[(long long)(n * 128 + ci + 1) * HW + pxb + px];
        } else {  // M_OUT
          float u0 = B0[(long long)(n * 128 + ci) * HW + pxb + px];
          float u1 = B0[(long long)(n * 128 + ci + 1) * HW + pxb + px];
          v0 = fmaxf(fmaf(u0, scale[ci], scale[128 + ci]), 0.f);
          v1 = fmaxf(fmaf(u1, scale[ci + 1], scale[128 + ci + 1]), 0.f);
        }
        Bs[px * 36 + k2l] = pk2(v0, v1);
      }
    }
    __syncthreads();
    #pragma unroll
    for (int ks = 0; ks < 2; ++ks) {
      bf16x8 af[4], bfr[4];
      #pragma unroll
      for (int mf = 0; mf < 4; ++mf)
        af[mf] = *(const bf16x8*)(&As[(wy * 64 + mf * 16 + l15) * 36 + ks * 16 + l4 * 4]);
      #pragma unroll
      for (int nf = 0; nf < 4; ++nf)
        bfr[nf] = *(const bf16x8*)(&Bs[(wx * 64 + nf * 16 + l15) * 36 + ks * 16 + l4 * 4]);
      #pragma unroll
      for (int mf = 0; mf < 4; ++mf)
        #pragma unroll
        for (int nf = 0; nf < 4; ++nf)
          acc[mf][nf] = __builtin_amdgcn_mfma_f32_16x16x32_bf16(af[mf], bfr[nf], acc[mf][nf], 0, 0, 0);
    }
  }
  if (MODE == M_EFF || MODE == M_FREQ) {
    unsigned short* oT = (unsigned short*)outp;
    #pragma unroll
    for (int nf = 0; nf < 4; ++nf) {
      int px = pxb + wx * 64 + nf * 16 + l15;
      int hh = px >> 7, wwp = (px & 127) + 1;
      long long rb = (long long)n * NHWC_N + ((long long)(hh + 1) * 130 + wwp) * 128;
      #pragma unroll
      for (int mf = 0; mf < 4; ++mf) {
        int ch = wy * 64 + mf * 16 + l4 * 4;
        u16x4 pk;
        #pragma unroll
        for (int r = 0; r < 4; ++r) {
          float v = acc[mf][nf][r] + ((MODE == M_EFF) ? bias[ch + r] : 0.f);
          if (MODE == M_FREQ) v += xres[(long long)(n * 128 + ch + r) * HW + px];
          pk[r] = f2b(v);
        }
        *(u16x4*)(&oT[rb + ch]) = pk;
      }
    }
  } else {
    float* of = (float*)outp;
    #pragma unroll
    for (int mf = 0; mf < 4; ++mf)
      #pragma unroll
      for (int nf = 0; nf < 4; ++nf) {
        int px = pxb + wx * 64 + nf * 16 + l15;
        #pragma unroll
        for (int r = 0; r < 4; ++r) {
          int ch = wy * 64 + mf * 16 + l4 * 4 + r;
          of[(long long)(n * 128 + ch) * HW + px] = acc[mf][nf][r] + bias[ch];
        }
      }
  }
}

// ---------------- qx softmax stats ----------------
__global__ __launch_bounds__(128) void k_qx_pmax(const float* __restrict__ qx, float* __restrict__ pmax) {
  int c = blockIdx.x, n = blockIdx.y, w = threadIdx.x;
  long long base = (long long)(n * 128 + c) * HW + w;
  float m = -3.0e38f;
  for (int h = 0; h < 128; ++h) m = fmaxf(m, qx[base + h * 128]);
  pmax[(n * 128 + c) * 128 + w] = m;
}
__global__ __launch_bounds__(128) void k_qx_rmax(const float* __restrict__ pmax, float* __restrict__ Mq) {
  int n = blockIdx.x, w = threadIdx.x;
  float m = -3.0e38f;
  for (int c = 0; c < 128; ++c) m = fmaxf(m, pmax[(n * 128 + c) * 128 + w]);
  Mq[n * 128 + w] = m;
}
__global__ __launch_bounds__(128) void k_qx_psum(const float* __restrict__ qx, const float* __restrict__ Mq,
                                                 float* __restrict__ psum) {
  int c = blockIdx.x, n = blockIdx.y, w = threadIdx.x;
  float M = Mq[n * 128 + w];
  long long base = (long long)(n * 128 + c) * HW + w;
  float s = 0.f;
  for (int h = 0; h < 128; ++h) s += expf(qx[base + h * 128] - M);
  psum[(n * 128 + c) * 128 + w] = s;
}
__global__ __launch_bounds__(128) void k_qx_rsum(const float* __restrict__ psum, float* __restrict__ invDq) {
  int n = blockIdx.x, w = threadIdx.x;
  float s = 0.f;
  for (int c = 0; c < 128; ++c) s += psum[(n * 128 + c) * 128 + w];
  invDq[n * 128 + w] = 1.f / s;
}

// ---------------- fused separable gaussian blur ----------------
template <int R, bool SUB>
__global__ __launch_bounds__(256) void k_blur2(const float* __restrict__ in, const float* __restrict__ xr,
                                               float* __restrict__ out, Taps tp) {
  constexpr int ROWS = 16 + 2 * R;
  __shared__ float s1[ROWS * 128];
  __shared__ float s2[ROWS * 128];
  int t = threadIdx.x;
  int h0 = blockIdx.x * 16;
  long long nc = blockIdx.y;
  const float* src = in + nc * HW;
  for (int e = t; e < ROWS * 128; e += 256) {
    int r = e >> 7;
    int h = h0 - R + r;
    s1[e] = ((unsigned)h < 128u) ? src[h * 128 + (e & 127)] : 0.f;
  }
  __syncthreads();
  for (int e = t; e < ROWS * 128; e += 256) {
    int w = e & 127;
    float s = 0.f;
    #pragma unroll
    for (int d = -R; d <= R; ++d) {
      int wd = w + d;
      if (0 <= wd && wd < 128) s = fmaf(tp.g[d + R], s1[e + d], s);
    }
    s2[e] = s;
  }
  __syncthreads();
  long long ob = nc * HW + (long long)h0 * 128;
  for (int e = t; e < 16 * 128; e += 256) {
    int r = e >> 7, w = e & 127;
    float s = 0.f;
    #pragma unroll
    for (int d = 0; d <= 2 * R; ++d) s = fmaf(tp.g[d], s2[(r + d) * 128 + w], s);
    out[ob + e] = SUB ? (xr[ob + e] - s) : s;
  }
}

// ---------------- ctx softmax stats ----------------
__global__ __launch_bounds__(256) void k_ctx_stats(const float* __restrict__ ctx, float* __restrict__ Mc,
                                                   float* __restrict__ invDc) {
  int c = blockIdx.x, n = blockIdx.y, t = threadIdx.x;
  long long base = (long long)(n * 128 + c) * HW;
  __shared__ float red[256];
  float m = -3.0e38f;
  for (int i = t; i < HW; i += 256) m = fmaxf(m, ctx[base + i]);
  red[t] = m; __syncthreads();
  for (int o = 128; o > 0; o >>= 1) { if (t < o) red[t] = fmaxf(red[t], red[t + o]); __syncthreads(); }
  m = red[0]; __syncthreads();
  float s = 0.f;
  for (int i = t; i < HW; i += 256) s += expf(ctx[base + i] - m);
  red[t] = s; __syncthreads();
  for (int o = 128; o > 0; o >>= 1) { if (t < o) red[t] += red[t + o]; __syncthreads(); }
  if (t == 0) { Mc[n * 128 + c] = m; invDc[n * 128 + c] = 1.f / red[0]; }
}

// ---------------- att = softmax(ctx) @ ctx^T via bf16 MFMA (partials over p-splits) ----------------
__global__ __launch_bounds__(256) void k_attm(const float* __restrict__ ctx, const float* __restrict__ Mc,
                                              const float* __restrict__ invDc, float* __restrict__ attp) {
  __shared__ unsigned int As[128 * 36];
  __shared__ unsigned int Bs[128 * 36];
  const int t = threadIdx.x, sp = blockIdx.x, n = blockIdx.y;
  const int wid = t >> 6, lane = t & 63, l15 = lane & 15, l4 = lane >> 4;
  const int wy = wid >> 1, wx = wid & 1;
  f32x4 acc[4][4];
  #pragma unroll
  for (int i = 0; i < 4; ++i)
    #pragma unroll
    for (int j = 0; j < 4; ++j) { f32x4 z = {0.f,0.f,0.f,0.f}; acc[i][j] = z; }
  for (int kc = 0; kc < 8; ++kc) {
    __syncthreads();
    int pb = sp * 512 + kc * 64;
    #pragma unroll
    for (int it = 0; it < 16; ++it) {
      int e = it * 256 + t;
      int row = e >> 5, p2 = e & 31;
      float2 v = *(const float2*)(&ctx[(long long)(n * 128 + row) * HW + pb + 2 * p2]);
      float m = Mc[n * 128 + row], d = invDc[n * 128 + row];
      Bs[row * 36 + p2] = pk2(v.x, v.y);
      As[row * 36 + p2] = pk2(expf(v.x - m) * d, expf(v.y - m) * d);
    }
    __syncthreads();
    #pragma unroll
    for (int ks = 0; ks < 2; ++ks) {
      bf16x8 af[4], bfr[4];
      #pragma unroll
      for (int mf = 0; mf < 4; ++mf)
        af[mf] = *(const bf16x8*)(&As[(wy * 64 + mf * 16 + l15) * 36 + ks * 16 + l4 * 4]);
      #pragma unroll
      for (int nf = 0; nf < 4; ++nf)
        bfr[nf] = *(const bf16x8*)(&Bs[(wx * 64 + nf * 16 + l15) * 36 + ks * 16 + l4 * 4]);
      #pragma unroll
      for (int mf = 0; mf < 4; ++mf)
        #pragma unroll
        for (int nf = 0; nf < 4; ++nf)
          acc[mf][nf] = __builtin_amdgcn_mfma_f32_16x16x32_bf16(af[mf], bfr[nf], acc[mf][nf], 0, 0, 0);
    }
  }
  long long ob = (long long)(sp * 8 + n) * 16384;
  #pragma unroll
  for (int mf = 0; mf < 4; ++mf)
    #pragma unroll
    for (int nf = 0; nf < 4; ++nf) {
      int d = wx * 64 + nf * 16 + l15;
      #pragma unroll
      for (int r = 0; r < 4; ++r) {
        int c = wy * 64 + mf * 16 + l4 * 4 + r;
        attp[ob + c * 128 + d] = acc[mf][nf][r];
      }
    }
}

__global__ __launch_bounds__(256) void k_attred(const float* __restrict__ attp, float* __restrict__ att) {
  int g = blockIdx.x * 256 + threadIdx.x;
  float s = 0.f;
  for (int sp = 0; sp < 32; ++sp) s += attp[(long long)sp * 131072 + g];
  att[g] = s;
}

// ---------------- pack conv weight [co][ci][3][3] f32 -> bf16 [co][tap*128+ci] ----------------
__global__ __launch_bounds__(256) void k_wpack(const float* __restrict__ w, unsigned short* __restrict__ wp) {
  int g = blockIdx.x * 256 + threadIdx.x;
  int ci = g & 127;
  int tap = (g >> 7) % 9;
  int co = g / 1152;
  wp[g] = f2b(w[co * 1152 + ci * 9 + tap]);
}

// ---------------- zero the halo of a padded NHWC bf16 tensor ----------------
__global__ __launch_bounds__(256) void k_haloz(unsigned short* __restrict__ p) {
  int idx = blockIdx.x * 256 + threadIdx.x;
  if (idx >= 66048) return;
  int n = idx / 8256;
  int r = idx % 8256;
  int cell = r >> 4, q = r & 15;
  int h, w;
  if (cell < 130)      { h = 0;   w = cell; }
  else if (cell < 260) { h = 129; w = cell - 130; }
  else if (cell < 388) { h = cell - 260 + 1; w = 0; }
  else                 { h = cell - 388 + 1; w = 129; }
  uint4 z = {0u, 0u, 0u, 0u};
  *(uint4*)(p + (long long)n * NHWC_N + ((long long)h * 130 + w) * 128 + q * 8) = z;
}

// ---------------- NCHW f32 -> padded NHWC bf16 transpose ----------------
__global__ __launch_bounds__(256) void k_t2nhwc(const float* __restrict__ in, unsigned short* __restrict__ outT) {
  __shared__ float ld[64 * 129];
  int t = threadIdx.x;
  int h = blockIdx.x, n = blockIdx.y;
  const float* src = in + (long long)n * 128 * HW + h * 128;
  unsigned short* dst = outT + (long long)n * NHWC_N + ((long long)(h + 1) * 130 + 1) * 128;
  for (int half = 0; half < 2; ++half) {
    __syncthreads();
    for (int e = t; e < 8192; e += 256) {
      int c = e >> 7, w = e & 127;
      ld[c * 129 + w] = src[(long long)(half * 64 + c) * HW + w];
    }
    __syncthreads();
    for (int q = t; q < 1024; q += 256) {
      int w = q >> 3, cg = q & 7;
      bf16x8 pk;
      #pragma unroll
      for (int u = 0; u < 8; ++u) pk[u] = (short)f2b(ld[(cg * 8 + u) * 129 + w]);
      *(bf16x8*)(dst + (long long)w * 128 + half * 64 + cg * 8) = pk;
    }
  }
}

// ---------------- 3x3 conv 128->128: bf16 MFMA, B direct from padded NHWC ----------------
__global__ __launch_bounds__(256) void k_conv3g(const unsigned short* __restrict__ inT,
                                                const unsigned short* __restrict__ wp,
                                                float* __restrict__ out) {
  const int t = threadIdx.x;
  const int h0 = blockIdx.x, n = blockIdx.y;
  const int wid = t >> 6, lane = t & 63;
  const int wy = wid >> 1, wx = wid & 1;
  const int l15 = lane & 15, l4 = lane >> 4;
  f32x4 acc[4][4];
  #pragma unroll
  for (int i = 0; i < 4; ++i)
    #pragma unroll
    for (int j = 0; j < 4; ++j) { f32x4 z = {0.f, 0.f, 0.f, 0.f}; acc[i][j] = z; }
  const unsigned short* bbase = inT + (long long)n * NHWC_N
                              + ((long long)h0 * 130 + wx * 64 + l15) * 128 + l4 * 8;
  const unsigned short* abase = wp + (wy * 64 + l15) * 1152 + l4 * 8;

  for (int kc = 0; kc < 4; ++kc) {
    #pragma unroll
    for (int ky = 0; ky < 3; ++ky) {
      #pragma unroll
      for (int kx = 0; kx < 3; ++kx) {
        bf16x8 af[4], bfr[4];
        #pragma unroll
        for (int cf = 0; cf < 4; ++cf)
          af[cf] = *(const bf16x8*)(abase + cf * 16 * 1152 + (ky * 3 + kx) * 128 + kc * 32);
        #pragma unroll
        for (int pf = 0; pf < 4; ++pf)
          bfr[pf] = *(const bf16x8*)(bbase + ((long long)ky * 130 + pf * 16 + kx) * 128 + kc * 32);
        #pragma unroll
        for (int cf = 0; cf < 4; ++cf)
          #pragma unroll
          for (int pf = 0; pf < 4; ++pf)
            acc[cf][pf] = __builtin_amdgcn_mfma_f32_16x16x32_bf16(af[cf], bfr[pf], acc[cf][pf], 0, 0, 0);
      }
    }
  }
  long long ob = (long long)n * 128 * HW + h0 * 128;
  #pragma unroll
  for (int cf = 0; cf < 4; ++cf)
    #pragma unroll
    for (int pf = 0; pf < 4; ++pf) {
      int co = wy * 64 + cf * 16 + l4 * 4;
      int w  = wx * 64 + pf * 16 + l15;
      #pragma unroll
      for (int r = 0; r < 4; ++r)
        out[ob + (long long)(co + r) * HW + w] = acc[cf][pf][r];
    }
}

// ---------------- BN batch stats ----------------
__global__ __launch_bounds__(256) void k_bnpart(const float* __restrict__ in, float* __restrict__ part) {
  int c = blockIdx.x, b = blockIdx.y, t = threadIdx.x;
  int n = b >> 3, seg = b & 7;
  long long base = (long long)(n * 128 + c) * HW + seg * 2048;
  float s = 0.f, ss = 0.f;
  for (int i = t; i < 2048; i += 256) { float v = in[base + i]; s += v; ss = fmaf(v, v, ss); }
  __shared__ float r1[256], r2[256];
  r1[t] = s; r2[t] = ss; __syncthreads();
  for (int o = 128; o > 0; o >>= 1) { if (t < o) { r1[t] += r1[t + o]; r2[t] += r2[t + o]; } __syncthreads(); }
  if (t == 0) { part[(c * 64 + b) * 2] = r1[0]; part[(c * 64 + b) * 2 + 1] = r2[0]; }
}
__global__ __launch_bounds__(64) void k_bnfin(const float* __restrict__ part, const float* __restrict__ g,
                                              const float* __restrict__ bb, float* __restrict__ ssout) {
  int c = blockIdx.x, t = threadIdx.x;
  float s = part[(c * 64 + t) * 2], ss = part[(c * 64 + t) * 2 + 1];
  for (int o = 32; o > 0; o >>= 1) { s += __shfl_down(s, o, 64); ss += __shfl_down(ss, o, 64); }
  if (t == 0) {
    float mean = s / 131072.f;
    float var = ss / 131072.f - mean * mean;
    float sc = g[c] * rsqrtf(var + 1e-5f);
    ssout[c] = sc;
    ssout[128 + c] = bb[c] - mean * sc;
  }
}

// ---------------- cubic power-mean per (n,c) ----------------
__global__ __launch_bounds__(256) void k_power(const float* __restrict__ in, const float* __restrict__ ss,
                                               float* __restrict__ dst, int off) {
  int c = blockIdx.x, n = blockIdx.y, t = threadIdx.x;
  float sc = ss[c], sh = ss[128 + c];
  long long base = (long long)(n * 128 + c) * HW;
  float s = 0.f;
  for (int i = t; i < HW; i += 256) {
    float r = fmaxf(fmaf(in[base + i], sc, sh), 0.f);
    s += r * r * r;
  }
  __shared__ float red[256];
  red[t] = s; __syncthreads();
  for (int o = 128; o > 0; o >>= 1) { if (t < o) red[t] += red[t + o]; __syncthreads(); }
  if (t == 0) dst[n * 256 + 2 * c + off] = cbrtf(red[0] * (1.f / 16384.f) + 1e-12f);
}

// ---------------- 1d conv x2 + sigmoid ----------------
__global__ __launch_bounds__(256) void k_dvec(const float* __restrict__ din, const float* __restrict__ c1,
                                              const float* __restrict__ c2, float* __restrict__ d0,
                                              float* __restrict__ d1) {
  __shared__ float a[256], b[256];
  int n = blockIdx.x, t = threadIdx.x;
  a[t] = din[n * 256 + t];
  __syncthreads();
  float acc = 0.f;
  #pragma unroll
  for (int k = 0; k < 5; ++k) { int j = t + k - 2; if (0 <= j && j < 256) acc = fmaf(c1[k], a[j], acc); }
  b[t] = acc; __syncthreads();
  float acc2 = 0.f;
  #pragma unroll
  for (int k = 0; k < 5; ++k) { int j = t + k - 2; if (0 <= j && j < 256) acc2 = fmaf(c2[k], b[j], acc2); }
  float sg = 1.f / (1.f + expf(-acc2));
  if ((t & 1) == 0) d0[n * 128 + (t >> 1)] = sg; else d1[n * 128 + (t >> 1)] = sg;
}

// ---------------- f = d0*relu(bn(low)) + d1*relu(bn(high)), in-place into low ----------------
__global__ __launch_bounds__(256) void k_fmix(float* __restrict__ low, const float* __restrict__ high,
                                              const float* __restrict__ ssl, const float* __restrict__ ssh,
                                              const float* __restrict__ d0, const float* __restrict__ d1) {
  int g = blockIdx.x * 256 + threadIdx.x;
  int c = (g >> 14) & 127, n = g >> 21;
  float xl = fmaxf(fmaf(low[g], ssl[c], ssl[128 + c]), 0.f);
  float xh = fmaxf(fmaf(high[g], ssh[c], ssh[128 + c]), 0.f);
  low[g] = d0[n * 128 + c] * xl + d1[n * 128 + c] * xh;
}

static void make_taps(int ks, double sigma, Taps* tp) {
  double c = (ks - 1) / 2.0, sum = 0.0, v[7];
  for (int i = 0; i < ks; ++i) { double d = i - c; v[i] = std::exp(-d * d / (2.0 * sigma * sigma)); sum += v[i]; }
  for (int i = 0; i < 7; ++i) tp->g[i] = (i < ks) ? (float)(v[i] / sum) : 0.f;
}

extern "C" void kernel_launch(void* const* d_in, const int* in_sizes, int n_in,
                              void* d_out, int out_size, void* d_ws, size_t ws_size,
                              hipStream_t stream) {
  const float* x         = (const float*)d_in[0];
  const float* dwconv_w  = (const float*)d_in[1];
  const float* dwconv_b  = (const float*)d_in[2];
  const float* qkvl_w    = (const float*)d_in[3];
  const float* qkvl_b    = (const float*)d_in[4];
  const float* reproj_w  = (const float*)d_in[5];
  const float* reproj_b  = (const float*)d_in[6];
  const float* queries_w = (const float*)d_in[7];
  const float* queries_b = (const float*)d_in[8];
  const float* sff_low_w = (const float*)d_in[9];
  const float* sff_low_g = (const float*)d_in[10];
  const float* sff_low_b = (const float*)d_in[11];
  const float* sff_high_w= (const float*)d_in[12];
  const float* sff_high_g= (const float*)d_in[13];
  const float* sff_high_b= (const float*)d_in[14];
  const float* sff_c1_w  = (const float*)d_in[15];
  const float* sff_c2_w  = (const float*)d_in[16];
  const float* out_conv_w= (const float*)d_in[17];
  const float* out_bn_g  = (const float*)d_in[18];
  const float* out_bn_b  = (const float*)d_in[19];
  const float* out_proj_w= (const float*)d_in[20];
  const float* out_proj_b= (const float*)d_in[21];
  float* ws  = (float*)d_ws;
  float* out = (float*)d_out;

  float* x1   = ws + OFF_X1;
  float* qs   = ws + OFF_QS;
  float* kk   = ws + OFF_KK;
  float* x2o  = ws + OFF_X2O;
  float* vv   = ws + OFF_V;
  float* lf   = ws + OFF_LF;
  float* qp   = ws + OFF_QP;
  float* kp   = ws + OFF_KP;
  float* tA   = ws;
  float* tB   = ws + U;
  float* ctx  = ws + U;
  float* attp = ws;
  float* qx   = ws;
  float* lowc = ws;
  float* highc= ws + U;
  float* fbuf = ws;
  float* qkb  = ws + OFF_QKB;
  float* Abuf = ws + OFF_AA;
  float* Mq   = ws + OFF_MQ;
  float* Dq   = ws + OFF_DQ;
  float* pmax = ws + OFF_PMAX;
  float* psum = ws + OFF_PSUM;
  float* Mc   = ws + OFF_MC;
  float* Dc   = ws + OFF_DC;
  float* att  = ws + OFF_ATT;
  float* bnp  = ws + OFF_BNP;
  float* ssl  = ws + OFF_SSL;
  float* ssh  = ws + OFF_SSH;
  float* ssy  = ws + OFF_SSY;
  float* dv   = ws + OFF_DV;
  float* d0v  = ws + OFF_D0;
  float* d1v  = ws + OFF_D1;
  unsigned short* wqk   = (unsigned short*)(ws + OFF_WQK);
  unsigned short* wlow  = (unsigned short*)(ws + OFF_WLOW);
  unsigned short* whigh = (unsigned short*)(ws + OFF_WHIGH);
  unsigned short* wout  = (unsigned short*)(ws + OFF_WOUT);
  unsigned short* effT  = (unsigned short*)out;
  unsigned short* freqT = (unsigned short*)(ws + U);
  unsigned short* fT    = (unsigned short*)(ws + U);
  float* ybuf = out;

  Taps t3, t5, t7;
  const double s3 = std::pow(2.0, 1.0 / 3.0);
  make_taps(3, 1.6, &t3);
  make_taps(5, 1.6 * s3, &t5);
  make_taps(7, 1.6 * s3 * s3, &t7);

  dim3 b256(256), b128(128);

  // ---- phase 1: eff -> effT (bf16 NHWC in d_out) ----
  k_wpackq<<<dim3(40), b256, 0, stream>>>(qkvl_w, wqk);
  k_haloz<<<dim3(258), b256, 0, stream>>>(effT);
  k_dwconv<<<dim3(32768), b256, 0, stream>>>(x, dwconv_w, dwconv_b, x1);
  k_qkvlm<<<dim3(128, 8), b256, 0, stream>>>(x, wqk, qkvl_b, qs, kk, vv, lf);
  k_avgpool<<<dim3(4096), b256, 0, stream>>>(qs, qp);
  k_maxpool<<<dim3(4096), b256, 0, stream>>>(kk, kp);
  k_qk<<<dim3(32, 8), b256, 0, stream>>>(qp, kp, qkb);
  k_qksm<<<dim3(8), dim3(32), 0, stream>>>(qkb, Abuf);
  k_x2o<<<dim3(512), b256, 0, stream>>>(Abuf, vv, x2o);
  k_gemm1x1m<M_EFF><<<dim3(128, 8), b256, 0, stream>>>(reproj_w, x1, lf, x2o, reproj_b,
                                                       nullptr, nullptr, nullptr, nullptr, effT);
  // ---- phase 2: ctx / att ----
  k_blur2<1, false><<<dim3(8, 1024), b256, 0, stream>>>(x, nullptr, tB, t3);
  k_blur2<2, false><<<dim3(8, 1024), b256, 0, stream>>>(tB, nullptr, tA, t5);
  k_blur2<3, true><<<dim3(8, 1024), b256, 0, stream>>>(tA, x, ctx, t7);
  k_ctx_stats<<<dim3(128, 8), b256, 0, stream>>>(ctx, Mc, Dc);
  k_attm<<<dim3(32, 8), b256, 0, stream>>>(ctx, Mc, Dc, attp);
  k_attred<<<dim3(512), b256, 0, stream>>>(attp, att);
  // ---- phase 3: qx -> freqT (bf16 NHWC in B2) ----
  k_gemm1x1m<M_QX><<<dim3(128, 8), b256, 0, stream>>>(queries_w, x, nullptr, nullptr, queries_b,
                                                      nullptr, nullptr, nullptr, nullptr, qx);
  k_qx_pmax<<<dim3(128, 8), b128, 0, stream>>>(qx, pmax);
  k_qx_rmax<<<dim3(8), b128, 0, stream>>>(pmax, Mq);
  k_qx_psum<<<dim3(128, 8), b128, 0, stream>>>(qx, Mq, psum);
  k_qx_rsum<<<dim3(8), b128, 0, stream>>>(psum, Dq);
  k_wpack<<<dim3(576), b256, 0, stream>>>(sff_low_w, wlow);
  k_wpack<<<dim3(576), b256, 0, stream>>>(sff_high_w, whigh);
  k_wpack<<<dim3(576), b256, 0, stream>>>(out_conv_w, wout);
  k_haloz<<<dim3(258), b256, 0, stream>>>(freqT);
  k_gemm1x1m<M_FREQ><<<dim3(128, 8), b256, 0, stream>>>(att, qx, nullptr, nullptr, nullptr,
                                                        nullptr, Mq, Dq, x, freqT);
  // ---- phase 4: convs / BN / mix / out ----
  k_conv3g<<<dim3(128, 8), b256, 0, stream>>>(freqT, wlow, lowc);
  k_conv3g<<<dim3(128, 8), b256, 0, stream>>>(effT, whigh, highc);
  k_bnpart<<<dim3(128, 64), b256, 0, stream>>>(lowc, bnp);
  k_bnfin<<<dim3(128), dim3(64), 0, stream>>>(bnp, sff_low_g, sff_low_b, ssl);
  k_bnpart<<<dim3(128, 64), b256, 0, stream>>>(highc, bnp);
  k_bnfin<<<dim3(128), dim3(64), 0, stream>>>(bnp, sff_high_g, sff_high_b, ssh);
  k_power<<<dim3(128, 8), b256, 0, stream>>>(lowc, ssl, dv, 0);
  k_power<<<dim3(128, 8), b256, 0, stream>>>(highc, ssh, dv, 1);
  k_dvec<<<dim3(8), b256, 0, stream>>>(dv, sff_c1_w, sff_c2_w, d0v, d1v);
  k_fmix<<<dim3(65536), b256, 0, stream>>>(lowc, highc, ssl, ssh, d0v, d1v);
  k_haloz<<<dim3(258), b256, 0, stream>>>(fT);
  k_t2nhwc<<<dim3(128, 8), b256, 0, stream>>>(fbuf, fT);
  k_conv3g<<<dim3(128, 8), b256, 0, stream>>>(fT, wout, ybuf);
  k_bnpart<<<dim3(128, 64), b256, 0, stream>>>(ybuf, bnp);
  k_bnfin<<<dim3(128), dim3(64), 0, stream>>>(bnp, out_bn_g, out_bn_b, ssy);
  k_gemm1x1m<M_OUT><<<dim3(128, 8), b256, 0, stream>>>(out_proj_w, ybuf, nullptr, nullptr, out_proj_b,
                                                       ssy, nullptr, nullptr, nullptr, out);
  (void)in_sizes; (void)n_in; (void)out_size; (void)ws_size;
}

// Round 7
// 1269.638 us; speedup vs baseline: 6.3743x; 1.0512x over previous
//
#include <hip/hip_runtime.h>
#include <hip/hip_bf16.h>
#include <cmath>

#define DEVFN __device__ __forceinline__

constexpr int HW = 16384;                      // 128*128
constexpr long long U = 16777216LL;            // 8*128*16384 floats
constexpr long long NHWC_N = 2163200LL;        // 130*130*128 ushorts per image

typedef __attribute__((ext_vector_type(8))) short bf16x8;
typedef __attribute__((ext_vector_type(4))) float f32x4;
typedef __attribute__((ext_vector_type(4))) unsigned short u16x4;

// ---- workspace layout (floats). B1 = ws[0,U), B2 = ws[U,2U), S = ws[2U,...). ~130 MB. ----
constexpr long long OFF_X1   = 0;
constexpr long long OFF_QS   = U/2;
constexpr long long OFF_KK   = 3*U/4;
constexpr long long OFF_X2O  = U/2;
constexpr long long OFF_V    = U;
constexpr long long OFF_LF   = U + U/4;
constexpr long long OFF_QP   = U + U/2;
constexpr long long OFF_KP   = U + U/2 + 1048576;
constexpr long long S0       = 2*U;
constexpr long long OFF_QKB  = S0;
constexpr long long OFF_AA   = S0 + 8192;
constexpr long long OFF_MQ   = S0 + 16384;
constexpr long long OFF_DQ   = S0 + 17408;
constexpr long long OFF_PMAX = S0 + 18432;     // 131072 (later: bf16 weight packs)
constexpr long long OFF_PSUM = S0 + 149504;    // 131072
constexpr long long OFF_MC   = S0 + 280576;
constexpr long long OFF_DC   = S0 + 281600;
constexpr long long OFF_ATT  = S0 + 282624;    // 131072
constexpr long long OFF_SSL  = S0 + 430080;
constexpr long long OFF_SSH  = S0 + 430336;
constexpr long long OFF_SSY  = S0 + 430592;
constexpr long long OFF_DV   = S0 + 430848;
constexpr long long OFF_D0   = S0 + 432896;
constexpr long long OFF_D1   = S0 + 433920;
constexpr long long OFF_WQK  = S0 + 434944;    // 5120 floats
constexpr long long OFF_WLOW  = OFF_PMAX;
constexpr long long OFF_WHIGH = OFF_PMAX + 73728;
constexpr long long OFF_WOUT  = OFF_PMAX + 147456;
// scratch in d_out tail (floats; NHWC region ends at float 8,652,800)
constexpr long long DOFF_CTXP  = 9000000;      // 16384 floats
constexpr long long DOFF_PARTA = 9100000;      // 262144
constexpr long long DOFF_PARTB = 9400000;      // 262144

struct Taps { float g[7]; };

DEVFN float gelu_f(float v) { return 0.5f * v * (1.0f + erff(v * 0.7071067811865475f)); }
DEVFN unsigned short f2b(float f) {
  unsigned u = __float_as_uint(f);
  unsigned r = u + 0x7fffu + ((u >> 16) & 1u);
  return (unsigned short)(r >> 16);
}
DEVFN unsigned pk2(float a, float b) {
  return (unsigned)f2b(a) | ((unsigned)f2b(b) << 16);
}

// ---------------- depthwise 3x3 + gelu on even channels ----------------
__global__ __launch_bounds__(256) void k_dwconv(const float* __restrict__ x, const float* __restrict__ w9,
                                                const float* __restrict__ bia, float* __restrict__ out) {
  int g = blockIdx.x * 256 + threadIdx.x;
  int w = g & 127, h = (g >> 7) & 127, c = (g >> 14) & 63, n = g >> 20;
  const float* src = x + (long long)(n * 128 + 2 * c) * HW;
  float acc = bia[c];
  #pragma unroll
  for (int ky = 0; ky < 3; ++ky) {
    int h2 = h + ky - 1;
    if ((unsigned)h2 < 128u) {
      #pragma unroll
      for (int kx = 0; kx < 3; ++kx) {
        int w2 = w + kx - 1;
        if ((unsigned)w2 < 128u) acc = fmaf(w9[c * 9 + ky * 3 + kx], src[h2 * 128 + w2], acc);
      }
    }
  }
  out[(long long)(n * 64 + c) * HW + h * 128 + w] = gelu_f(acc);
}

// ---------------- pack qkvl weights ----------------
__global__ __launch_bounds__(256) void k_wpackq(const float* __restrict__ w, unsigned short* __restrict__ wp) {
  int g = blockIdx.x * 256 + threadIdx.x;
  if (g < 10240) wp[g] = f2b(w[g]);
}

// ---------------- qkvl 1x1 conv (64->160) via bf16 MFMA + gelu + head routing ----------------
__global__ __launch_bounds__(256) void k_qkvlm(const float* __restrict__ x, const unsigned short* __restrict__ wqk,
                                               const float* __restrict__ bq, float* __restrict__ qs,
                                               float* __restrict__ kk, float* __restrict__ vv,
                                               float* __restrict__ lf) {
  __shared__ unsigned int As[160 * 36];
  __shared__ unsigned int Bs[128 * 36];
  const int t = threadIdx.x;
  const int bx = blockIdx.x, n = blockIdx.y;
  const int pxb = bx * 128;
  for (int e = t; e < 5120; e += 256) As[(e >> 5) * 36 + (e & 31)] = ((const unsigned int*)wqk)[e];
  #pragma unroll
  for (int it = 0; it < 16; ++it) {
    int e = it * 256 + t;
    int px = e & 127, k2 = e >> 7;
    float v0 = x[(long long)(n * 128 + 4 * k2 + 1) * HW + pxb + px];
    float v1 = x[(long long)(n * 128 + 4 * k2 + 3) * HW + pxb + px];
    Bs[px * 36 + k2] = pk2(v0, v1);
  }
  __syncthreads();
  const int wid = t >> 6, lane = t & 63, l15 = lane & 15, l4 = lane >> 4;
  f32x4 acc[10][2];
  #pragma unroll
  for (int m = 0; m < 10; ++m)
    #pragma unroll
    for (int p = 0; p < 2; ++p) { f32x4 z = {0.f,0.f,0.f,0.f}; acc[m][p] = z; }
  #pragma unroll
  for (int ks = 0; ks < 2; ++ks) {
    bf16x8 bfr[2];
    #pragma unroll
    for (int pf = 0; pf < 2; ++pf)
      bfr[pf] = *(const bf16x8*)(&Bs[(wid * 32 + pf * 16 + l15) * 36 + ks * 16 + l4 * 4]);
    #pragma unroll
    for (int mf = 0; mf < 10; ++mf) {
      bf16x8 af = *(const bf16x8*)(&As[(mf * 16 + l15) * 36 + ks * 16 + l4 * 4]);
      acc[mf][0] = __builtin_amdgcn_mfma_f32_16x16x32_bf16(af, bfr[0], acc[mf][0], 0, 0, 0);
      acc[mf][1] = __builtin_amdgcn_mfma_f32_16x16x32_bf16(af, bfr[1], acc[mf][1], 0, 0, 0);
    }
  }
  #pragma unroll
  for (int pf = 0; pf < 2; ++pf) {
    int px = pxb + wid * 32 + pf * 16 + l15;
    #pragma unroll
    for (int mf = 0; mf < 2; ++mf) {
      #pragma unroll
      for (int r = 0; r < 4; ++r) {
        int j = mf * 16 + l4 * 4 + r;
        long long o = (long long)(n * 32 + j) * HW + px;
        float a0 = gelu_f(acc[mf][pf][r] + bq[j]);
        float a1 = gelu_f(acc[mf + 2][pf][r] + bq[32 + j]);
        qs[o] = a0 + a1;
        kk[o] = gelu_f(acc[mf + 4][pf][r] + bq[64 + j]);
        vv[o] = gelu_f(acc[mf + 6][pf][r] + bq[96 + j]);
        lf[o] = gelu_f(acc[mf + 8][pf][r] + bq[128 + j]);
      }
    }
  }
}

// ---------------- pools ----------------
__global__ __launch_bounds__(256) void k_avgpool(const float* __restrict__ in, float* __restrict__ out) {
  int g = blockIdx.x * 256 + threadIdx.x;
  int ow = g & 63, oh = (g >> 6) & 63, c = (g >> 12) & 31, n = g >> 17;
  const float* src = in + (long long)(n * 32 + c) * HW;
  float s = 0.f;
  #pragma unroll
  for (int i = 0; i < 3; ++i) {
    int h = oh * 2 - 1 + i;
    if ((unsigned)h < 128u) {
      #pragma unroll
      for (int j = 0; j < 3; ++j) {
        int w = ow * 2 - 1 + j;
        if ((unsigned)w < 128u) s += src[h * 128 + w];
      }
    }
  }
  out[(long long)(n * 32 + c) * 4096 + oh * 64 + ow] = s * (1.f / 9.f);
}

__global__ __launch_bounds__(256) void k_maxpool(const float* __restrict__ in, float* __restrict__ out) {
  int g = blockIdx.x * 256 + threadIdx.x;
  int ow = g & 63, oh = (g >> 6) & 63, c = (g >> 12) & 31, n = g >> 17;
  const float* src = in + (long long)(n * 32 + c) * HW;
  float m = -3.0e38f;
  #pragma unroll
  for (int i = 0; i < 2; ++i)
    #pragma unroll
    for (int j = 0; j < 2; ++j)
      m = fmaxf(m, src[(oh * 2 + i) * 128 + ow * 2 + j]);
  out[(long long)(n * 32 + c) * 4096 + oh * 64 + ow] = m;
}

// ---------------- qk (32x32 per n, K=4096) ----------------
__global__ __launch_bounds__(256) void k_qk(const float* __restrict__ qp, const float* __restrict__ kp,
                                            float* __restrict__ qk) {
  int c = blockIdx.x, n = blockIdx.y;
  int t = threadIdx.x, d = t >> 3, r = t & 7;
  const float* qr = qp + (long long)(n * 32 + c) * 4096;
  const float* kr = kp + (long long)(n * 32 + d) * 4096;
  float acc = 0.f;
  for (int p = r; p < 4096; p += 8) acc = fmaf(qr[p], kr[p], acc);
  acc += __shfl_down(acc, 4, 8);
  acc += __shfl_down(acc, 2, 8);
  acc += __shfl_down(acc, 1, 8);
  if (r == 0) qk[(n * 32 + c) * 32 + d] = acc;
}

__global__ void k_qksm(const float* __restrict__ qk, float* __restrict__ A) {
  int n = blockIdx.x, d = threadIdx.x;
  float m = -3.0e38f;
  for (int c = 0; c < 32; ++c) m = fmaxf(m, qk[(n * 32 + c) * 32 + d]);
  float s = 0.f;
  for (int c = 0; c < 32; ++c) s += expf(qk[(n * 32 + c) * 32 + d] - m);
  float inv = 1.f / s;
  for (int c = 0; c < 32; ++c) A[(n * 32 + c) * 32 + d] = expf(qk[(n * 32 + c) * 32 + d] - m) * inv;
}

// ---------------- x2o = A^T @ v ----------------
__global__ __launch_bounds__(256) void k_x2o(const float* __restrict__ A, const float* __restrict__ vsrc,
                                             float* __restrict__ out) {
  __shared__ float lA[1024];
  int t = threadIdx.x;
  int g = blockIdx.x * 256 + t;
  int n = g >> 14, p = g & 16383;
  for (int e = t; e < 1024; e += 256) lA[e] = A[n * 1024 + e];
  __syncthreads();
  float acc[32];
  #pragma unroll
  for (int i = 0; i < 32; ++i) acc[i] = 0.f;
  for (int q = 0; q < 32; ++q) {
    float vv = vsrc[(long long)(n * 32 + q) * HW + p];
    #pragma unroll
    for (int k2 = 0; k2 < 32; ++k2) acc[k2] = fmaf(lA[q * 32 + k2], vv, acc[k2]);
  }
  #pragma unroll
  for (int k2 = 0; k2 < 32; ++k2) out[(long long)(n * 32 + k2) * HW + p] = acc[k2];
}

// ---------------- 128x128x128 GEMMs via bf16 MFMA ----------------
enum { M_EFF = 0, M_QX = 1, M_OUT = 2, M_FREQ = 3 };

template <int MODE>
__global__ __launch_bounds__(256) void k_gemm1x1m(
    const float* __restrict__ Amat, const float* __restrict__ B0, const float* __restrict__ B1,
    const float* __restrict__ B2, const float* __restrict__ bias, const float* __restrict__ scale,
    const float* __restrict__ Mq, const float* __restrict__ invDq, const float* __restrict__ xres,
    void* __restrict__ outp) {
  __shared__ unsigned int As[128 * 36];
  __shared__ unsigned int Bs[128 * 36];
  const int t = threadIdx.x;
  const int bx = blockIdx.x, n = blockIdx.y;
  const int pxb = bx * 128;
  const int wid = t >> 6, lane = t & 63, l15 = lane & 15, l4 = lane >> 4;
  const int wy = wid >> 1, wx = wid & 1;
  f32x4 acc[4][4];
  #pragma unroll
  for (int i = 0; i < 4; ++i)
    #pragma unroll
    for (int j = 0; j < 4; ++j) { f32x4 z = {0.f,0.f,0.f,0.f}; acc[i][j] = z; }

  for (int kc = 0; kc < 2; ++kc) {
    __syncthreads();
    if (MODE == M_FREQ) {
      #pragma unroll
      for (int it = 0; it < 16; ++it) {
        int e = it * 256 + t;
        int i = e & 127, j2l = e >> 7;
        int j = kc * 64 + 2 * j2l;
        float v0 = Amat[(long long)(n * 128 + j) * 128 + i];
        float v1 = Amat[(long long)(n * 128 + j + 1) * 128 + i];
        As[i * 36 + j2l] = pk2(v0, v1);
      }
    } else {
      #pragma unroll
      for (int it = 0; it < 16; ++it) {
        int e = it * 256 + t;
        int m = e >> 5, k2l = e & 31;
        float2 v = *(const float2*)(&Amat[m * 128 + kc * 64 + 2 * k2l]);
        As[m * 36 + k2l] = pk2(v.x, v.y);
      }
    }
    if (MODE == M_FREQ) {
      #pragma unroll
      for (int it = 0; it < 16; ++it) {
        int e = it * 256 + t;
        int j2l = e & 31, px = e >> 5;
        int j = kc * 64 + 2 * j2l;
        long long qb = ((long long)n * HW + pxb + px) * 128 + j;
        float2 v = *(const float2*)(&B0[qb]);
        float e0 = expf(v.x - Mq[n * 128 + j]) * invDq[n * 128 + j];
        float e1 = expf(v.y - Mq[n * 128 + j + 1]) * invDq[n * 128 + j + 1];
        Bs[px * 36 + j2l] = pk2(e0, e1);
      }
    } else {
      #pragma unroll
      for (int it = 0; it < 16; ++it) {
        int e = it * 256 + t;
        int px = e & 127, k2l = e >> 7;
        int ci = kc * 64 + 2 * k2l;
        float v0, v1;
        if (MODE == M_EFF) {
          if (ci < 64) {
            v0 = B0[(long long)(n * 64 + ci) * HW + pxb + px];
            v1 = B0[(long long)(n * 64 + ci + 1) * HW + pxb + px];
          } else if (ci < 96) {
            v0 = B1[(long long)(n * 32 + ci - 64) * HW + pxb + px];
            v1 = B1[(long long)(n * 32 + ci - 63) * HW + pxb + px];
          } else {
            v0 = B2[(long long)(n * 32 + ci - 96) * HW + pxb + px];
            v1 = B2[(long long)(n * 32 + ci - 95) * HW + pxb + px];
          }
        } else if (MODE == M_QX) {
          v0 = B0[(long long)(n * 128 + ci) * HW + pxb + px];
          v1 = B0[(long long)(n * 128 + ci + 1) * HW + pxb + px];
        } else {
          float u0 = B0[(long long)(n * 128 + ci) * HW + pxb + px];
          float u1 = B0[(long long)(n * 128 + ci + 1) * HW + pxb + px];
          v0 = fmaxf(fmaf(u0, scale[ci], scale[128 + ci]), 0.f);
          v1 = fmaxf(fmaf(u1, scale[ci + 1], scale[128 + ci + 1]), 0.f);
        }
        Bs[px * 36 + k2l] = pk2(v0, v1);
      }
    }
    __syncthreads();
    #pragma unroll
    for (int ks = 0; ks < 2; ++ks) {
      bf16x8 af[4], bfr[4];
      #pragma unroll
      for (int mf = 0; mf < 4; ++mf)
        af[mf] = *(const bf16x8*)(&As[(wy * 64 + mf * 16 + l15) * 36 + ks * 16 + l4 * 4]);
      #pragma unroll
      for (int nf = 0; nf < 4; ++nf)
        bfr[nf] = *(const bf16x8*)(&Bs[(wx * 64 + nf * 16 + l15) * 36 + ks * 16 + l4 * 4]);
      #pragma unroll
      for (int mf = 0; mf < 4; ++mf)
        #pragma unroll
        for (int nf = 0; nf < 4; ++nf)
          acc[mf][nf] = __builtin_amdgcn_mfma_f32_16x16x32_bf16(af[mf], bfr[nf], acc[mf][nf], 0, 0, 0);
    }
  }
  if (MODE == M_EFF || MODE == M_FREQ) {
    unsigned short* oT = (unsigned short*)outp;
    #pragma unroll
    for (int nf = 0; nf < 4; ++nf) {
      int px = pxb + wx * 64 + nf * 16 + l15;
      int hh = px >> 7, wwp = (px & 127) + 1;
      long long rb = (long long)n * NHWC_N + ((long long)(hh + 1) * 130 + wwp) * 128;
      #pragma unroll
      for (int mf = 0; mf < 4; ++mf) {
        int ch = wy * 64 + mf * 16 + l4 * 4;
        u16x4 pk;
        #pragma unroll
        for (int r = 0; r < 4; ++r) {
          float v = acc[mf][nf][r] + ((MODE == M_EFF) ? bias[ch + r] : 0.f);
          if (MODE == M_FREQ) v += xres[(long long)(n * 128 + ch + r) * HW + px];
          pk[r] = f2b(v);
        }
        *(u16x4*)(&oT[rb + ch]) = pk;
      }
    }
  } else {
    float* of = (float*)outp;
    #pragma unroll
    for (int mf = 0; mf < 4; ++mf)
      #pragma unroll
      for (int nf = 0; nf < 4; ++nf) {
        int px = pxb + wx * 64 + nf * 16 + l15;
        #pragma unroll
        for (int r = 0; r < 4; ++r) {
          int ch = wy * 64 + mf * 16 + l4 * 4 + r;
          of[(long long)(n * 128 + ch) * HW + px] = acc[mf][nf][r] + bias[ch];
        }
      }
  }
}

// ---------------- qx softmax stats (fused max+sum, then cross-c reduce) ----------------
__global__ __launch_bounds__(128) void k_qx_stat1(const float* __restrict__ qx, float* __restrict__ pm,
                                                  float* __restrict__ ps) {
  int c = blockIdx.x, n = blockIdx.y, w = threadIdx.x;
  long long base = (long long)(n * 128 + c) * HW + w;
  float m = -3.0e38f;
  for (int h = 0; h < 128; ++h) m = fmaxf(m, qx[base + h * 128]);
  float s = 0.f;
  for (int h = 0; h < 128; ++h) s += expf(qx[base + h * 128] - m);
  pm[(n * 128 + c) * 128 + w] = m;
  ps[(n * 128 + c) * 128 + w] = s;
}
__global__ __launch_bounds__(128) void k_qx_stat2(const float* __restrict__ pm, const float* __restrict__ ps,
                                                  float* __restrict__ Mq, float* __restrict__ Dq) {
  int n = blockIdx.x, w = threadIdx.x;
  float M = -3.0e38f;
  for (int c = 0; c < 128; ++c) M = fmaxf(M, pm[(n * 128 + c) * 128 + w]);
  float D = 0.f;
  for (int c = 0; c < 128; ++c) D += ps[(n * 128 + c) * 128 + w] * expf(pm[(n * 128 + c) * 128 + w] - M);
  Mq[n * 128 + w] = M;
  Dq[n * 128 + w] = 1.f / D;
}

// ---------------- fused 3-stage gaussian pyramid + ctx + online softmax partials ----------------
DEVFN void blur_stage(float* sA, float* sB, const float* g, int R, int lo, int hi, int h0, int t) {
  __syncthreads();
  for (int e = t; e < 3584; e += 256) {
    int w = e & 127;
    float s = 0.f;
    for (int d = -R; d <= R; ++d) {
      int wd = w + d;
      if (0 <= wd && wd < 128) s = fmaf(g[d + R], sA[e + d], s);
    }
    sB[e] = s;
  }
  __syncthreads();
  for (int e = t; e < 3584; e += 256) {
    int r = e >> 7;
    if (r < lo || r > hi) continue;
    int h = h0 - 6 + r;
    float s = 0.f;
    for (int d = -R; d <= R; ++d) s = fmaf(g[d + R], sB[e + d * 128], s);
    sA[e] = ((unsigned)h < 128u) ? s : 0.f;
  }
}

__global__ __launch_bounds__(256) void k_blur3(const float* __restrict__ x, float* __restrict__ ctx,
                                               float* __restrict__ ctxp, Taps t3, Taps t5, Taps t7) {
  __shared__ float sA[3584];
  __shared__ float sB[3584];
  __shared__ float rm[256], rs[256];
  const int t = threadIdx.x;
  const int ht = blockIdx.x, h0 = ht * 16;
  const long long nc = blockIdx.y;
  const float* src = x + nc * HW;
  for (int e = t; e < 3584; e += 256) {
    int r = e >> 7, h = h0 - 6 + r;
    sA[e] = ((unsigned)h < 128u) ? src[h * 128 + (e & 127)] : 0.f;
  }
  blur_stage(sA, sB, t3.g, 1, 1, 26, h0, t);
  blur_stage(sA, sB, t5.g, 2, 3, 24, h0, t);
  blur_stage(sA, sB, t7.g, 3, 6, 21, h0, t);
  __syncthreads();
  long long ob = nc * HW + (long long)h0 * 128;
  float lm = -3.0e38f, lsum = 0.f;
  for (int e = t; e < 2048; e += 256) {
    int r = e >> 7, w = e & 127;
    float v = src[(h0 + r) * 128 + w] - sA[(6 + r) * 128 + w];
    ctx[ob + e] = v;
    if (v > lm) { lsum = lsum * expf(lm - v) + 1.f; lm = v; }
    else lsum += expf(v - lm);
  }
  rm[t] = lm; rs[t] = lsum; __syncthreads();
  for (int o = 128; o > 0; o >>= 1) {
    if (t < o) {
      float m2 = rm[t + o], s2 = rs[t + o];
      float M = fmaxf(rm[t], m2);
      rs[t] = rs[t] * expf(rm[t] - M) + s2 * expf(m2 - M);
      rm[t] = M;
    }
    __syncthreads();
  }
  if (t == 0) { ctxp[nc * 16 + ht * 2] = rm[0]; ctxp[nc * 16 + ht * 2 + 1] = rs[0]; }
}

__global__ __launch_bounds__(256) void k_ctx_red(const float* __restrict__ ctxp, float* __restrict__ Mc,
                                                 float* __restrict__ Dc) {
  int g = blockIdx.x * 256 + threadIdx.x;   // 1024
  float M = -3.0e38f, S = 0.f;
  #pragma unroll
  for (int i = 0; i < 8; ++i) {
    float m2 = ctxp[g * 16 + i * 2], s2 = ctxp[g * 16 + i * 2 + 1];
    float Mn = fmaxf(M, m2);
    S = S * expf(M - Mn) + s2 * expf(m2 - Mn);
    M = Mn;
  }
  Mc[g] = M; Dc[g] = 1.f / S;
}

// ---------------- att = softmax(ctx) @ ctx^T via bf16 MFMA (partials) ----------------
__global__ __launch_bounds__(256) void k_attm(const float* __restrict__ ctx, const float* __restrict__ Mc,
                                              const float* __restrict__ invDc, float* __restrict__ attp) {
  __shared__ unsigned int As[128 * 36];
  __shared__ unsigned int Bs[128 * 36];
  const int t = threadIdx.x, sp = blockIdx.x, n = blockIdx.y;
  const int wid = t >> 6, lane = t & 63, l15 = lane & 15, l4 = lane >> 4;
  const int wy = wid >> 1, wx = wid & 1;
  f32x4 acc[4][4];
  #pragma unroll
  for (int i = 0; i < 4; ++i)
    #pragma unroll
    for (int j = 0; j < 4; ++j) { f32x4 z = {0.f,0.f,0.f,0.f}; acc[i][j] = z; }
  for (int kc = 0; kc < 8; ++kc) {
    __syncthreads();
    int pb = sp * 512 + kc * 64;
    #pragma unroll
    for (int it = 0; it < 16; ++it) {
      int e = it * 256 + t;
      int row = e >> 5, p2 = e & 31;
      float2 v = *(const float2*)(&ctx[(long long)(n * 128 + row) * HW + pb + 2 * p2]);
      float m = Mc[n * 128 + row], d = invDc[n * 128 + row];
      Bs[row * 36 + p2] = pk2(v.x, v.y);
      As[row * 36 + p2] = pk2(expf(v.x - m) * d, expf(v.y - m) * d);
    }
    __syncthreads();
    #pragma unroll
    for (int ks = 0; ks < 2; ++ks) {
      bf16x8 af[4], bfr[4];
      #pragma unroll
      for (int mf = 0; mf < 4; ++mf)
        af[mf] = *(const bf16x8*)(&As[(wy * 64 + mf * 16 + l15) * 36 + ks * 16 + l4 * 4]);
      #pragma unroll
      for (int nf = 0; nf < 4; ++nf)
        bfr[nf] = *(const bf16x8*)(&Bs[(wx * 64 + nf * 16 + l15) * 36 + ks * 16 + l4 * 4]);
      #pragma unroll
      for (int mf = 0; mf < 4; ++mf)
        #pragma unroll
        for (int nf = 0; nf < 4; ++nf)
          acc[mf][nf] = __builtin_amdgcn_mfma_f32_16x16x32_bf16(af[mf], bfr[nf], acc[mf][nf], 0, 0, 0);
    }
  }
  long long ob = (long long)(sp * 8 + n) * 16384;
  #pragma unroll
  for (int mf = 0; mf < 4; ++mf)
    #pragma unroll
    for (int nf = 0; nf < 4; ++nf) {
      int d = wx * 64 + nf * 16 + l15;
      #pragma unroll
      for (int r = 0; r < 4; ++r) {
        int c = wy * 64 + mf * 16 + l4 * 4 + r;
        attp[ob + c * 128 + d] = acc[mf][nf][r];
      }
    }
}

__global__ __launch_bounds__(256) void k_attred(const float* __restrict__ attp, float* __restrict__ att) {
  int g = blockIdx.x * 256 + threadIdx.x;
  float s = 0.f;
  for (int sp = 0; sp < 32; ++sp) s += attp[(long long)sp * 131072 + g];
  att[g] = s;
}

// ---------------- pack conv weight -> bf16 [co][tap*128+ci] ----------------
__global__ __launch_bounds__(256) void k_wpack(const float* __restrict__ w, unsigned short* __restrict__ wp) {
  int g = blockIdx.x * 256 + threadIdx.x;
  int ci = g & 127;
  int tap = (g >> 7) % 9;
  int co = g / 1152;
  wp[g] = f2b(w[co * 1152 + ci * 9 + tap]);
}

// ---------------- zero halo of padded NHWC bf16 ----------------
__global__ __launch_bounds__(256) void k_haloz(unsigned short* __restrict__ p) {
  int idx = blockIdx.x * 256 + threadIdx.x;
  if (idx >= 66048) return;
  int n = idx / 8256;
  int r = idx % 8256;
  int cell = r >> 4, q = r & 15;
  int h, w;
  if (cell < 130)      { h = 0;   w = cell; }
  else if (cell < 260) { h = 129; w = cell - 130; }
  else if (cell < 388) { h = cell - 260 + 1; w = 0; }
  else                 { h = cell - 388 + 1; w = 129; }
  uint4 z = {0u, 0u, 0u, 0u};
  *(uint4*)(p + (long long)n * NHWC_N + ((long long)h * 130 + w) * 128 + q * 8) = z;
}

// ---------------- 3x3 conv: bf16 MFMA, software-pipelined direct-global, + BN partials ----------------
__global__ __launch_bounds__(256) void k_conv3g(const unsigned short* __restrict__ inT,
                                                const unsigned short* __restrict__ wp,
                                                float* __restrict__ out,
                                                float* __restrict__ part) {
  const int t = threadIdx.x;
  const int h0 = blockIdx.x, n = blockIdx.y;
  const int wid = t >> 6, lane = t & 63;
  const int wy = wid >> 1, wx = wid & 1;
  const int l15 = lane & 15, l4 = lane >> 4;
  f32x4 acc[4][4];
  #pragma unroll
  for (int i = 0; i < 4; ++i)
    #pragma unroll
    for (int j = 0; j < 4; ++j) { f32x4 z = {0.f, 0.f, 0.f, 0.f}; acc[i][j] = z; }
  const unsigned short* bbase = inT + (long long)n * NHWC_N
                              + ((long long)h0 * 130 + wx * 64 + l15) * 128 + l4 * 8;
  const unsigned short* abase = wp + (wy * 64 + l15) * 1152 + l4 * 8;

  bf16x8 fa[2][4], fb[2][4];
  auto LOADS = [&](int s, bf16x8* A, bf16x8* B) {
    const int kc = s / 9, tap = s % 9, ky = tap / 3, kx = tap % 3;
    #pragma unroll
    for (int cf = 0; cf < 4; ++cf)
      A[cf] = *(const bf16x8*)(abase + cf * 16 * 1152 + tap * 128 + kc * 32);
    #pragma unroll
    for (int pf = 0; pf < 4; ++pf)
      B[pf] = *(const bf16x8*)(bbase + ((long long)ky * 130 + pf * 16 + kx) * 128 + kc * 32);
  };
  LOADS(0, fa[0], fb[0]);
  #pragma unroll
  for (int s = 0; s < 36; ++s) {
    const int cur = s & 1;
    if (s < 35) LOADS(s + 1, fa[cur ^ 1], fb[cur ^ 1]);
    #pragma unroll
    for (int cf = 0; cf < 4; ++cf)
      #pragma unroll
      for (int pf = 0; pf < 4; ++pf)
        acc[cf][pf] = __builtin_amdgcn_mfma_f32_16x16x32_bf16(fa[cur][cf], fb[cur][pf], acc[cf][pf], 0, 0, 0);
  }
  long long ob = (long long)n * 128 * HW + h0 * 128;
  #pragma unroll
  for (int cf = 0; cf < 4; ++cf)
    #pragma unroll
    for (int pf = 0; pf < 4; ++pf) {
      int co = wy * 64 + cf * 16 + l4 * 4;
      int w  = wx * 64 + pf * 16 + l15;
      #pragma unroll
      for (int r = 0; r < 4; ++r)
        out[ob + (long long)(co + r) * HW + w] = acc[cf][pf][r];
    }
  // BN partials: per-co sum / sumsq over this block's 128 px
  __shared__ float redS[4][64], redQ[4][64];
  #pragma unroll
  for (int cf = 0; cf < 4; ++cf)
    #pragma unroll
    for (int r = 0; r < 4; ++r) {
      float s = 0.f, q = 0.f;
      #pragma unroll
      for (int pf = 0; pf < 4; ++pf) { float v = acc[cf][pf][r]; s += v; q = fmaf(v, v, q); }
      #pragma unroll
      for (int off = 1; off < 16; off <<= 1) { s += __shfl_xor(s, off, 16); q += __shfl_xor(q, off, 16); }
      if (l15 == 0) { redS[wid][cf * 16 + l4 * 4 + r] = s; redQ[wid][cf * 16 + l4 * 4 + r] = q; }
    }
  __syncthreads();
  if (t < 128) {
    int wy2 = t >> 6, col = t & 63;
    int co = wy2 * 64 + col;
    float s = redS[wy2 * 2][col] + redS[wy2 * 2 + 1][col];
    float q = redQ[wy2 * 2][col] + redQ[wy2 * 2 + 1][col];
    long long pb = ((long long)(n * 128 + h0) * 128 + co) * 2;
    part[pb] = s; part[pb + 1] = q;
  }
}

// ---------------- BN reduce over 1024 block-partials ----------------
__global__ __launch_bounds__(256) void k_bnred(const float* __restrict__ part, const float* __restrict__ g,
                                               const float* __restrict__ bb, float* __restrict__ ssout) {
  int c = blockIdx.x, t = threadIdx.x;
  float s = 0.f, q = 0.f;
  for (int b = t; b < 1024; b += 256) {
    s += part[((long long)b * 128 + c) * 2];
    q += part[((long long)b * 128 + c) * 2 + 1];
  }
  __shared__ float r1[256], r2[256];
  r1[t] = s; r2[t] = q; __syncthreads();
  for (int o = 128; o > 0; o >>= 1) { if (t < o) { r1[t] += r1[t + o]; r2[t] += r2[t + o]; } __syncthreads(); }
  if (t == 0) {
    float mean = r1[0] / 131072.f;
    float var = r2[0] / 131072.f - mean * mean;
    float sc = g[c] * rsqrtf(var + 1e-5f);
    ssout[c] = sc;
    ssout[128 + c] = bb[c] - mean * sc;
  }
}

// ---------------- cubic power-mean per (n,c) ----------------
__global__ __launch_bounds__(256) void k_power(const float* __restrict__ in, const float* __restrict__ ss,
                                               float* __restrict__ dst, int off) {
  int c = blockIdx.x, n = blockIdx.y, t = threadIdx.x;
  float sc = ss[c], sh = ss[128 + c];
  long long base = (long long)(n * 128 + c) * HW;
  float s = 0.f;
  for (int i = t; i < HW; i += 256) {
    float r = fmaxf(fmaf(in[base + i], sc, sh), 0.f);
    s += r * r * r;
  }
  __shared__ float red[256];
  red[t] = s; __syncthreads();
  for (int o = 128; o > 0; o >>= 1) { if (t < o) red[t] += red[t + o]; __syncthreads(); }
  if (t == 0) dst[n * 256 + 2 * c + off] = cbrtf(red[0] * (1.f / 16384.f) + 1e-12f);
}

// ---------------- 1d conv x2 + sigmoid ----------------
__global__ __launch_bounds__(256) void k_dvec(const float* __restrict__ din, const float* __restrict__ c1,
                                              const float* __restrict__ c2, float* __restrict__ d0,
                                              float* __restrict__ d1) {
  __shared__ float a[256], b[256];
  int n = blockIdx.x, t = threadIdx.x;
  a[t] = din[n * 256 + t];
  __syncthreads();
  float acc = 0.f;
  #pragma unroll
  for (int k = 0; k < 5; ++k) { int j = t + k - 2; if (0 <= j && j < 256) acc = fmaf(c1[k], a[j], acc); }
  b[t] = acc; __syncthreads();
  float acc2 = 0.f;
  #pragma unroll
  for (int k = 0; k < 5; ++k) { int j = t + k - 2; if (0 <= j && j < 256) acc2 = fmaf(c2[k], b[j], acc2); }
  float sg = 1.f / (1.f + expf(-acc2));
  if ((t & 1) == 0) d0[n * 128 + (t >> 1)] = sg; else d1[n * 128 + (t >> 1)] = sg;
}

// ---------------- fused fmix + NHWC bf16 pack (f = d0*relu(bn(low)) + d1*relu(bn(high))) ----------------
__global__ __launch_bounds__(256) void k_fmixT(const float* __restrict__ low, const float* __restrict__ high,
                                               const float* __restrict__ ssl, const float* __restrict__ ssh,
                                               const float* __restrict__ d0, const float* __restrict__ d1,
                                               unsigned short* __restrict__ outT) {
  __shared__ float ld[64 * 129];
  int t = threadIdx.x;
  int h = blockIdx.x, n = blockIdx.y;
  const long long sb = (long long)n * 128 * HW + h * 128;
  unsigned short* dst = outT + (long long)n * NHWC_N + ((long long)(h + 1) * 130 + 1) * 128;
  for (int half = 0; half < 2; ++half) {
    __syncthreads();
    for (int e = t; e < 8192; e += 256) {
      int c = e >> 7, w = e & 127;
      int cg = half * 64 + c;
      float xl = fmaxf(fmaf(low[sb + (long long)cg * HW + w], ssl[cg], ssl[128 + cg]), 0.f);
      float xh = fmaxf(fmaf(high[sb + (long long)cg * HW + w], ssh[cg], ssh[128 + cg]), 0.f);
      ld[c * 129 + w] = d0[n * 128 + cg] * xl + d1[n * 128 + cg] * xh;
    }
    __syncthreads();
    for (int q = t; q < 1024; q += 256) {
      int w = q >> 3, cg8 = q & 7;
      bf16x8 pk;
      #pragma unroll
      for (int u = 0; u < 8; ++u) pk[u] = (short)f2b(ld[(cg8 * 8 + u) * 129 + w]);
      *(bf16x8*)(dst + (long long)w * 128 + half * 64 + cg8 * 8) = pk;
    }
  }
}

static void make_taps(int ks, double sigma, Taps* tp) {
  double c = (ks - 1) / 2.0, sum = 0.0, v[7];
  for (int i = 0; i < ks; ++i) { double d = i - c; v[i] = std::exp(-d * d / (2.0 * sigma * sigma)); sum += v[i]; }
  for (int i = 0; i < 7; ++i) tp->g[i] = (i < ks) ? (float)(v[i] / sum) : 0.f;
}

extern "C" void kernel_launch(void* const* d_in, const int* in_sizes, int n_in,
                              void* d_out, int out_size, void* d_ws, size_t ws_size,
                              hipStream_t stream) {
  const float* x         = (const float*)d_in[0];
  const float* dwconv_w  = (const float*)d_in[1];
  const float* dwconv_b  = (const float*)d_in[2];
  const float* qkvl_w    = (const float*)d_in[3];
  const float* qkvl_b    = (const float*)d_in[4];
  const float* reproj_w  = (const float*)d_in[5];
  const float* reproj_b  = (const float*)d_in[6];
  const float* queries_w = (const float*)d_in[7];
  const float* queries_b = (const float*)d_in[8];
  const float* sff_low_w = (const float*)d_in[9];
  const float* sff_low_g = (const float*)d_in[10];
  const float* sff_low_b = (const float*)d_in[11];
  const float* sff_high_w= (const float*)d_in[12];
  const float* sff_high_g= (const float*)d_in[13];
  const float* sff_high_b= (const float*)d_in[14];
  const float* sff_c1_w  = (const float*)d_in[15];
  const float* sff_c2_w  = (const float*)d_in[16];
  const float* out_conv_w= (const float*)d_in[17];
  const float* out_bn_g  = (const float*)d_in[18];
  const float* out_bn_b  = (const float*)d_in[19];
  const float* out_proj_w= (const float*)d_in[20];
  const float* out_proj_b= (const float*)d_in[21];
  float* ws  = (float*)d_ws;
  float* out = (float*)d_out;

  float* x1   = ws + OFF_X1;
  float* qs   = ws + OFF_QS;
  float* kk   = ws + OFF_KK;
  float* x2o  = ws + OFF_X2O;
  float* vv   = ws + OFF_V;
  float* lf   = ws + OFF_LF;
  float* qp   = ws + OFF_QP;
  float* kp   = ws + OFF_KP;
  float* ctx  = ws + U;
  float* attp = ws;
  float* qx   = ws;
  float* lowc = ws;
  float* highc= ws + U;
  float* ybuf = ws;             // B1 (lowc dead after fmixT)
  float* qkb  = ws + OFF_QKB;
  float* Abuf = ws + OFF_AA;
  float* Mq   = ws + OFF_MQ;
  float* Dq   = ws + OFF_DQ;
  float* pm   = ws + OFF_PMAX;
  float* psv  = ws + OFF_PSUM;
  float* Mc   = ws + OFF_MC;
  float* Dc   = ws + OFF_DC;
  float* att  = ws + OFF_ATT;
  float* ssl  = ws + OFF_SSL;
  float* ssh  = ws + OFF_SSH;
  float* ssy  = ws + OFF_SSY;
  float* dv   = ws + OFF_DV;
  float* d0v  = ws + OFF_D0;
  float* d1v  = ws + OFF_D1;
  unsigned short* wqk   = (unsigned short*)(ws + OFF_WQK);
  unsigned short* wlow  = (unsigned short*)(ws + OFF_WLOW);
  unsigned short* whigh = (unsigned short*)(ws + OFF_WHIGH);
  unsigned short* wout  = (unsigned short*)(ws + OFF_WOUT);
  unsigned short* effT  = (unsigned short*)out;      // d_out NHWC bf16 (front 34.6MB)
  unsigned short* freqT = (unsigned short*)(ws + U); // B2 front
  unsigned short* fT    = (unsigned short*)out;      // reuses effT region (halo already zero)
  float* ctxp  = out + DOFF_CTXP;                    // d_out tail scratch
  float* partA = out + DOFF_PARTA;
  float* partB = out + DOFF_PARTB;

  Taps t3, t5, t7;
  const double s3 = std::pow(2.0, 1.0 / 3.0);
  make_taps(3, 1.6, &t3);
  make_taps(5, 1.6 * s3, &t5);
  make_taps(7, 1.6 * s3 * s3, &t7);

  dim3 b256(256), b128(128);

  // ---- phase 1: eff -> effT ----
  k_wpackq<<<dim3(40), b256, 0, stream>>>(qkvl_w, wqk);
  k_haloz<<<dim3(258), b256, 0, stream>>>(effT);
  k_dwconv<<<dim3(32768), b256, 0, stream>>>(x, dwconv_w, dwconv_b, x1);
  k_qkvlm<<<dim3(128, 8), b256, 0, stream>>>(x, wqk, qkvl_b, qs, kk, vv, lf);
  k_avgpool<<<dim3(4096), b256, 0, stream>>>(qs, qp);
  k_maxpool<<<dim3(4096), b256, 0, stream>>>(kk, kp);
  k_qk<<<dim3(32, 8), b256, 0, stream>>>(qp, kp, qkb);
  k_qksm<<<dim3(8), dim3(32), 0, stream>>>(qkb, Abuf);
  k_x2o<<<dim3(512), b256, 0, stream>>>(Abuf, vv, x2o);
  k_gemm1x1m<M_EFF><<<dim3(128, 8), b256, 0, stream>>>(reproj_w, x1, lf, x2o, reproj_b,
                                                       nullptr, nullptr, nullptr, nullptr, effT);
  // ---- phase 2: ctx / att (fused pyramid + stats) ----
  k_blur3<<<dim3(8, 1024), b256, 0, stream>>>(x, ctx, ctxp, t3, t5, t7);
  k_ctx_red<<<dim3(4), b256, 0, stream>>>(ctxp, Mc, Dc);
  k_attm<<<dim3(32, 8), b256, 0, stream>>>(ctx, Mc, Dc, attp);
  k_attred<<<dim3(512), b256, 0, stream>>>(attp, att);
  // ---- phase 3: qx -> freqT ----
  k_gemm1x1m<M_QX><<<dim3(128, 8), b256, 0, stream>>>(queries_w, x, nullptr, nullptr, queries_b,
                                                      nullptr, nullptr, nullptr, nullptr, qx);
  k_qx_stat1<<<dim3(128, 8), b128, 0, stream>>>(qx, pm, psv);
  k_qx_stat2<<<dim3(8), b128, 0, stream>>>(pm, psv, Mq, Dq);
  k_wpack<<<dim3(576), b256, 0, stream>>>(sff_low_w, wlow);
  k_wpack<<<dim3(576), b256, 0, stream>>>(sff_high_w, whigh);
  k_wpack<<<dim3(576), b256, 0, stream>>>(out_conv_w, wout);
  k_haloz<<<dim3(258), b256, 0, stream>>>(freqT);
  k_gemm1x1m<M_FREQ><<<dim3(128, 8), b256, 0, stream>>>(att, qx, nullptr, nullptr, nullptr,
                                                        nullptr, Mq, Dq, x, freqT);
  // ---- phase 4: convs (+fused BN partials) / power / mix / out ----
  k_conv3g<<<dim3(128, 8), b256, 0, stream>>>(freqT, wlow, lowc, partA);
  k_conv3g<<<dim3(128, 8), b256, 0, stream>>>(effT, whigh, highc, partB);
  k_bnred<<<dim3(128), b256, 0, stream>>>(partA, sff_low_g, sff_low_b, ssl);
  k_bnred<<<dim3(128), b256, 0, stream>>>(partB, sff_high_g, sff_high_b, ssh);
  k_power<<<dim3(128, 8), b256, 0, stream>>>(lowc, ssl, dv, 0);
  k_power<<<dim3(128, 8), b256, 0, stream>>>(highc, ssh, dv, 1);
  k_dvec<<<dim3(8), b256, 0, stream>>>(dv, sff_c1_w, sff_c2_w, d0v, d1v);
  k_fmixT<<<dim3(128, 8), b256, 0, stream>>>(lowc, highc, ssl, ssh, d0v, d1v, fT);
  k_conv3g<<<dim3(128, 8), b256, 0, stream>>>(fT, wout, ybuf, partA);
  k_bnred<<<dim3(128), b256, 0, stream>>>(partA, out_bn_g, out_bn_b, ssy);
  k_gemm1x1m<M_OUT><<<dim3(128, 8), b256, 0, stream>>>(out_proj_w, ybuf, nullptr, nullptr, out_proj_b,
                                                       ssy, nullptr, nullptr, nullptr, out);
  (void)in_sizes; (void)n_in; (void)out_size; (void)ws_size;
}